// Round 5
// baseline (4344.267 us; speedup 1.0000x reference)
//
#include <hip/hip_runtime.h>
#include <hip/hip_cooperative_groups.h>
#include <stdint.h>

namespace cg = cooperative_groups;

// ---------------------------------------------------------------------------
// TopologicalContrastiveLoss: H0 persistence (MST edge weights) of 3 point
// clouds -> 1-Wasserstein between sorted death vectors -> hinge loss.
//
// R5: per-cloud Boruvka fused into ONE cooperative kernel (1024x256,
// grid.sync between phases). Round-1 scan fused into the GEMM epilogue.
// Keys carry a decreasing round prefix ((12-r)<<60) so best[] never needs
// resetting and stale entries are self-identifying. Each block keeps comp[]
// in its own LDS and redundantly runs the identical merge; the only
// cross-block state is best[] (device-scope atomicMin).
// ---------------------------------------------------------------------------

#define NPTS 4096
#define DIMF 1024
typedef unsigned short u16;
typedef _Float16 f16;
typedef unsigned long long ull;
static const ull KEY_MAX_ULL = ~0ull;

typedef f16 f16x8 __attribute__((ext_vector_type(8)));
typedef f16 f16x4v __attribute__((ext_vector_type(4)));
typedef float f32x4 __attribute__((ext_vector_type(4)));

#define GLOAD_LDS16(g, l)                                                      \
  __builtin_amdgcn_global_load_lds(                                            \
      (const __attribute__((address_space(1))) void*)(g),                      \
      (__attribute__((address_space(3))) void*)(l), 16, 0, 0)

// ------------------------------ init ---------------------------------------
__global__ void k_init_global(float* __restrict__ deaths, int* __restrict__ cnt) {
  int i = blockIdx.x * blockDim.x + threadIdx.x;
  if (i < 3 * NPTS) deaths[i] = __int_as_float(0x7f800000);  // +inf pad
  if (i < 4) cnt[i] = 0;  // cnt[0..2]=death counters, cnt[3]=done flag
}

__global__ void k_init_cloud(int* __restrict__ comp, ull* __restrict__ best,
                             int* __restrict__ done) {
  int i = blockIdx.x * blockDim.x + threadIdx.x;
  if (i < NPTS) { comp[i] = i; best[i] = KEY_MAX_ULL; }
  if (i == 0) *done = 0;
}

// ------------------------------ prep: norms + f16 cast ----------------------
__global__ __launch_bounds__(256)
void k_prep(const float* __restrict__ x, float* __restrict__ sq,
            f16* __restrict__ hi) {
  const int row = blockIdx.x;
  const int t = threadIdx.x;
  const float4 v = ((const float4*)(x + (size_t)row * DIMF))[t];
  f16x4v h;
  h.x = (f16)v.x; h.y = (f16)v.y; h.z = (f16)v.z; h.w = (f16)v.w;
  ((f16x4v*)(hi + (size_t)row * DIMF))[t] = h;
  float s = v.x * v.x + v.y * v.y + v.z * v.z + v.w * v.w;
  for (int off = 32; off > 0; off >>= 1) s += __shfl_xor(s, off, 64);
  __shared__ float ws[4];
  if ((t & 63) == 0) ws[t >> 6] = s;
  __syncthreads();
  if (t == 0) sq[row] = ws[0] + ws[1] + ws[2] + ws[3];
}

// fp32-path norms (fallback)
__global__ __launch_bounds__(256)
void k_norms(const float* __restrict__ x, float* __restrict__ sq) {
  const int row = blockIdx.x;
  const int t = threadIdx.x;
  const float4 v = ((const float4*)(x + (size_t)row * DIMF))[t];
  float s = v.x * v.x + v.y * v.y + v.z * v.z + v.w * v.w;
  for (int off = 32; off > 0; off >>= 1) s += __shfl_xor(s, off, 64);
  __shared__ float ws[4];
  if ((t & 63) == 0) ws[t >> 6] = s;
  __syncthreads();
  if (t == 0) sq[row] = ws[0] + ws[1] + ws[2] + ws[3];
}

// ------------------------------ fp16 MFMA GEMM + round-1 scan ---------------
// d2[i][j] = max(sq[i]+sq[j]-2*(Hi@Hi^T), 0). K=1024. 128x128 tile, 2x2 wave
// grid, 16x16x32 f16 MFMA. Epilogue also computes per-row min (excl. diag)
// with round-1-prefixed keys and atomicMins into best (comp==identity).
__global__ __launch_bounds__(256)
void k_gemm_f16(const f16* __restrict__ hi, const float* __restrict__ sq,
                float* __restrict__ d2, ull* __restrict__ best) {
  __shared__ u16 smem[8192];  // As 128x32 f16 (8KB) + Bs 128x32 f16 (8KB)
  u16* As = smem;
  u16* Bs = smem + 4096;
  const int t = threadIdx.x;
  const int w = t >> 6, l = t & 63;
  const int wm = w >> 1, wn = w & 1;  // 2x2 wave grid, 64x64 each
  const int ml = l & 15, kq = l >> 4;
  const int i0 = blockIdx.y * 128, j0 = blockIdx.x * 128;

  const int srow = t >> 2, schk = t & 3;
  char* ldsA0 = (char*)As + t * 16;
  char* ldsB0 = (char*)Bs + t * 16;

  f32x4 acc[4][4];
#pragma unroll
  for (int a = 0; a < 4; ++a)
#pragma unroll
    for (int b = 0; b < 4; ++b) acc[a][b] = (f32x4)0.f;

  for (int k0 = 0; k0 < DIMF; k0 += 32) {
    __syncthreads();
    {
      const f16* ga0 = hi + (size_t)(i0 + srow) * DIMF + k0 + schk * 8;
      const f16* ga1 = hi + (size_t)(i0 + srow + 64) * DIMF + k0 + schk * 8;
      const f16* gb0 = hi + (size_t)(j0 + srow) * DIMF + k0 + schk * 8;
      const f16* gb1 = hi + (size_t)(j0 + srow + 64) * DIMF + k0 + schk * 8;
      GLOAD_LDS16(ga0, ldsA0);
      GLOAD_LDS16(ga1, ldsA0 + 4096);
      GLOAD_LDS16(gb0, ldsB0);
      GLOAD_LDS16(gb1, ldsB0 + 4096);
    }
    asm volatile("s_waitcnt vmcnt(0)" ::: "memory");
    __syncthreads();

    const char* Ab = (const char*)As + (wm * 64 + ml) * 64 + kq * 16;
    const char* Bb = (const char*)Bs + (wn * 64 + ml) * 64 + kq * 16;
    f16x8 af[4], bf[4];
#pragma unroll
    for (int mt = 0; mt < 4; ++mt) af[mt] = *(const f16x8*)(Ab + mt * 1024);
#pragma unroll
    for (int nt = 0; nt < 4; ++nt) bf[nt] = *(const f16x8*)(Bb + nt * 1024);
#pragma unroll
    for (int mt = 0; mt < 4; ++mt)
#pragma unroll
      for (int nt = 0; nt < 4; ++nt)
        acc[mt][nt] = __builtin_amdgcn_mfma_f32_16x16x32_f16(
            af[mt], bf[nt], acc[mt][nt], 0, 0, 0);
  }

  // epilogue: C/D layout col=lane&15, row=(lane>>4)*4+reg
  float sr[4][4], sc[4];
#pragma unroll
  for (int mt = 0; mt < 4; ++mt)
#pragma unroll
    for (int r = 0; r < 4; ++r)
      sr[mt][r] = sq[i0 + wm * 64 + mt * 16 + kq * 4 + r];
#pragma unroll
  for (int nt = 0; nt < 4; ++nt) sc[nt] = sq[j0 + wn * 64 + nt * 16 + ml];

  const ull PREF1 = (ull)11 << 60;  // round 1 prefix = 12-1
#pragma unroll
  for (int mt = 0; mt < 4; ++mt) {
#pragma unroll
    for (int r = 0; r < 4; ++r) {
      const int row = i0 + wm * 64 + mt * 16 + kq * 4 + r;
      const float si = sr[mt][r];
      ull kmin = KEY_MAX_ULL;
#pragma unroll
      for (int nt = 0; nt < 4; ++nt) {
        const int col = j0 + wn * 64 + nt * 16 + ml;
        const float v = fmaxf(si + sc[nt] - 2.f * acc[mt][nt][r], 0.f);
        d2[(size_t)row * NPTS + col] = v;
        if (col != row) {
          const ull pair = (row < col) ? (((ull)row << 12) | (unsigned)col)
                                       : (((ull)col << 12) | (unsigned)row);
          const ull key = PREF1 | ((ull)__float_as_uint(v) << 24) | pair;
          kmin = (key < kmin) ? key : kmin;
        }
      }
      // reduce across the 16 lanes sharing this row (xor over ml bits)
#pragma unroll
      for (int m = 1; m <= 8; m <<= 1) {
        const ull o = __shfl_xor(kmin, m, 64);
        kmin = (o < kmin) ? o : kmin;
      }
      if ((l & 15) == 0) atomicMin(best + row, kmin);
    }
  }
}

// ------------------------------ fp32 GEMM fallback --------------------------
#define BM 128
#define BN 128
#define BK 16
__global__ __launch_bounds__(256)
void k_gemm_d2(const float* __restrict__ X, const float* __restrict__ sq,
               float* __restrict__ d2) {
  __shared__ float As[BK][BM];
  __shared__ float Bs[BK][BN];
  const int tid = threadIdx.x;
  const int tx = tid & 15, ty = tid >> 4;
  const int i0 = blockIdx.y * BM, j0 = blockIdx.x * BN;
  float acc[8][8] = {};
  for (int k0 = 0; k0 < DIMF; k0 += BK) {
#pragma unroll
    for (int id = tid; id < 512; id += 256) {
      const int row = id >> 2;
      const int kk = (id & 3) << 2;
      const float4 a = *(const float4*)(X + (size_t)(i0 + row) * DIMF + k0 + kk);
      const float4 b = *(const float4*)(X + (size_t)(j0 + row) * DIMF + k0 + kk);
      As[kk + 0][row] = a.x; As[kk + 1][row] = a.y;
      As[kk + 2][row] = a.z; As[kk + 3][row] = a.w;
      Bs[kk + 0][row] = b.x; Bs[kk + 1][row] = b.y;
      Bs[kk + 2][row] = b.z; Bs[kk + 3][row] = b.w;
    }
    __syncthreads();
#pragma unroll
    for (int kk = 0; kk < BK; ++kk) {
      float a[8], b[8];
#pragma unroll
      for (int m = 0; m < 8; ++m) a[m] = As[kk][ty * 8 + m];
#pragma unroll
      for (int n = 0; n < 8; ++n) b[n] = Bs[kk][tx * 8 + n];
#pragma unroll
      for (int m = 0; m < 8; ++m)
#pragma unroll
        for (int n = 0; n < 8; ++n)
          acc[m][n] = fmaf(a[m], b[n], acc[m][n]);
    }
    __syncthreads();
  }
#pragma unroll
  for (int m = 0; m < 8; ++m) {
    const int i = i0 + ty * 8 + m;
    const float si = sq[i];
    const int j = j0 + tx * 8;
    float4 o0, o1;
    o0.x = fmaxf(si + sq[j + 0] - 2.f * acc[m][0], 0.f);
    o0.y = fmaxf(si + sq[j + 1] - 2.f * acc[m][1], 0.f);
    o0.z = fmaxf(si + sq[j + 2] - 2.f * acc[m][2], 0.f);
    o0.w = fmaxf(si + sq[j + 3] - 2.f * acc[m][3], 0.f);
    o1.x = fmaxf(si + sq[j + 4] - 2.f * acc[m][4], 0.f);
    o1.y = fmaxf(si + sq[j + 5] - 2.f * acc[m][5], 0.f);
    o1.z = fmaxf(si + sq[j + 6] - 2.f * acc[m][6], 0.f);
    o1.w = fmaxf(si + sq[j + 7] - 2.f * acc[m][7], 0.f);
    *(float4*)(d2 + (size_t)i * NPTS + j) = o0;
    *(float4*)(d2 + (size_t)i * NPTS + j + 4) = o1;
  }
}

// ------------------------------ cooperative Boruvka -------------------------
// Grid 1024x256 (4 rows/block scan). best[] pre-filled with round-1 keys by
// the GEMM. Per round: [r>1: scan w/ prefix (12-r) keys], grid.sync, local
// merge in LDS (identical in every block; block 0 records deaths), break when
// one component, grid.sync.
__global__ __launch_bounds__(256, 4)
void k_boruvka(const float* __restrict__ d2, ull* __restrict__ best,
               float* __restrict__ deaths, int* __restrict__ cnt) {
  cg::grid_group grid = cg::this_grid();
  __shared__ int cl[NPTS];  // 16KB: this block's copy of comp
  __shared__ int hk[NPTS];  // 16KB: hook targets
  __shared__ ull red[4];
  __shared__ int redi[4];
  const int t = threadIdx.x;
  const int blk = blockIdx.x;

#pragma unroll
  for (int s = 0; s < 16; ++s) cl[t + s * 256] = t + s * 256;
  __syncthreads();

  for (int r = 1; r <= 12; ++r) {
    const ull want = (ull)(12 - r);
    if (r > 1) {
      // ---- scan: 4 rows per block ----
      const ull pref = want << 60;
      int cj[16];
#pragma unroll
      for (int s = 0; s < 16; ++s) cj[s] = cl[t * 16 + s];
      for (int rr = 0; rr < 4; ++rr) {
        const int i = blk * 4 + rr;
        const int ci = cl[i];
        const float* rowp = d2 + (size_t)i * NPTS;
        ull kmin = KEY_MAX_ULL;
#pragma unroll
        for (int q = 0; q < 4; ++q) {
          const float4 v = ((const float4*)rowp)[t * 4 + q];
          const float vv[4] = {v.x, v.y, v.z, v.w};
#pragma unroll
          for (int u = 0; u < 4; ++u) {
            const int j = t * 16 + q * 4 + u;
            if (cj[q * 4 + u] != ci) {
              const ull pair = (i < j) ? (((ull)i << 12) | (unsigned)j)
                                       : (((ull)j << 12) | (unsigned)i);
              const ull key = pref | ((ull)__float_as_uint(vv[u]) << 24) | pair;
              kmin = (key < kmin) ? key : kmin;
            }
          }
        }
        for (int off = 32; off > 0; off >>= 1) {
          const ull o = __shfl_xor(kmin, off, 64);
          kmin = (o < kmin) ? o : kmin;
        }
        if ((t & 63) == 0) red[t >> 6] = kmin;
        __syncthreads();
        if (t == 0) {
          ull k2 = red[0];
          k2 = (red[1] < k2) ? red[1] : k2;
          k2 = (red[2] < k2) ? red[2] : k2;
          k2 = (red[3] < k2) ? red[3] : k2;
          if (k2 != KEY_MAX_ULL) atomicMin(best + ci, k2);
        }
        __syncthreads();
      }
      __threadfence();
      grid.sync();
    }

    // ---- local merge (identical in every block) ----
    ull bb[16];
#pragma unroll
    for (int s = 0; s < 16; ++s) bb[s] = best[t + s * 256];
#pragma unroll
    for (int s = 0; s < 16; ++s) {
      const int v = t + s * 256;
      int h;
      if ((bb[s] >> 60) == want) {
        const int pair = (int)(bb[s] & 0xFFFFFF);
        const int a = pair >> 12, c2 = pair & 4095;
        const int ra = cl[a], rb = cl[c2];
        h = (ra == v) ? rb : ra;  // other component's root
      } else {
        h = cl[v];  // stale/absent: non-root or no outgoing edge
      }
      hk[v] = h;
    }
    __syncthreads();
    bool win[16];
#pragma unroll
    for (int s = 0; s < 16; ++s) {
      const int v = t + s * 256;
      win[s] = false;
      if ((bb[s] >> 60) == want) {
        const int so = hk[v];
        const bool mut = (hk[so] == v);
        win[s] = mut && (v < so);
        if (!mut || v < so) {  // each MST edge recorded once
          if (blk == 0) {
            const float dd = __uint_as_float((unsigned)((bb[s] >> 24) & 0xFFFFFFFFu));
            deaths[atomicAdd(cnt, 1)] = sqrtf(fmaxf(dd, 1e-12f));
          }
        }
      }
    }
    __syncthreads();
#pragma unroll
    for (int s = 0; s < 16; ++s)
      if (win[s]) hk[t + s * 256] = t + s * 256;  // mutual winner = new root
    __syncthreads();
    for (int it = 0; it < 12; ++it) {
      int w2[16];
#pragma unroll
      for (int s = 0; s < 16; ++s) w2[s] = hk[hk[t + s * 256]];
      __syncthreads();
#pragma unroll
      for (int s = 0; s < 16; ++s) hk[t + s * 256] = w2[s];
      __syncthreads();
    }
    int nroot = 0;
#pragma unroll
    for (int s = 0; s < 16; ++s) {
      const int v = t + s * 256;
      const int rv = hk[v];
      cl[v] = rv;
      nroot += (rv == v);
    }
    for (int off = 32; off > 0; off >>= 1) nroot += __shfl_xor(nroot, off, 64);
    if ((t & 63) == 0) redi[t >> 6] = nroot;
    __syncthreads();
    const int tot = redi[0] + redi[1] + redi[2] + redi[3];
    if (tot == 1) break;  // identical in every block
    __threadfence();
    grid.sync();
  }
}

// -------------------- fallback Boruvka (non-cooperative) --------------------
__global__ __launch_bounds__(256)
void k_scan(const float* __restrict__ d2, const int* __restrict__ comp,
            ull* __restrict__ best, const int* __restrict__ done) {
  if (*done) return;
  const int i = blockIdx.x;
  const int t = threadIdx.x;
  __shared__ ull red[4];
  int cj[16];
  {
    const int4* cp = (const int4*)comp;
    const int4 a0 = cp[t * 4 + 0], a1 = cp[t * 4 + 1];
    const int4 a2 = cp[t * 4 + 2], a3 = cp[t * 4 + 3];
    cj[0] = a0.x;  cj[1] = a0.y;  cj[2] = a0.z;  cj[3] = a0.w;
    cj[4] = a1.x;  cj[5] = a1.y;  cj[6] = a1.z;  cj[7] = a1.w;
    cj[8] = a2.x;  cj[9] = a2.y;  cj[10] = a2.z; cj[11] = a2.w;
    cj[12] = a3.x; cj[13] = a3.y; cj[14] = a3.z; cj[15] = a3.w;
  }
  const int ci = comp[i];
  const float* row = d2 + (size_t)i * NPTS;
  ull kmin = KEY_MAX_ULL;
#pragma unroll
  for (int q = 0; q < 4; ++q) {
    const float4 v = ((const float4*)row)[t * 4 + q];
    const float vv[4] = {v.x, v.y, v.z, v.w};
#pragma unroll
    for (int u = 0; u < 4; ++u) {
      const int j = t * 16 + q * 4 + u;
      if (cj[q * 4 + u] != ci) {
        const ull pair = (i < j) ? (((ull)i << 12) | (unsigned)j)
                                 : (((ull)j << 12) | (unsigned)i);
        const ull key = ((ull)__float_as_uint(vv[u]) << 24) | pair;
        kmin = (key < kmin) ? key : kmin;
      }
    }
  }
  for (int off = 32; off > 0; off >>= 1) {
    const ull o = __shfl_xor(kmin, off, 64);
    kmin = (o < kmin) ? o : kmin;
  }
  if ((t & 63) == 0) red[t >> 6] = kmin;
  __syncthreads();
  if (t == 0) {
    ull k2 = red[0];
    k2 = (red[1] < k2) ? red[1] : k2;
    k2 = (red[2] < k2) ? red[2] : k2;
    k2 = (red[3] < k2) ? red[3] : k2;
    if (k2 != KEY_MAX_ULL) atomicMin(best + ci, k2);
  }
}

__global__ __launch_bounds__(1024)
void k_merge(ull* __restrict__ best, int* __restrict__ comp,
             float* __restrict__ deaths, int* __restrict__ cnt,
             int* __restrict__ done) {
  if (*done) return;
  __shared__ int par[NPTS];
  __shared__ int hk[NPTS];
  __shared__ int redi[16];
  const int t = threadIdx.x;
  ull bb[4];
#pragma unroll
  for (int s = 0; s < 4; ++s) {
    const int v = t + s * 1024;
    par[v] = comp[v];
    bb[s] = best[v];
    best[v] = KEY_MAX_ULL;
  }
  __syncthreads();
#pragma unroll
  for (int s = 0; s < 4; ++s) {
    const int v = t + s * 1024;
    const ull b2 = bb[s];
    int h;
    if (b2 == KEY_MAX_ULL) {
      h = par[v];
    } else {
      const int pair = (int)(b2 & 0xFFFFFF);
      const int a = pair >> 12, c2 = pair & 4095;
      const int ra = par[a], rb = par[c2];
      h = (ra == v) ? rb : ra;
    }
    hk[v] = h;
  }
  __syncthreads();
  bool win[4];
#pragma unroll
  for (int s = 0; s < 4; ++s) {
    const int v = t + s * 1024;
    const ull b2 = bb[s];
    win[s] = false;
    if (b2 != KEY_MAX_ULL) {
      const int so = hk[v];
      const bool mut = (hk[so] == v);
      win[s] = mut && (v < so);
      if (!mut || v < so) {
        const float dd = __uint_as_float((unsigned)(b2 >> 24));
        deaths[atomicAdd(cnt, 1)] = sqrtf(fmaxf(dd, 1e-12f));
      }
    }
  }
  __syncthreads();
#pragma unroll
  for (int s = 0; s < 4; ++s)
    if (win[s]) hk[t + s * 1024] = t + s * 1024;
  __syncthreads();
  for (int it = 0; it < 12; ++it) {
    int w2[4];
#pragma unroll
    for (int s = 0; s < 4; ++s) w2[s] = hk[hk[t + s * 1024]];
    __syncthreads();
#pragma unroll
    for (int s = 0; s < 4; ++s) hk[t + s * 1024] = w2[s];
    __syncthreads();
  }
  int nroot = 0;
#pragma unroll
  for (int s = 0; s < 4; ++s) {
    const int v = t + s * 1024;
    const int rv = hk[v];
    comp[v] = rv;
    nroot += (rv == v);
  }
  for (int off = 32; off > 0; off >>= 1) nroot += __shfl_xor(nroot, off, 64);
  if ((t & 63) == 0) redi[t >> 6] = nroot;
  __syncthreads();
  if (t == 0) {
    int tot = 0;
    for (int q = 0; q < 16; ++q) tot += redi[q];
    if (tot == 1) *done = 1;
  }
}

// ------------------------------ sort (bitonic, 4096 in LDS) -----------------
__global__ __launch_bounds__(1024)
void k_sort(float* __restrict__ deaths) {
  __shared__ float s[NPTS];
  float* g = deaths + (size_t)blockIdx.x * NPTS;
  const int t = threadIdx.x;
#pragma unroll
  for (int q = 0; q < 4; ++q) s[t + q * 1024] = g[t + q * 1024];
  for (int k = 2; k <= NPTS; k <<= 1) {
    for (int j = k >> 1; j > 0; j >>= 1) {
      __syncthreads();
#pragma unroll
      for (int q = 0; q < 4; ++q) {
        const int i = t + q * 1024;
        const int ixj = i ^ j;
        if (ixj > i) {
          const float a = s[i], b = s[ixj];
          const bool up = ((i & k) == 0);
          if ((a > b) == up) { s[i] = b; s[ixj] = a; }
        }
      }
    }
  }
  __syncthreads();
#pragma unroll
  for (int q = 0; q < 4; ++q) g[t + q * 1024] = s[t + q * 1024];
}

// ------------------------------ final loss ----------------------------------
__global__ __launch_bounds__(1024)
void k_final(const float* __restrict__ deaths, float* __restrict__ out) {
  const float* a = deaths;
  const float* p = deaths + NPTS;
  const float* n = deaths + 2 * NPTS;
  const int t = threadIdx.x;
  float s1 = 0.f, s2 = 0.f;
  for (int i = t; i < NPTS - 1; i += 1024) {
    s1 += fabsf(a[i] - p[i]);
    s2 += fabsf(a[i] - n[i]);
  }
  for (int off = 32; off > 0; off >>= 1) {
    s1 += __shfl_xor(s1, off, 64);
    s2 += __shfl_xor(s2, off, 64);
  }
  __shared__ float r1[16], r2[16];
  if ((t & 63) == 0) { r1[t >> 6] = s1; r2[t >> 6] = s2; }
  __syncthreads();
  if (t == 0) {
    float t1 = 0.f, t2 = 0.f;
    for (int q = 0; q < 16; ++q) { t1 += r1[q]; t2 += r2[q]; }
    out[0] = fmaxf(t1 - t2 + 1.0f, 0.0f);
  }
}

__global__ void k_fail(float* out) { if (threadIdx.x == 0) out[0] = 0.f; }

// ------------------------------ launch --------------------------------------
extern "C" void kernel_launch(void* const* d_in, const int* in_sizes, int n_in,
                              void* d_out, int out_size, void* d_ws, size_t ws_size,
                              hipStream_t stream) {
  const float* xs[3] = {(const float*)d_in[0], (const float*)d_in[1],
                        (const float*)d_in[2]};
  char* ws = (char*)d_ws;
  const size_t d2_bytes = (size_t)NPTS * NPTS * 4;   // 64MB
  const size_t hi_bytes = (size_t)NPTS * DIMF * 2;   // 8MB
  const size_t small = NPTS * 4 /*sq*/ + NPTS * 4 /*comp*/ + NPTS * 8 /*best*/ +
                       3 * NPTS * 4 /*deaths*/ + 256;
  const size_t need_fp32 = d2_bytes + small;
  const size_t need_f16 = d2_bytes + hi_bytes + small;
  if (ws_size < need_fp32) {
    k_fail<<<1, 64, 0, stream>>>((float*)d_out);
    return;
  }
  const bool use_f16 = (ws_size >= need_f16);
  const size_t tail0 = use_f16 ? (d2_bytes + hi_bytes) : d2_bytes;

  float* d2 = (float*)ws;
  f16* hi = (f16*)(ws + d2_bytes);
  float* sq = (float*)(ws + tail0);
  int* comp = (int*)(ws + tail0 + NPTS * 4);
  ull* best = (ull*)(ws + tail0 + NPTS * 8);
  float* deaths = (float*)(ws + tail0 + NPTS * 16);
  int* cnt = (int*)(ws + tail0 + NPTS * 16 + 3 * NPTS * 4);
  int* done = cnt + 3;

  k_init_global<<<48, 256, 0, stream>>>(deaths, cnt);
  for (int c = 0; c < 3; ++c) {
    float* dth = deaths + c * NPTS;
    int* cn = cnt + c;
    if (use_f16) {
      k_prep<<<NPTS, 256, 0, stream>>>(xs[c], sq, hi);
      k_init_cloud<<<16, 256, 0, stream>>>(comp, best, done);
      k_gemm_f16<<<dim3(NPTS / 128, NPTS / 128), 256, 0, stream>>>(hi, sq, d2, best);
      void* args[] = {(void*)&d2, (void*)&best, (void*)&dth, (void*)&cn};
      hipError_t e = hipLaunchCooperativeKernel((void*)k_boruvka, dim3(1024),
                                                dim3(256), args, 0, stream);
      if (e != hipSuccess) {
        // fallback: prefix-tagged best from GEMM is incompatible with the
        // plain scan/merge; reset and run the proven non-coop loop.
        k_init_cloud<<<16, 256, 0, stream>>>(comp, best, done);
        for (int r = 0; r < 12; ++r) {
          k_scan<<<NPTS, 256, 0, stream>>>(d2, comp, best, done);
          k_merge<<<1, 1024, 0, stream>>>(best, comp, dth, cn, done);
        }
      }
    } else {
      k_norms<<<NPTS, 256, 0, stream>>>(xs[c], sq);
      k_init_cloud<<<16, 256, 0, stream>>>(comp, best, done);
      k_gemm_d2<<<dim3(NPTS / BN, NPTS / BM), 256, 0, stream>>>(xs[c], sq, d2);
      for (int r = 0; r < 12; ++r) {
        k_scan<<<NPTS, 256, 0, stream>>>(d2, comp, best, done);
        k_merge<<<1, 1024, 0, stream>>>(best, comp, dth, cn, done);
      }
    }
  }
  k_sort<<<3, 1024, 0, stream>>>(deaths);
  k_final<<<1, 1024, 0, stream>>>(deaths, (float*)d_out);
}

// Round 6
// 3622.215 us; speedup vs baseline: 1.1993x; 1.1993x over previous
//
#include <hip/hip_runtime.h>
#include <stdint.h>

// ---------------------------------------------------------------------------
// TopologicalContrastiveLoss: H0 persistence (MST edge weights) of 3 point
// clouds -> 1-Wasserstein between sorted death vectors -> hinge loss.
//
// R6: R4 skeleton (783us proven) +
//  (a) round-0 scan fused into the GEMM epilogue (R5-verified, plain keys)
//  (b) rounds 1..11 as ticket-fused k_round: R4's exact scan (1 row/block,
//      no LDS) + last-block inline merge (hk[] 16KB LDS only; comp read from
//      L2; atomicExch read+reset of best for intra-kernel coherence)
//  (c) early-exit pointer jumping in merges
//  NO grid.sync anywhere (R5 lesson: coop sync >> kernel launch cost).
// ---------------------------------------------------------------------------

#define NPTS 4096
#define DIMF 1024
typedef unsigned short u16;
typedef _Float16 f16;
typedef unsigned long long ull;
static const ull KEY_MAX_ULL = ~0ull;

typedef f16 f16x8 __attribute__((ext_vector_type(8)));
typedef f16 f16x4v __attribute__((ext_vector_type(4)));
typedef float f32x4 __attribute__((ext_vector_type(4)));

#define GLOAD_LDS16(g, l)                                                      \
  __builtin_amdgcn_global_load_lds(                                            \
      (const __attribute__((address_space(1))) void*)(g),                      \
      (__attribute__((address_space(3))) void*)(l), 16, 0, 0)

// ------------------------------ init ---------------------------------------
__global__ void k_init_global(float* __restrict__ deaths, int* __restrict__ cnt) {
  int i = blockIdx.x * blockDim.x + threadIdx.x;
  if (i < 3 * NPTS) deaths[i] = __int_as_float(0x7f800000);  // +inf pad
  if (i < 4) cnt[i] = 0;  // cnt[0..2]=death counters, cnt[3]=done flag
}

// fallback-path per-cloud init
__global__ void k_init_cloud(int* __restrict__ comp, ull* __restrict__ best,
                             int* __restrict__ done) {
  int i = blockIdx.x * blockDim.x + threadIdx.x;
  if (i < NPTS) { comp[i] = i; best[i] = KEY_MAX_ULL; }
  if (i == 0) *done = 0;
}

// ------------------- prep: norms + f16 cast + per-cloud init ----------------
__global__ __launch_bounds__(256)
void k_prep(const float* __restrict__ x, float* __restrict__ sq,
            f16* __restrict__ hi, int* __restrict__ comp,
            ull* __restrict__ best, int* __restrict__ done,
            int* __restrict__ tickets) {
  const int row = blockIdx.x;
  const int t = threadIdx.x;
  const float4 v = ((const float4*)(x + (size_t)row * DIMF))[t];
  f16x4v h;
  h.x = (f16)v.x; h.y = (f16)v.y; h.z = (f16)v.z; h.w = (f16)v.w;
  ((f16x4v*)(hi + (size_t)row * DIMF))[t] = h;
  float s = v.x * v.x + v.y * v.y + v.z * v.z + v.w * v.w;
  for (int off = 32; off > 0; off >>= 1) s += __shfl_xor(s, off, 64);
  __shared__ float ws[4];
  if ((t & 63) == 0) ws[t >> 6] = s;
  // fused per-cloud init (one element per (block,thread) pair for blocks 0..15)
  if (row < 16) {
    const int i = row * 256 + t;
    comp[i] = i;
    best[i] = KEY_MAX_ULL;
    if (i < 12) tickets[i] = 0;
    if (i == 0) *done = 0;
  }
  __syncthreads();
  if (t == 0) sq[row] = ws[0] + ws[1] + ws[2] + ws[3];
}

// fp32-path norms (fallback)
__global__ __launch_bounds__(256)
void k_norms(const float* __restrict__ x, float* __restrict__ sq) {
  const int row = blockIdx.x;
  const int t = threadIdx.x;
  const float4 v = ((const float4*)(x + (size_t)row * DIMF))[t];
  float s = v.x * v.x + v.y * v.y + v.z * v.z + v.w * v.w;
  for (int off = 32; off > 0; off >>= 1) s += __shfl_xor(s, off, 64);
  __shared__ float ws[4];
  if ((t & 63) == 0) ws[t >> 6] = s;
  __syncthreads();
  if (t == 0) sq[row] = ws[0] + ws[1] + ws[2] + ws[3];
}

// ------------------------------ fp16 MFMA GEMM + round-0 scan ---------------
// d2[i][j] = max(sq[i]+sq[j]-2*(Hi@Hi^T), 0). K=1024. Epilogue also computes
// per-row min (excl. diag) with PLAIN keys and atomicMins into best
// (comp == identity at round 0, so best is indexed by row).
__global__ __launch_bounds__(256)
void k_gemm_f16(const f16* __restrict__ hi, const float* __restrict__ sq,
                float* __restrict__ d2, ull* __restrict__ best) {
  __shared__ u16 smem[8192];  // As 128x32 f16 (8KB) + Bs 128x32 f16 (8KB)
  u16* As = smem;
  u16* Bs = smem + 4096;
  const int t = threadIdx.x;
  const int w = t >> 6, l = t & 63;
  const int wm = w >> 1, wn = w & 1;  // 2x2 wave grid, 64x64 each
  const int ml = l & 15, kq = l >> 4;
  const int i0 = blockIdx.y * 128, j0 = blockIdx.x * 128;

  const int srow = t >> 2, schk = t & 3;
  char* ldsA0 = (char*)As + t * 16;
  char* ldsB0 = (char*)Bs + t * 16;

  f32x4 acc[4][4];
#pragma unroll
  for (int a = 0; a < 4; ++a)
#pragma unroll
    for (int b = 0; b < 4; ++b) acc[a][b] = (f32x4)0.f;

  for (int k0 = 0; k0 < DIMF; k0 += 32) {
    __syncthreads();
    {
      const f16* ga0 = hi + (size_t)(i0 + srow) * DIMF + k0 + schk * 8;
      const f16* ga1 = hi + (size_t)(i0 + srow + 64) * DIMF + k0 + schk * 8;
      const f16* gb0 = hi + (size_t)(j0 + srow) * DIMF + k0 + schk * 8;
      const f16* gb1 = hi + (size_t)(j0 + srow + 64) * DIMF + k0 + schk * 8;
      GLOAD_LDS16(ga0, ldsA0);
      GLOAD_LDS16(ga1, ldsA0 + 4096);
      GLOAD_LDS16(gb0, ldsB0);
      GLOAD_LDS16(gb1, ldsB0 + 4096);
    }
    asm volatile("s_waitcnt vmcnt(0)" ::: "memory");
    __syncthreads();

    const char* Ab = (const char*)As + (wm * 64 + ml) * 64 + kq * 16;
    const char* Bb = (const char*)Bs + (wn * 64 + ml) * 64 + kq * 16;
    f16x8 af[4], bf[4];
#pragma unroll
    for (int mt = 0; mt < 4; ++mt) af[mt] = *(const f16x8*)(Ab + mt * 1024);
#pragma unroll
    for (int nt = 0; nt < 4; ++nt) bf[nt] = *(const f16x8*)(Bb + nt * 1024);
#pragma unroll
    for (int mt = 0; mt < 4; ++mt)
#pragma unroll
      for (int nt = 0; nt < 4; ++nt)
        acc[mt][nt] = __builtin_amdgcn_mfma_f32_16x16x32_f16(
            af[mt], bf[nt], acc[mt][nt], 0, 0, 0);
  }

  // epilogue: C/D layout col=lane&15, row=(lane>>4)*4+reg
  float sr[4][4], sc[4];
#pragma unroll
  for (int mt = 0; mt < 4; ++mt)
#pragma unroll
    for (int r = 0; r < 4; ++r)
      sr[mt][r] = sq[i0 + wm * 64 + mt * 16 + kq * 4 + r];
#pragma unroll
  for (int nt = 0; nt < 4; ++nt) sc[nt] = sq[j0 + wn * 64 + nt * 16 + ml];

#pragma unroll
  for (int mt = 0; mt < 4; ++mt) {
#pragma unroll
    for (int r = 0; r < 4; ++r) {
      const int row = i0 + wm * 64 + mt * 16 + kq * 4 + r;
      const float si = sr[mt][r];
      ull kmin = KEY_MAX_ULL;
#pragma unroll
      for (int nt = 0; nt < 4; ++nt) {
        const int col = j0 + wn * 64 + nt * 16 + ml;
        const float v = fmaxf(si + sc[nt] - 2.f * acc[mt][nt][r], 0.f);
        d2[(size_t)row * NPTS + col] = v;
        if (col != row) {
          const ull pair = (row < col) ? (((ull)row << 12) | (unsigned)col)
                                       : (((ull)col << 12) | (unsigned)row);
          const ull key = ((ull)__float_as_uint(v) << 24) | pair;
          kmin = (key < kmin) ? key : kmin;
        }
      }
      // reduce across the 16 lanes sharing this row
#pragma unroll
      for (int m = 1; m <= 8; m <<= 1) {
        const ull o = __shfl_xor(kmin, m, 64);
        kmin = (o < kmin) ? o : kmin;
      }
      if ((l & 15) == 0) atomicMin(best + row, kmin);
    }
  }
}

// ------------------------------ fp32 GEMM fallback --------------------------
#define BM 128
#define BN 128
#define BK 16
__global__ __launch_bounds__(256)
void k_gemm_d2(const float* __restrict__ X, const float* __restrict__ sq,
               float* __restrict__ d2) {
  __shared__ float As[BK][BM];
  __shared__ float Bs[BK][BN];
  const int tid = threadIdx.x;
  const int tx = tid & 15, ty = tid >> 4;
  const int i0 = blockIdx.y * BM, j0 = blockIdx.x * BN;
  float acc[8][8] = {};
  for (int k0 = 0; k0 < DIMF; k0 += BK) {
#pragma unroll
    for (int id = tid; id < 512; id += 256) {
      const int row = id >> 2;
      const int kk = (id & 3) << 2;
      const float4 a = *(const float4*)(X + (size_t)(i0 + row) * DIMF + k0 + kk);
      const float4 b = *(const float4*)(X + (size_t)(j0 + row) * DIMF + k0 + kk);
      As[kk + 0][row] = a.x; As[kk + 1][row] = a.y;
      As[kk + 2][row] = a.z; As[kk + 3][row] = a.w;
      Bs[kk + 0][row] = b.x; Bs[kk + 1][row] = b.y;
      Bs[kk + 2][row] = b.z; Bs[kk + 3][row] = b.w;
    }
    __syncthreads();
#pragma unroll
    for (int kk = 0; kk < BK; ++kk) {
      float a[8], b[8];
#pragma unroll
      for (int m = 0; m < 8; ++m) a[m] = As[kk][ty * 8 + m];
#pragma unroll
      for (int n = 0; n < 8; ++n) b[n] = Bs[kk][tx * 8 + n];
#pragma unroll
      for (int m = 0; m < 8; ++m)
#pragma unroll
        for (int n = 0; n < 8; ++n)
          acc[m][n] = fmaf(a[m], b[n], acc[m][n]);
    }
    __syncthreads();
  }
#pragma unroll
  for (int m = 0; m < 8; ++m) {
    const int i = i0 + ty * 8 + m;
    const float si = sq[i];
    const int j = j0 + tx * 8;
    float4 o0, o1;
    o0.x = fmaxf(si + sq[j + 0] - 2.f * acc[m][0], 0.f);
    o0.y = fmaxf(si + sq[j + 1] - 2.f * acc[m][1], 0.f);
    o0.z = fmaxf(si + sq[j + 2] - 2.f * acc[m][2], 0.f);
    o0.w = fmaxf(si + sq[j + 3] - 2.f * acc[m][3], 0.f);
    o1.x = fmaxf(si + sq[j + 4] - 2.f * acc[m][4], 0.f);
    o1.y = fmaxf(si + sq[j + 5] - 2.f * acc[m][5], 0.f);
    o1.z = fmaxf(si + sq[j + 6] - 2.f * acc[m][6], 0.f);
    o1.w = fmaxf(si + sq[j + 7] - 2.f * acc[m][7], 0.f);
    *(float4*)(d2 + (size_t)i * NPTS + j) = o0;
    *(float4*)(d2 + (size_t)i * NPTS + j + 4) = o1;
  }
}

// ------------------------------ standalone scan (fallback) ------------------
__global__ __launch_bounds__(256)
void k_scan(const float* __restrict__ d2, const int* __restrict__ comp,
            ull* __restrict__ best, const int* __restrict__ done) {
  if (*done) return;
  const int i = blockIdx.x;
  const int t = threadIdx.x;
  __shared__ ull red[4];
  int cj[16];
  {
    const int4* cp = (const int4*)comp;
    const int4 a0 = cp[t * 4 + 0], a1 = cp[t * 4 + 1];
    const int4 a2 = cp[t * 4 + 2], a3 = cp[t * 4 + 3];
    cj[0] = a0.x;  cj[1] = a0.y;  cj[2] = a0.z;  cj[3] = a0.w;
    cj[4] = a1.x;  cj[5] = a1.y;  cj[6] = a1.z;  cj[7] = a1.w;
    cj[8] = a2.x;  cj[9] = a2.y;  cj[10] = a2.z; cj[11] = a2.w;
    cj[12] = a3.x; cj[13] = a3.y; cj[14] = a3.z; cj[15] = a3.w;
  }
  const int ci = comp[i];
  const float* row = d2 + (size_t)i * NPTS;
  ull kmin = KEY_MAX_ULL;
#pragma unroll
  for (int q = 0; q < 4; ++q) {
    const float4 v = ((const float4*)row)[t * 4 + q];
    const float vv[4] = {v.x, v.y, v.z, v.w};
#pragma unroll
    for (int u = 0; u < 4; ++u) {
      const int j = t * 16 + q * 4 + u;
      if (cj[q * 4 + u] != ci) {
        const ull pair = (i < j) ? (((ull)i << 12) | (unsigned)j)
                                 : (((ull)j << 12) | (unsigned)i);
        const ull key = ((ull)__float_as_uint(vv[u]) << 24) | pair;
        kmin = (key < kmin) ? key : kmin;
      }
    }
  }
  for (int off = 32; off > 0; off >>= 1) {
    const ull o = __shfl_xor(kmin, off, 64);
    kmin = (o < kmin) ? o : kmin;
  }
  if ((t & 63) == 0) red[t >> 6] = kmin;
  __syncthreads();
  if (t == 0) {
    ull k2 = red[0];
    k2 = (red[1] < k2) ? red[1] : k2;
    k2 = (red[2] < k2) ? red[2] : k2;
    k2 = (red[3] < k2) ? red[3] : k2;
    if (k2 != KEY_MAX_ULL) atomicMin(best + ci, k2);
  }
}

// ------------------------------ standalone merge ----------------------------
// Used for round 0 (after GEMM-fused scan) and the fp32 fallback path.
__global__ __launch_bounds__(1024)
void k_merge(ull* __restrict__ best, int* __restrict__ comp,
             float* __restrict__ deaths, int* __restrict__ cnt,
             int* __restrict__ done) {
  if (*done) return;
  __shared__ int par[NPTS];
  __shared__ int hk[NPTS];
  __shared__ int redi[16];
  __shared__ int chg;
  const int t = threadIdx.x;
  ull bb[4];
#pragma unroll
  for (int s = 0; s < 4; ++s) {
    const int v = t + s * 1024;
    par[v] = comp[v];
    bb[s] = best[v];
    best[v] = KEY_MAX_ULL;
  }
  __syncthreads();
#pragma unroll
  for (int s = 0; s < 4; ++s) {
    const int v = t + s * 1024;
    const ull b2 = bb[s];
    int h;
    if (b2 == KEY_MAX_ULL) {
      h = par[v];
    } else {
      const int pair = (int)(b2 & 0xFFFFFF);
      const int a = pair >> 12, c2 = pair & 4095;
      const int ra = par[a], rb = par[c2];
      h = (ra == v) ? rb : ra;
    }
    hk[v] = h;
  }
  __syncthreads();
  bool win[4];
#pragma unroll
  for (int s = 0; s < 4; ++s) {
    const int v = t + s * 1024;
    const ull b2 = bb[s];
    win[s] = false;
    if (b2 != KEY_MAX_ULL) {
      const int so = hk[v];
      const bool mut = (hk[so] == v);
      win[s] = mut && (v < so);
      if (!mut || v < so) {
        const float dd = __uint_as_float((unsigned)(b2 >> 24));
        deaths[atomicAdd(cnt, 1)] = sqrtf(fmaxf(dd, 1e-12f));
      }
    }
  }
  if (t == 0) chg = 0;
  __syncthreads();
#pragma unroll
  for (int s = 0; s < 4; ++s)
    if (win[s]) hk[t + s * 1024] = t + s * 1024;
  __syncthreads();
  for (int it = 0; it < 12; ++it) {
    int w2[4]; int ch = 0;
#pragma unroll
    for (int s = 0; s < 4; ++s) {
      const int v = t + s * 1024;
      w2[s] = hk[hk[v]];
      ch |= (w2[s] != hk[v]);
    }
    __syncthreads();
#pragma unroll
    for (int s = 0; s < 4; ++s) hk[t + s * 1024] = w2[s];
    if (ch) chg = 1;
    __syncthreads();
    const int any = chg;
    __syncthreads();
    if (t == 0) chg = 0;
    if (!any) break;
  }
  int nroot = 0;
#pragma unroll
  for (int s = 0; s < 4; ++s) {
    const int v = t + s * 1024;
    const int rv = hk[v];
    comp[v] = rv;
    nroot += (rv == v);
  }
  for (int off = 32; off > 0; off >>= 1) nroot += __shfl_xor(nroot, off, 64);
  if ((t & 63) == 0) redi[t >> 6] = nroot;
  __syncthreads();
  if (t == 0) {
    int tot = 0;
    for (int q = 0; q < 16; ++q) tot += redi[q];
    if (tot == 1) *done = 1;
  }
}

// ------------------------------ ticket-fused round --------------------------
// 4096 blocks x 256: R4's exact scan (1 row/block, register labels), then the
// last block (ticket) performs the merge inline: best via atomicExch (device
// coherent read+reset), comp read from global (L2-hot, unmodified), hk in
// 16KB LDS, early-exit pointer jumping, comp writeback, done flag.
__global__ __launch_bounds__(256)
void k_round(const float* __restrict__ d2, int* __restrict__ comp,
             ull* __restrict__ best, float* __restrict__ deaths,
             int* __restrict__ cnt, int* __restrict__ done,
             int* __restrict__ ticket) {
  if (*done) return;
  const int i = blockIdx.x;
  const int t = threadIdx.x;
  __shared__ ull red[4];
  __shared__ int hk[NPTS];  // 16KB (merge phase, last block only)
  __shared__ int redi[4];
  __shared__ int amlast;
  __shared__ int chg;

  // ---- scan row i (identical to k_scan) ----
  int cj[16];
  {
    const int4* cp = (const int4*)comp;
    const int4 a0 = cp[t * 4 + 0], a1 = cp[t * 4 + 1];
    const int4 a2 = cp[t * 4 + 2], a3 = cp[t * 4 + 3];
    cj[0] = a0.x;  cj[1] = a0.y;  cj[2] = a0.z;  cj[3] = a0.w;
    cj[4] = a1.x;  cj[5] = a1.y;  cj[6] = a1.z;  cj[7] = a1.w;
    cj[8] = a2.x;  cj[9] = a2.y;  cj[10] = a2.z; cj[11] = a2.w;
    cj[12] = a3.x; cj[13] = a3.y; cj[14] = a3.z; cj[15] = a3.w;
  }
  const int ci = comp[i];
  {
    const float* row = d2 + (size_t)i * NPTS;
    ull kmin = KEY_MAX_ULL;
#pragma unroll
    for (int q = 0; q < 4; ++q) {
      const float4 v = ((const float4*)row)[t * 4 + q];
      const float vv[4] = {v.x, v.y, v.z, v.w};
#pragma unroll
      for (int u = 0; u < 4; ++u) {
        const int j = t * 16 + q * 4 + u;
        if (cj[q * 4 + u] != ci) {
          const ull pair = (i < j) ? (((ull)i << 12) | (unsigned)j)
                                   : (((ull)j << 12) | (unsigned)i);
          const ull key = ((ull)__float_as_uint(vv[u]) << 24) | pair;
          kmin = (key < kmin) ? key : kmin;
        }
      }
    }
    for (int off = 32; off > 0; off >>= 1) {
      const ull o = __shfl_xor(kmin, off, 64);
      kmin = (o < kmin) ? o : kmin;
    }
    if ((t & 63) == 0) red[t >> 6] = kmin;
    __syncthreads();
    if (t == 0) {
      ull k2 = red[0];
      k2 = (red[1] < k2) ? red[1] : k2;
      k2 = (red[2] < k2) ? red[2] : k2;
      k2 = (red[3] < k2) ? red[3] : k2;
      if (k2 != KEY_MAX_ULL) atomicMin(best + ci, k2);
    }
  }

  // ---- last-block ticket (R3-proven pattern) ----
  __threadfence();
  if (t == 0) amlast = (atomicAdd(ticket, 1) == NPTS - 1);
  __syncthreads();
  if (!amlast) return;
  __threadfence();

  // ---- inline merge (256 threads, 16 items each) ----
  ull bb[16];
#pragma unroll
  for (int s = 0; s < 16; ++s)
    bb[s] = atomicExch(best + (t + s * 256), KEY_MAX_ULL);
#pragma unroll
  for (int s = 0; s < 16; ++s) {
    const int v = t + s * 256;
    int h;
    if (bb[s] == KEY_MAX_ULL) {
      h = comp[v];  // non-root (or lone root): its root / self
    } else {
      const int pair = (int)(bb[s] & 0xFFFFFF);
      const int a = pair >> 12, c2 = pair & 4095;
      const int ra = comp[a], rb = comp[c2];
      h = (ra == v) ? rb : ra;  // other component's root
    }
    hk[v] = h;
  }
  __syncthreads();
  bool win[16];
#pragma unroll
  for (int s = 0; s < 16; ++s) {
    const int v = t + s * 256;
    win[s] = false;
    if (bb[s] != KEY_MAX_ULL) {
      const int so = hk[v];
      const bool mut = (hk[so] == v);
      win[s] = mut && (v < so);
      if (!mut || v < so) {  // each MST edge recorded once
        const float dd = __uint_as_float((unsigned)(bb[s] >> 24));
        deaths[atomicAdd(cnt, 1)] = sqrtf(fmaxf(dd, 1e-12f));
      }
    }
  }
  if (t == 0) chg = 0;
  __syncthreads();
#pragma unroll
  for (int s = 0; s < 16; ++s)
    if (win[s]) hk[t + s * 256] = t + s * 256;  // mutual winner = new root
  __syncthreads();
  for (int it = 0; it < 12; ++it) {
    int w2[16]; int ch = 0;
#pragma unroll
    for (int s = 0; s < 16; ++s) {
      const int v = t + s * 256;
      w2[s] = hk[hk[v]];
      ch |= (w2[s] != hk[v]);
    }
    __syncthreads();
#pragma unroll
    for (int s = 0; s < 16; ++s) hk[t + s * 256] = w2[s];
    if (ch) chg = 1;
    __syncthreads();
    const int any = chg;
    __syncthreads();
    if (t == 0) chg = 0;
    if (!any) break;
  }
  int nroot = 0;
#pragma unroll
  for (int s = 0; s < 16; ++s) {
    const int v = t + s * 256;
    const int rv = hk[v];
    comp[v] = rv;
    nroot += (rv == v);
  }
  for (int off = 32; off > 0; off >>= 1) nroot += __shfl_xor(nroot, off, 64);
  if ((t & 63) == 0) redi[t >> 6] = nroot;
  __syncthreads();
  if (t == 0) {
    const int tot = redi[0] + redi[1] + redi[2] + redi[3];
    if (tot == 1) *done = 1;
  }
}

// ------------------------------ sort (bitonic, 4096 in LDS) -----------------
__global__ __launch_bounds__(1024)
void k_sort(float* __restrict__ deaths) {
  __shared__ float s[NPTS];
  float* g = deaths + (size_t)blockIdx.x * NPTS;
  const int t = threadIdx.x;
#pragma unroll
  for (int q = 0; q < 4; ++q) s[t + q * 1024] = g[t + q * 1024];
  for (int k = 2; k <= NPTS; k <<= 1) {
    for (int j = k >> 1; j > 0; j >>= 1) {
      __syncthreads();
#pragma unroll
      for (int q = 0; q < 4; ++q) {
        const int i = t + q * 1024;
        const int ixj = i ^ j;
        if (ixj > i) {
          const float a = s[i], b = s[ixj];
          const bool up = ((i & k) == 0);
          if ((a > b) == up) { s[i] = b; s[ixj] = a; }
        }
      }
    }
  }
  __syncthreads();
#pragma unroll
  for (int q = 0; q < 4; ++q) g[t + q * 1024] = s[t + q * 1024];
}

// ------------------------------ final loss ----------------------------------
__global__ __launch_bounds__(1024)
void k_final(const float* __restrict__ deaths, float* __restrict__ out) {
  const float* a = deaths;
  const float* p = deaths + NPTS;
  const float* n = deaths + 2 * NPTS;
  const int t = threadIdx.x;
  float s1 = 0.f, s2 = 0.f;
  for (int i = t; i < NPTS - 1; i += 1024) {
    s1 += fabsf(a[i] - p[i]);
    s2 += fabsf(a[i] - n[i]);
  }
  for (int off = 32; off > 0; off >>= 1) {
    s1 += __shfl_xor(s1, off, 64);
    s2 += __shfl_xor(s2, off, 64);
  }
  __shared__ float r1[16], r2[16];
  if ((t & 63) == 0) { r1[t >> 6] = s1; r2[t >> 6] = s2; }
  __syncthreads();
  if (t == 0) {
    float t1 = 0.f, t2 = 0.f;
    for (int q = 0; q < 16; ++q) { t1 += r1[q]; t2 += r2[q]; }
    out[0] = fmaxf(t1 - t2 + 1.0f, 0.0f);
  }
}

__global__ void k_fail(float* out) { if (threadIdx.x == 0) out[0] = 0.f; }

// ------------------------------ launch --------------------------------------
extern "C" void kernel_launch(void* const* d_in, const int* in_sizes, int n_in,
                              void* d_out, int out_size, void* d_ws, size_t ws_size,
                              hipStream_t stream) {
  const float* xs[3] = {(const float*)d_in[0], (const float*)d_in[1],
                        (const float*)d_in[2]};
  char* ws = (char*)d_ws;
  const size_t d2_bytes = (size_t)NPTS * NPTS * 4;   // 64MB
  const size_t hi_bytes = (size_t)NPTS * DIMF * 2;   // 8MB
  const size_t small = NPTS * 4 /*sq*/ + NPTS * 4 /*comp*/ + NPTS * 8 /*best*/ +
                       3 * NPTS * 4 /*deaths*/ + 256;
  const size_t need_fp32 = d2_bytes + small;
  const size_t need_f16 = d2_bytes + hi_bytes + small;
  if (ws_size < need_fp32) {
    k_fail<<<1, 64, 0, stream>>>((float*)d_out);
    return;
  }
  const bool use_f16 = (ws_size >= need_f16);
  const size_t tail0 = use_f16 ? (d2_bytes + hi_bytes) : d2_bytes;

  float* d2 = (float*)ws;
  f16* hi = (f16*)(ws + d2_bytes);
  float* sq = (float*)(ws + tail0);
  int* comp = (int*)(ws + tail0 + NPTS * 4);
  ull* best = (ull*)(ws + tail0 + NPTS * 8);
  float* deaths = (float*)(ws + tail0 + NPTS * 16);
  int* cnt = (int*)(ws + tail0 + NPTS * 16 + 3 * NPTS * 4);
  int* done = cnt + 3;
  int* tickets = cnt + 4;  // 12 ints

  k_init_global<<<48, 256, 0, stream>>>(deaths, cnt);
  for (int c = 0; c < 3; ++c) {
    float* dth = deaths + c * NPTS;
    int* cn = cnt + c;
    if (use_f16) {
      k_prep<<<NPTS, 256, 0, stream>>>(xs[c], sq, hi, comp, best, done, tickets);
      k_gemm_f16<<<dim3(NPTS / 128, NPTS / 128), 256, 0, stream>>>(hi, sq, d2,
                                                                   best);
      k_merge<<<1, 1024, 0, stream>>>(best, comp, dth, cn, done);  // round 0
      for (int r = 1; r < 12; ++r) {
        k_round<<<NPTS, 256, 0, stream>>>(d2, comp, best, dth, cn, done,
                                          tickets + r);
      }
    } else {
      k_norms<<<NPTS, 256, 0, stream>>>(xs[c], sq);
      k_init_cloud<<<16, 256, 0, stream>>>(comp, best, done);
      k_gemm_d2<<<dim3(NPTS / BN, NPTS / BM), 256, 0, stream>>>(xs[c], sq, d2);
      for (int r = 0; r < 12; ++r) {
        k_scan<<<NPTS, 256, 0, stream>>>(d2, comp, best, done);
        k_merge<<<1, 1024, 0, stream>>>(best, comp, dth, cn, done);
      }
    }
  }
  k_sort<<<3, 1024, 0, stream>>>(deaths);
  k_final<<<1, 1024, 0, stream>>>(deaths, (float*)d_out);
}

// Round 7
// 667.054 us; speedup vs baseline: 6.5126x; 5.4302x over previous
//
#include <hip/hip_runtime.h>
#include <stdint.h>

// ---------------------------------------------------------------------------
// TopologicalContrastiveLoss: H0 persistence (MST edge weights) of 3 point
// clouds -> 1-Wasserstein between sorted death vectors -> hinge loss.
//
// R7: R4 fence-free kernels + structural round reduction:
//  (a) round-0 scan fused into GEMM epilogue (verified R5/R6, free)
//  (b) exactly 3 (scan,merge) pairs after merge0 -> C <= 256 GUARANTEED
//      (Boruvka halving), so no idle rounds and no worst-case-12 launches
//  (c) k_contract: one d2 pass -> contracted <=256x256 min-key matrix
//      (LDS table + global atomicMin); k_merge gains dense relabel comp2
//  (d) k_finish: single workgroup finishes all remaining Boruvka rounds on
//      the 512KB contracted graph (only __syncthreads; no device fences --
//      R5/R6 lesson: device-scope fences evict the L2/L3 working set)
// ---------------------------------------------------------------------------

#define NPTS 4096
#define DIMF 1024
typedef unsigned short u16;
typedef _Float16 f16;
typedef unsigned long long ull;
static const ull KEY_MAX_ULL = ~0ull;

typedef f16 f16x8 __attribute__((ext_vector_type(8)));
typedef f16 f16x4v __attribute__((ext_vector_type(4)));
typedef float f32x4 __attribute__((ext_vector_type(4)));

#define GLOAD_LDS16(g, l)                                                      \
  __builtin_amdgcn_global_load_lds(                                            \
      (const __attribute__((address_space(1))) void*)(g),                      \
      (__attribute__((address_space(3))) void*)(l), 16, 0, 0)

// ------------------------------ init ---------------------------------------
__global__ void k_init_global(float* __restrict__ deaths, int* __restrict__ cnt) {
  int i = blockIdx.x * blockDim.x + threadIdx.x;
  if (i < 3 * NPTS) deaths[i] = __int_as_float(0x7f800000);  // +inf pad
  if (i < 8) cnt[i] = 0;  // cnt[0..2]=death counters, cnt[3]=done, cnt[5]=C
}

// fallback-path per-cloud init
__global__ void k_init_cloud(int* __restrict__ comp, ull* __restrict__ best,
                             int* __restrict__ done) {
  int i = blockIdx.x * blockDim.x + threadIdx.x;
  if (i < NPTS) { comp[i] = i; best[i] = KEY_MAX_ULL; }
  if (i == 0) *done = 0;
}

// -------- prep: norms + f16 cast + per-cloud init (comp/best/done/cd) -------
__global__ __launch_bounds__(256)
void k_prep(const float* __restrict__ x, float* __restrict__ sq,
            f16* __restrict__ hi, int* __restrict__ comp,
            ull* __restrict__ best, int* __restrict__ done,
            ull* __restrict__ cd) {
  const int row = blockIdx.x;
  const int t = threadIdx.x;
  const float4 v = ((const float4*)(x + (size_t)row * DIMF))[t];
  f16x4v h;
  h.x = (f16)v.x; h.y = (f16)v.y; h.z = (f16)v.z; h.w = (f16)v.w;
  ((f16x4v*)(hi + (size_t)row * DIMF))[t] = h;
  float s = v.x * v.x + v.y * v.y + v.z * v.z + v.w * v.w;
  for (int off = 32; off > 0; off >>= 1) s += __shfl_xor(s, off, 64);
  __shared__ float ws[4];
  if ((t & 63) == 0) ws[t >> 6] = s;
  if (row < 16) {  // comp/best/done init
    const int i = row * 256 + t;
    comp[i] = i;
    best[i] = KEY_MAX_ULL;
    if (i == 0) *done = 0;
  } else if (row < 80) {  // cd init: 64 blocks x 256 thr x 4 cells = 65536
    const int i = (row - 16) * 256 + t;
#pragma unroll
    for (int q = 0; q < 4; ++q) cd[i * 4 + q] = KEY_MAX_ULL;
  }
  __syncthreads();
  if (t == 0) sq[row] = ws[0] + ws[1] + ws[2] + ws[3];
}

// fp32-path norms (fallback)
__global__ __launch_bounds__(256)
void k_norms(const float* __restrict__ x, float* __restrict__ sq) {
  const int row = blockIdx.x;
  const int t = threadIdx.x;
  const float4 v = ((const float4*)(x + (size_t)row * DIMF))[t];
  float s = v.x * v.x + v.y * v.y + v.z * v.z + v.w * v.w;
  for (int off = 32; off > 0; off >>= 1) s += __shfl_xor(s, off, 64);
  __shared__ float ws[4];
  if ((t & 63) == 0) ws[t >> 6] = s;
  __syncthreads();
  if (t == 0) sq[row] = ws[0] + ws[1] + ws[2] + ws[3];
}

// ------------------------------ fp16 MFMA GEMM + round-0 scan ---------------
__global__ __launch_bounds__(256)
void k_gemm_f16(const f16* __restrict__ hi, const float* __restrict__ sq,
                float* __restrict__ d2, ull* __restrict__ best) {
  __shared__ u16 smem[8192];
  u16* As = smem;
  u16* Bs = smem + 4096;
  const int t = threadIdx.x;
  const int w = t >> 6, l = t & 63;
  const int wm = w >> 1, wn = w & 1;
  const int ml = l & 15, kq = l >> 4;
  const int i0 = blockIdx.y * 128, j0 = blockIdx.x * 128;

  const int srow = t >> 2, schk = t & 3;
  char* ldsA0 = (char*)As + t * 16;
  char* ldsB0 = (char*)Bs + t * 16;

  f32x4 acc[4][4];
#pragma unroll
  for (int a = 0; a < 4; ++a)
#pragma unroll
    for (int b = 0; b < 4; ++b) acc[a][b] = (f32x4)0.f;

  for (int k0 = 0; k0 < DIMF; k0 += 32) {
    __syncthreads();
    {
      const f16* ga0 = hi + (size_t)(i0 + srow) * DIMF + k0 + schk * 8;
      const f16* ga1 = hi + (size_t)(i0 + srow + 64) * DIMF + k0 + schk * 8;
      const f16* gb0 = hi + (size_t)(j0 + srow) * DIMF + k0 + schk * 8;
      const f16* gb1 = hi + (size_t)(j0 + srow + 64) * DIMF + k0 + schk * 8;
      GLOAD_LDS16(ga0, ldsA0);
      GLOAD_LDS16(ga1, ldsA0 + 4096);
      GLOAD_LDS16(gb0, ldsB0);
      GLOAD_LDS16(gb1, ldsB0 + 4096);
    }
    asm volatile("s_waitcnt vmcnt(0)" ::: "memory");
    __syncthreads();

    const char* Ab = (const char*)As + (wm * 64 + ml) * 64 + kq * 16;
    const char* Bb = (const char*)Bs + (wn * 64 + ml) * 64 + kq * 16;
    f16x8 af[4], bf[4];
#pragma unroll
    for (int mt = 0; mt < 4; ++mt) af[mt] = *(const f16x8*)(Ab + mt * 1024);
#pragma unroll
    for (int nt = 0; nt < 4; ++nt) bf[nt] = *(const f16x8*)(Bb + nt * 1024);
#pragma unroll
    for (int mt = 0; mt < 4; ++mt)
#pragma unroll
      for (int nt = 0; nt < 4; ++nt)
        acc[mt][nt] = __builtin_amdgcn_mfma_f32_16x16x32_f16(
            af[mt], bf[nt], acc[mt][nt], 0, 0, 0);
  }

  float sr[4][4], sc[4];
#pragma unroll
  for (int mt = 0; mt < 4; ++mt)
#pragma unroll
    for (int r = 0; r < 4; ++r)
      sr[mt][r] = sq[i0 + wm * 64 + mt * 16 + kq * 4 + r];
#pragma unroll
  for (int nt = 0; nt < 4; ++nt) sc[nt] = sq[j0 + wn * 64 + nt * 16 + ml];

#pragma unroll
  for (int mt = 0; mt < 4; ++mt) {
#pragma unroll
    for (int r = 0; r < 4; ++r) {
      const int row = i0 + wm * 64 + mt * 16 + kq * 4 + r;
      const float si = sr[mt][r];
      ull kmin = KEY_MAX_ULL;
#pragma unroll
      for (int nt = 0; nt < 4; ++nt) {
        const int col = j0 + wn * 64 + nt * 16 + ml;
        const float v = fmaxf(si + sc[nt] - 2.f * acc[mt][nt][r], 0.f);
        d2[(size_t)row * NPTS + col] = v;
        if (col != row) {
          const ull pair = (row < col) ? (((ull)row << 12) | (unsigned)col)
                                       : (((ull)col << 12) | (unsigned)row);
          const ull key = ((ull)__float_as_uint(v) << 24) | pair;
          kmin = (key < kmin) ? key : kmin;
        }
      }
#pragma unroll
      for (int m = 1; m <= 8; m <<= 1) {
        const ull o = __shfl_xor(kmin, m, 64);
        kmin = (o < kmin) ? o : kmin;
      }
      if ((l & 15) == 0) atomicMin(best + row, kmin);
    }
  }
}

// ------------------------------ fp32 GEMM fallback --------------------------
#define BM 128
#define BN 128
#define BK 16
__global__ __launch_bounds__(256)
void k_gemm_d2(const float* __restrict__ X, const float* __restrict__ sq,
               float* __restrict__ d2) {
  __shared__ float As[BK][BM];
  __shared__ float Bs[BK][BN];
  const int tid = threadIdx.x;
  const int tx = tid & 15, ty = tid >> 4;
  const int i0 = blockIdx.y * BM, j0 = blockIdx.x * BN;
  float acc[8][8] = {};
  for (int k0 = 0; k0 < DIMF; k0 += BK) {
#pragma unroll
    for (int id = tid; id < 512; id += 256) {
      const int row = id >> 2;
      const int kk = (id & 3) << 2;
      const float4 a = *(const float4*)(X + (size_t)(i0 + row) * DIMF + k0 + kk);
      const float4 b = *(const float4*)(X + (size_t)(j0 + row) * DIMF + k0 + kk);
      As[kk + 0][row] = a.x; As[kk + 1][row] = a.y;
      As[kk + 2][row] = a.z; As[kk + 3][row] = a.w;
      Bs[kk + 0][row] = b.x; Bs[kk + 1][row] = b.y;
      Bs[kk + 2][row] = b.z; Bs[kk + 3][row] = b.w;
    }
    __syncthreads();
#pragma unroll
    for (int kk = 0; kk < BK; ++kk) {
      float a[8], b[8];
#pragma unroll
      for (int m = 0; m < 8; ++m) a[m] = As[kk][ty * 8 + m];
#pragma unroll
      for (int n = 0; n < 8; ++n) b[n] = Bs[kk][tx * 8 + n];
#pragma unroll
      for (int m = 0; m < 8; ++m)
#pragma unroll
        for (int n = 0; n < 8; ++n)
          acc[m][n] = fmaf(a[m], b[n], acc[m][n]);
    }
    __syncthreads();
  }
#pragma unroll
  for (int m = 0; m < 8; ++m) {
    const int i = i0 + ty * 8 + m;
    const float si = sq[i];
    const int j = j0 + tx * 8;
    float4 o0, o1;
    o0.x = fmaxf(si + sq[j + 0] - 2.f * acc[m][0], 0.f);
    o0.y = fmaxf(si + sq[j + 1] - 2.f * acc[m][1], 0.f);
    o0.z = fmaxf(si + sq[j + 2] - 2.f * acc[m][2], 0.f);
    o0.w = fmaxf(si + sq[j + 3] - 2.f * acc[m][3], 0.f);
    o1.x = fmaxf(si + sq[j + 4] - 2.f * acc[m][4], 0.f);
    o1.y = fmaxf(si + sq[j + 5] - 2.f * acc[m][5], 0.f);
    o1.z = fmaxf(si + sq[j + 6] - 2.f * acc[m][6], 0.f);
    o1.w = fmaxf(si + sq[j + 7] - 2.f * acc[m][7], 0.f);
    *(float4*)(d2 + (size_t)i * NPTS + j) = o0;
    *(float4*)(d2 + (size_t)i * NPTS + j + 4) = o1;
  }
}

// ------------------------------ Boruvka scan (R4, fence-free) ---------------
__global__ __launch_bounds__(256)
void k_scan(const float* __restrict__ d2, const int* __restrict__ comp,
            ull* __restrict__ best, const int* __restrict__ done) {
  if (*done) return;
  const int i = blockIdx.x;
  const int t = threadIdx.x;
  __shared__ ull red[4];
  int cj[16];
  {
    const int4* cp = (const int4*)comp;
    const int4 a0 = cp[t * 4 + 0], a1 = cp[t * 4 + 1];
    const int4 a2 = cp[t * 4 + 2], a3 = cp[t * 4 + 3];
    cj[0] = a0.x;  cj[1] = a0.y;  cj[2] = a0.z;  cj[3] = a0.w;
    cj[4] = a1.x;  cj[5] = a1.y;  cj[6] = a1.z;  cj[7] = a1.w;
    cj[8] = a2.x;  cj[9] = a2.y;  cj[10] = a2.z; cj[11] = a2.w;
    cj[12] = a3.x; cj[13] = a3.y; cj[14] = a3.z; cj[15] = a3.w;
  }
  const int ci = comp[i];
  const float* row = d2 + (size_t)i * NPTS;
  ull kmin = KEY_MAX_ULL;
#pragma unroll
  for (int q = 0; q < 4; ++q) {
    const float4 v = ((const float4*)row)[t * 4 + q];
    const float vv[4] = {v.x, v.y, v.z, v.w};
#pragma unroll
    for (int u = 0; u < 4; ++u) {
      const int j = t * 16 + q * 4 + u;
      if (cj[q * 4 + u] != ci) {
        const ull pair = (i < j) ? (((ull)i << 12) | (unsigned)j)
                                 : (((ull)j << 12) | (unsigned)i);
        const ull key = ((ull)__float_as_uint(vv[u]) << 24) | pair;
        kmin = (key < kmin) ? key : kmin;
      }
    }
  }
  for (int off = 32; off > 0; off >>= 1) {
    const ull o = __shfl_xor(kmin, off, 64);
    kmin = (o < kmin) ? o : kmin;
  }
  if ((t & 63) == 0) red[t >> 6] = kmin;
  __syncthreads();
  if (t == 0) {
    ull k2 = red[0];
    k2 = (red[1] < k2) ? red[1] : k2;
    k2 = (red[2] < k2) ? red[2] : k2;
    k2 = (red[3] < k2) ? red[3] : k2;
    if (k2 != KEY_MAX_ULL) atomicMin(best + ci, k2);
  }
}

// --------------------- Boruvka merge + dense relabel ------------------------
__global__ __launch_bounds__(1024)
void k_merge(ull* __restrict__ best, int* __restrict__ comp,
             int* __restrict__ comp2, float* __restrict__ deaths,
             int* __restrict__ cnt, int* __restrict__ done,
             int* __restrict__ Cout) {
  if (*done) return;
  __shared__ int par[NPTS];
  __shared__ int hk[NPTS];
  __shared__ int redi[16];
  __shared__ int chg;
  __shared__ int cdense;
  const int t = threadIdx.x;
  ull bb[4];
#pragma unroll
  for (int s = 0; s < 4; ++s) {
    const int v = t + s * 1024;
    par[v] = comp[v];
    bb[s] = best[v];
    best[v] = KEY_MAX_ULL;
  }
  __syncthreads();
#pragma unroll
  for (int s = 0; s < 4; ++s) {
    const int v = t + s * 1024;
    const ull b2 = bb[s];
    int h;
    if (b2 == KEY_MAX_ULL) {
      h = par[v];
    } else {
      const int pair = (int)(b2 & 0xFFFFFF);
      const int a = pair >> 12, c2 = pair & 4095;
      const int ra = par[a], rb = par[c2];
      h = (ra == v) ? rb : ra;
    }
    hk[v] = h;
  }
  __syncthreads();
  bool win[4];
#pragma unroll
  for (int s = 0; s < 4; ++s) {
    const int v = t + s * 1024;
    const ull b2 = bb[s];
    win[s] = false;
    if (b2 != KEY_MAX_ULL) {
      const int so = hk[v];
      const bool mut = (hk[so] == v);
      win[s] = mut && (v < so);
      if (!mut || v < so) {
        const float dd = __uint_as_float((unsigned)(b2 >> 24));
        deaths[atomicAdd(cnt, 1)] = sqrtf(fmaxf(dd, 1e-12f));
      }
    }
  }
  if (t == 0) chg = 0;
  __syncthreads();
#pragma unroll
  for (int s = 0; s < 4; ++s)
    if (win[s]) hk[t + s * 1024] = t + s * 1024;
  __syncthreads();
  for (int it = 0; it < 12; ++it) {
    int w2[4]; int ch = 0;
#pragma unroll
    for (int s = 0; s < 4; ++s) {
      const int v = t + s * 1024;
      w2[s] = hk[hk[v]];
      ch |= (w2[s] != hk[v]);
    }
    __syncthreads();
#pragma unroll
    for (int s = 0; s < 4; ++s) hk[t + s * 1024] = w2[s];
    if (ch) chg = 1;
    __syncthreads();
    const int any = chg;
    __syncthreads();
    if (t == 0) chg = 0;
    if (!any) break;
  }
  int nroot = 0;
#pragma unroll
  for (int s = 0; s < 4; ++s) {
    const int v = t + s * 1024;
    const int rv = hk[v];
    comp[v] = rv;
    nroot += (rv == v);
  }
  for (int off = 32; off > 0; off >>= 1) nroot += __shfl_xor(nroot, off, 64);
  if ((t & 63) == 0) redi[t >> 6] = nroot;
  // dense relabel: par[root] = dense id; comp2[v] = par[hk[v]]
  if (t == 0) cdense = 0;
  __syncthreads();
#pragma unroll
  for (int s = 0; s < 4; ++s) {
    const int v = t + s * 1024;
    if (hk[v] == v) par[v] = atomicAdd(&cdense, 1);
  }
  __syncthreads();
#pragma unroll
  for (int s = 0; s < 4; ++s) {
    const int v = t + s * 1024;
    comp2[v] = par[hk[v]];
  }
  if (t == 0) {
    int tot = 0;
    for (int q = 0; q < 16; ++q) tot += redi[q];
    *Cout = cdense;
    if (tot == 1) *done = 1;
  }
}

// ------------------------------ contraction ---------------------------------
// Block per row i: per-target-component min key via LDS table (C<=256), then
// one global atomicMin per live target into cd[ci*256+c].
__global__ __launch_bounds__(256)
void k_contract(const float* __restrict__ d2, const int* __restrict__ comp2,
                ull* __restrict__ cd, const int* __restrict__ done) {
  if (*done) return;
  const int i = blockIdx.x;
  const int t = threadIdx.x;
  __shared__ ull tbl[256];
  tbl[t] = KEY_MAX_ULL;
  int cj[16];
  {
    const int4* cp = (const int4*)comp2;
    const int4 a0 = cp[t * 4 + 0], a1 = cp[t * 4 + 1];
    const int4 a2 = cp[t * 4 + 2], a3 = cp[t * 4 + 3];
    cj[0] = a0.x;  cj[1] = a0.y;  cj[2] = a0.z;  cj[3] = a0.w;
    cj[4] = a1.x;  cj[5] = a1.y;  cj[6] = a1.z;  cj[7] = a1.w;
    cj[8] = a2.x;  cj[9] = a2.y;  cj[10] = a2.z; cj[11] = a2.w;
    cj[12] = a3.x; cj[13] = a3.y; cj[14] = a3.z; cj[15] = a3.w;
  }
  const int ci = comp2[i];
  __syncthreads();
  const float* row = d2 + (size_t)i * NPTS;
#pragma unroll
  for (int q = 0; q < 4; ++q) {
    const float4 v = ((const float4*)row)[t * 4 + q];
    const float vv[4] = {v.x, v.y, v.z, v.w};
#pragma unroll
    for (int u = 0; u < 4; ++u) {
      const int j = t * 16 + q * 4 + u;
      const int c = cj[q * 4 + u];
      if (c != ci) {
        const ull pair = (i < j) ? (((ull)i << 12) | (unsigned)j)
                                 : (((ull)j << 12) | (unsigned)i);
        const ull key = ((ull)__float_as_uint(vv[u]) << 24) | pair;
        atomicMin(&tbl[c], key);
      }
    }
  }
  __syncthreads();
  const ull tv = tbl[t];
  if (tv != KEY_MAX_ULL) atomicMin(&cd[ci * 256 + t], tv);
}

// ------------------------------ finish (single WG) --------------------------
// All remaining Boruvka rounds on the contracted graph (C<=256 nodes).
__global__ __launch_bounds__(1024)
void k_finish(const ull* __restrict__ cd, const int* __restrict__ comp2,
              const int* __restrict__ Cptr, float* __restrict__ deaths,
              int* __restrict__ cnt, const int* __restrict__ done) {
  if (*done) return;
  __shared__ int c2[NPTS];  // 16KB: vertex -> cid
  __shared__ ull bst[256];
  __shared__ int lbl[256];
  __shared__ int hk2[256];
  __shared__ int mk[256];
  __shared__ int nr_sh;
  const int t = threadIdx.x;
  const int C = *Cptr;
#pragma unroll
  for (int s = 0; s < 4; ++s) c2[t + s * 1024] = comp2[t + s * 1024];
  if (t < 256) lbl[t] = t;
  __syncthreads();
  for (int round = 0; round < 9; ++round) {
    if (t < 256) { bst[t] = KEY_MAX_ULL; mk[t] = 0; }
    if (t == 0) nr_sh = 0;
    __syncthreads();
    for (int idx = t; idx < C * 256; idx += 1024) {
      const int d = idx & 255;
      if (d < C) {
        const ull k = cd[idx];
        if (k != KEY_MAX_ULL) {
          const int lc = lbl[idx >> 8], ld = lbl[d];
          if (lc != ld) atomicMin(&bst[lc], k);
        }
      }
    }
    __syncthreads();
    if (t < 256) {
      int h = t;
      const ull b = bst[t];
      if (t < C && b != KEY_MAX_ULL) {
        const int pair = (int)(b & 0xFFFFFF);
        const int a = pair >> 12, b2 = pair & 4095;
        const int sa = lbl[c2[a]], sb = lbl[c2[b2]];
        const int other = (sa == t) ? sb : sa;
        const ull bo = bst[other];
        const bool mut = (bo != KEY_MAX_ULL) && ((int)(bo & 0xFFFFFF) == pair);
        bool rec;
        if (mut) { h = (t < other) ? t : other; rec = (t < other); }
        else     { h = other;                   rec = true; }
        if (rec) {
          const float dd = __uint_as_float((unsigned)(b >> 24));
          deaths[atomicAdd(cnt, 1)] = sqrtf(fmaxf(dd, 1e-12f));
        }
      }
      hk2[t] = h;
    }
    __syncthreads();
    for (int it = 0; it < 8; ++it) {
      int w2 = 0;
      if (t < 256) w2 = hk2[hk2[t]];
      __syncthreads();
      if (t < 256) hk2[t] = w2;
      __syncthreads();
    }
    if (t < 256) lbl[t] = hk2[lbl[t]];
    __syncthreads();
    if (t < C) mk[lbl[t]] = 1;
    __syncthreads();
    if (t < 256 && mk[t]) atomicAdd(&nr_sh, 1);
    __syncthreads();
    if (nr_sh <= 1) break;
  }
}

// ------------------------------ sort (bitonic, 4096 in LDS) -----------------
__global__ __launch_bounds__(1024)
void k_sort(float* __restrict__ deaths) {
  __shared__ float s[NPTS];
  float* g = deaths + (size_t)blockIdx.x * NPTS;
  const int t = threadIdx.x;
#pragma unroll
  for (int q = 0; q < 4; ++q) s[t + q * 1024] = g[t + q * 1024];
  for (int k = 2; k <= NPTS; k <<= 1) {
    for (int j = k >> 1; j > 0; j >>= 1) {
      __syncthreads();
#pragma unroll
      for (int q = 0; q < 4; ++q) {
        const int i = t + q * 1024;
        const int ixj = i ^ j;
        if (ixj > i) {
          const float a = s[i], b = s[ixj];
          const bool up = ((i & k) == 0);
          if ((a > b) == up) { s[i] = b; s[ixj] = a; }
        }
      }
    }
  }
  __syncthreads();
#pragma unroll
  for (int q = 0; q < 4; ++q) g[t + q * 1024] = s[t + q * 1024];
}

// ------------------------------ final loss ----------------------------------
__global__ __launch_bounds__(1024)
void k_final(const float* __restrict__ deaths, float* __restrict__ out) {
  const float* a = deaths;
  const float* p = deaths + NPTS;
  const float* n = deaths + 2 * NPTS;
  const int t = threadIdx.x;
  float s1 = 0.f, s2 = 0.f;
  for (int i = t; i < NPTS - 1; i += 1024) {
    s1 += fabsf(a[i] - p[i]);
    s2 += fabsf(a[i] - n[i]);
  }
  for (int off = 32; off > 0; off >>= 1) {
    s1 += __shfl_xor(s1, off, 64);
    s2 += __shfl_xor(s2, off, 64);
  }
  __shared__ float r1[16], r2[16];
  if ((t & 63) == 0) { r1[t >> 6] = s1; r2[t >> 6] = s2; }
  __syncthreads();
  if (t == 0) {
    float t1 = 0.f, t2 = 0.f;
    for (int q = 0; q < 16; ++q) { t1 += r1[q]; t2 += r2[q]; }
    out[0] = fmaxf(t1 - t2 + 1.0f, 0.0f);
  }
}

__global__ void k_fail(float* out) { if (threadIdx.x == 0) out[0] = 0.f; }

// ------------------------------ launch --------------------------------------
extern "C" void kernel_launch(void* const* d_in, const int* in_sizes, int n_in,
                              void* d_out, int out_size, void* d_ws, size_t ws_size,
                              hipStream_t stream) {
  const float* xs[3] = {(const float*)d_in[0], (const float*)d_in[1],
                        (const float*)d_in[2]};
  char* ws = (char*)d_ws;
  const size_t d2_bytes = (size_t)NPTS * NPTS * 4;   // 64MB
  const size_t hi_bytes = (size_t)NPTS * DIMF * 2;   // 8MB
  const size_t cd_bytes = 256 * 256 * 8;             // 512KB
  const size_t small = NPTS * 4 /*sq*/ + NPTS * 4 /*comp*/ + NPTS * 8 /*best*/ +
                       3 * NPTS * 4 /*deaths*/ + NPTS * 4 /*comp2*/ + 256;
  const size_t need_fp32 = d2_bytes + small;
  const size_t need_f16 = d2_bytes + hi_bytes + cd_bytes + small;
  if (ws_size < need_fp32) {
    k_fail<<<1, 64, 0, stream>>>((float*)d_out);
    return;
  }
  const bool use_f16 = (ws_size >= need_f16);
  const size_t tail0 = use_f16 ? (d2_bytes + hi_bytes + cd_bytes) : d2_bytes;

  float* d2 = (float*)ws;
  f16* hi = (f16*)(ws + d2_bytes);
  ull* cd = (ull*)(ws + d2_bytes + hi_bytes);
  float* sq = (float*)(ws + tail0);
  int* comp = (int*)(ws + tail0 + NPTS * 4);
  ull* best = (ull*)(ws + tail0 + NPTS * 8);
  float* deaths = (float*)(ws + tail0 + NPTS * 16);
  int* comp2 = (int*)(ws + tail0 + NPTS * 16 + 3 * NPTS * 4);
  int* cnt = (int*)(ws + tail0 + NPTS * 16 + 3 * NPTS * 4 + NPTS * 4);
  int* done = cnt + 3;
  int* Cdev = cnt + 5;

  k_init_global<<<48, 256, 0, stream>>>(deaths, cnt);
  for (int c = 0; c < 3; ++c) {
    float* dth = deaths + c * NPTS;
    int* cn = cnt + c;
    if (use_f16) {
      k_prep<<<NPTS, 256, 0, stream>>>(xs[c], sq, hi, comp, best, done, cd);
      k_gemm_f16<<<dim3(NPTS / 128, NPTS / 128), 256, 0, stream>>>(hi, sq, d2,
                                                                   best);
      // round 0 (scan fused in GEMM) + 3 more rounds -> C <= 256 guaranteed
      k_merge<<<1, 1024, 0, stream>>>(best, comp, comp2, dth, cn, done, Cdev);
      for (int r = 0; r < 3; ++r) {
        k_scan<<<NPTS, 256, 0, stream>>>(d2, comp, best, done);
        k_merge<<<1, 1024, 0, stream>>>(best, comp, comp2, dth, cn, done, Cdev);
      }
      k_contract<<<NPTS, 256, 0, stream>>>(d2, comp2, cd, done);
      k_finish<<<1, 1024, 0, stream>>>(cd, comp2, Cdev, dth, cn, done);
    } else {
      k_norms<<<NPTS, 256, 0, stream>>>(xs[c], sq);
      k_init_cloud<<<16, 256, 0, stream>>>(comp, best, done);
      k_gemm_d2<<<dim3(NPTS / BN, NPTS / BM), 256, 0, stream>>>(xs[c], sq, d2);
      for (int r = 0; r < 12; ++r) {
        k_scan<<<NPTS, 256, 0, stream>>>(d2, comp, best, done);
        k_merge<<<1, 1024, 0, stream>>>(best, comp, comp2, dth, cn, done, Cdev);
      }
    }
  }
  k_sort<<<3, 1024, 0, stream>>>(deaths);
  k_final<<<1, 1024, 0, stream>>>(deaths, (float*)d_out);
}

// Round 8
// 625.528 us; speedup vs baseline: 6.9450x; 1.0664x over previous
//
#include <hip/hip_runtime.h>
#include <stdint.h>

// ---------------------------------------------------------------------------
// TopologicalContrastiveLoss: H0 persistence (MST edge weights) of 3 point
// clouds -> 1-Wasserstein between sorted death vectors -> hinge loss.
//
// R8: R7 structure (4 merges -> C<=256 -> contract -> finish, all fence-free)
//  (a) round-0 scan UN-fused from GEMM (R7 counter: fusion cost +34us/GEMM
//      vs 13us standalone scan) -- GEMM back to the clean 55.7us epilogue
//  (b) f16 shadow d16 (32MB) written by GEMM; scans+contract read d16
//      (half traffic). Keys (f16bits<<24)|pair: f16 is monotone, ties broken
//      by pair -> unique valid MST; deaths looked up EXACT from f32 d2[pair].
//  (c) merge/finish record deaths via d2 lookup (pair-indexed).
// ---------------------------------------------------------------------------

#define NPTS 4096
#define DIMF 1024
typedef unsigned short u16;
typedef _Float16 f16;
typedef unsigned long long ull;
static const ull KEY_MAX_ULL = ~0ull;

typedef f16 f16x8 __attribute__((ext_vector_type(8)));
typedef f16 f16x4v __attribute__((ext_vector_type(4)));
typedef float f32x4 __attribute__((ext_vector_type(4)));

#define GLOAD_LDS16(g, l)                                                      \
  __builtin_amdgcn_global_load_lds(                                            \
      (const __attribute__((address_space(1))) void*)(g),                      \
      (__attribute__((address_space(3))) void*)(l), 16, 0, 0)

// ------------------------------ init ---------------------------------------
__global__ void k_init_global(float* __restrict__ deaths, int* __restrict__ cnt) {
  int i = blockIdx.x * blockDim.x + threadIdx.x;
  if (i < 3 * NPTS) deaths[i] = __int_as_float(0x7f800000);  // +inf pad
  if (i < 8) cnt[i] = 0;  // cnt[0..2]=death counters, cnt[3]=done, cnt[5]=C
}

// fallback-path per-cloud init
__global__ void k_init_cloud(int* __restrict__ comp, ull* __restrict__ best,
                             int* __restrict__ done) {
  int i = blockIdx.x * blockDim.x + threadIdx.x;
  if (i < NPTS) { comp[i] = i; best[i] = KEY_MAX_ULL; }
  if (i == 0) *done = 0;
}

// -------- prep: norms + f16 cast + per-cloud init (comp/best/done/cd) -------
__global__ __launch_bounds__(256)
void k_prep(const float* __restrict__ x, float* __restrict__ sq,
            f16* __restrict__ hi, int* __restrict__ comp,
            ull* __restrict__ best, int* __restrict__ done,
            ull* __restrict__ cd) {
  const int row = blockIdx.x;
  const int t = threadIdx.x;
  const float4 v = ((const float4*)(x + (size_t)row * DIMF))[t];
  f16x4v h;
  h.x = (f16)v.x; h.y = (f16)v.y; h.z = (f16)v.z; h.w = (f16)v.w;
  ((f16x4v*)(hi + (size_t)row * DIMF))[t] = h;
  float s = v.x * v.x + v.y * v.y + v.z * v.z + v.w * v.w;
  for (int off = 32; off > 0; off >>= 1) s += __shfl_xor(s, off, 64);
  __shared__ float ws[4];
  if ((t & 63) == 0) ws[t >> 6] = s;
  if (row < 16) {  // comp/best/done init
    const int i = row * 256 + t;
    comp[i] = i;
    best[i] = KEY_MAX_ULL;
    if (i == 0) *done = 0;
  } else if (row < 80) {  // cd init: 64 blocks x 256 thr x 4 cells = 65536
    const int i = (row - 16) * 256 + t;
#pragma unroll
    for (int q = 0; q < 4; ++q) cd[i * 4 + q] = KEY_MAX_ULL;
  }
  __syncthreads();
  if (t == 0) sq[row] = ws[0] + ws[1] + ws[2] + ws[3];
}

// fp32-path norms (fallback)
__global__ __launch_bounds__(256)
void k_norms(const float* __restrict__ x, float* __restrict__ sq) {
  const int row = blockIdx.x;
  const int t = threadIdx.x;
  const float4 v = ((const float4*)(x + (size_t)row * DIMF))[t];
  float s = v.x * v.x + v.y * v.y + v.z * v.z + v.w * v.w;
  for (int off = 32; off > 0; off >>= 1) s += __shfl_xor(s, off, 64);
  __shared__ float ws[4];
  if ((t & 63) == 0) ws[t >> 6] = s;
  __syncthreads();
  if (t == 0) sq[row] = ws[0] + ws[1] + ws[2] + ws[3];
}

// ------------------------------ fp16 MFMA GEMM ------------------------------
// d2[i][j] = max(sq[i]+sq[j]-2*(Hi@Hi^T), 0); optional f16 shadow d16.
// Clean R4 epilogue (no fused scan -- R7 showed fusion costs 2.5x a scan).
__global__ __launch_bounds__(256)
void k_gemm_f16(const f16* __restrict__ hi, const float* __restrict__ sq,
                float* __restrict__ d2, f16* __restrict__ d16) {
  __shared__ u16 smem[8192];
  u16* As = smem;
  u16* Bs = smem + 4096;
  const int t = threadIdx.x;
  const int w = t >> 6, l = t & 63;
  const int wm = w >> 1, wn = w & 1;
  const int ml = l & 15, kq = l >> 4;
  const int i0 = blockIdx.y * 128, j0 = blockIdx.x * 128;

  const int srow = t >> 2, schk = t & 3;
  char* ldsA0 = (char*)As + t * 16;
  char* ldsB0 = (char*)Bs + t * 16;

  f32x4 acc[4][4];
#pragma unroll
  for (int a = 0; a < 4; ++a)
#pragma unroll
    for (int b = 0; b < 4; ++b) acc[a][b] = (f32x4)0.f;

  for (int k0 = 0; k0 < DIMF; k0 += 32) {
    __syncthreads();
    {
      const f16* ga0 = hi + (size_t)(i0 + srow) * DIMF + k0 + schk * 8;
      const f16* ga1 = hi + (size_t)(i0 + srow + 64) * DIMF + k0 + schk * 8;
      const f16* gb0 = hi + (size_t)(j0 + srow) * DIMF + k0 + schk * 8;
      const f16* gb1 = hi + (size_t)(j0 + srow + 64) * DIMF + k0 + schk * 8;
      GLOAD_LDS16(ga0, ldsA0);
      GLOAD_LDS16(ga1, ldsA0 + 4096);
      GLOAD_LDS16(gb0, ldsB0);
      GLOAD_LDS16(gb1, ldsB0 + 4096);
    }
    asm volatile("s_waitcnt vmcnt(0)" ::: "memory");
    __syncthreads();

    const char* Ab = (const char*)As + (wm * 64 + ml) * 64 + kq * 16;
    const char* Bb = (const char*)Bs + (wn * 64 + ml) * 64 + kq * 16;
    f16x8 af[4], bf[4];
#pragma unroll
    for (int mt = 0; mt < 4; ++mt) af[mt] = *(const f16x8*)(Ab + mt * 1024);
#pragma unroll
    for (int nt = 0; nt < 4; ++nt) bf[nt] = *(const f16x8*)(Bb + nt * 1024);
#pragma unroll
    for (int mt = 0; mt < 4; ++mt)
#pragma unroll
      for (int nt = 0; nt < 4; ++nt)
        acc[mt][nt] = __builtin_amdgcn_mfma_f32_16x16x32_f16(
            af[mt], bf[nt], acc[mt][nt], 0, 0, 0);
  }

  float sr[4][4], sc[4];
#pragma unroll
  for (int mt = 0; mt < 4; ++mt)
#pragma unroll
    for (int r = 0; r < 4; ++r)
      sr[mt][r] = sq[i0 + wm * 64 + mt * 16 + kq * 4 + r];
#pragma unroll
  for (int nt = 0; nt < 4; ++nt) sc[nt] = sq[j0 + wn * 64 + nt * 16 + ml];

  if (d16 != nullptr) {
#pragma unroll
    for (int mt = 0; mt < 4; ++mt)
#pragma unroll
      for (int nt = 0; nt < 4; ++nt) {
        const int col = j0 + wn * 64 + nt * 16 + ml;
#pragma unroll
        for (int r = 0; r < 4; ++r) {
          const int row = i0 + wm * 64 + mt * 16 + kq * 4 + r;
          const float v = fmaxf(sr[mt][r] + sc[nt] - 2.f * acc[mt][nt][r], 0.f);
          d2[(size_t)row * NPTS + col] = v;
          d16[(size_t)row * NPTS + col] = (f16)v;
        }
      }
  } else {
#pragma unroll
    for (int mt = 0; mt < 4; ++mt)
#pragma unroll
      for (int nt = 0; nt < 4; ++nt) {
        const int col = j0 + wn * 64 + nt * 16 + ml;
#pragma unroll
        for (int r = 0; r < 4; ++r) {
          const int row = i0 + wm * 64 + mt * 16 + kq * 4 + r;
          const float v = fmaxf(sr[mt][r] + sc[nt] - 2.f * acc[mt][nt][r], 0.f);
          d2[(size_t)row * NPTS + col] = v;
        }
      }
  }
}

// ------------------------------ fp32 GEMM fallback --------------------------
#define BM 128
#define BN 128
#define BK 16
__global__ __launch_bounds__(256)
void k_gemm_d2(const float* __restrict__ X, const float* __restrict__ sq,
               float* __restrict__ d2) {
  __shared__ float As[BK][BM];
  __shared__ float Bs[BK][BN];
  const int tid = threadIdx.x;
  const int tx = tid & 15, ty = tid >> 4;
  const int i0 = blockIdx.y * BM, j0 = blockIdx.x * BN;
  float acc[8][8] = {};
  for (int k0 = 0; k0 < DIMF; k0 += BK) {
#pragma unroll
    for (int id = tid; id < 512; id += 256) {
      const int row = id >> 2;
      const int kk = (id & 3) << 2;
      const float4 a = *(const float4*)(X + (size_t)(i0 + row) * DIMF + k0 + kk);
      const float4 b = *(const float4*)(X + (size_t)(j0 + row) * DIMF + k0 + kk);
      As[kk + 0][row] = a.x; As[kk + 1][row] = a.y;
      As[kk + 2][row] = a.z; As[kk + 3][row] = a.w;
      Bs[kk + 0][row] = b.x; Bs[kk + 1][row] = b.y;
      Bs[kk + 2][row] = b.z; Bs[kk + 3][row] = b.w;
    }
    __syncthreads();
#pragma unroll
    for (int kk = 0; kk < BK; ++kk) {
      float a[8], b[8];
#pragma unroll
      for (int m = 0; m < 8; ++m) a[m] = As[kk][ty * 8 + m];
#pragma unroll
      for (int n = 0; n < 8; ++n) b[n] = Bs[kk][tx * 8 + n];
#pragma unroll
      for (int m = 0; m < 8; ++m)
#pragma unroll
        for (int n = 0; n < 8; ++n)
          acc[m][n] = fmaf(a[m], b[n], acc[m][n]);
    }
    __syncthreads();
  }
#pragma unroll
  for (int m = 0; m < 8; ++m) {
    const int i = i0 + ty * 8 + m;
    const float si = sq[i];
    const int j = j0 + tx * 8;
    float4 o0, o1;
    o0.x = fmaxf(si + sq[j + 0] - 2.f * acc[m][0], 0.f);
    o0.y = fmaxf(si + sq[j + 1] - 2.f * acc[m][1], 0.f);
    o0.z = fmaxf(si + sq[j + 2] - 2.f * acc[m][2], 0.f);
    o0.w = fmaxf(si + sq[j + 3] - 2.f * acc[m][3], 0.f);
    o1.x = fmaxf(si + sq[j + 4] - 2.f * acc[m][4], 0.f);
    o1.y = fmaxf(si + sq[j + 5] - 2.f * acc[m][5], 0.f);
    o1.z = fmaxf(si + sq[j + 6] - 2.f * acc[m][6], 0.f);
    o1.w = fmaxf(si + sq[j + 7] - 2.f * acc[m][7], 0.f);
    *(float4*)(d2 + (size_t)i * NPTS + j) = o0;
    *(float4*)(d2 + (size_t)i * NPTS + j + 4) = o1;
  }
}

// ------------------------- f16 Boruvka scan (tier a) ------------------------
// One block per row i; 16 cols/thread via two uint4 loads of d16; keys are
// 40-bit (f16bits<<24)|pair. Fence-free.
__global__ __launch_bounds__(256)
void k_scan16(const u16* __restrict__ d16, const int* __restrict__ comp,
              ull* __restrict__ best, const int* __restrict__ done) {
  if (*done) return;
  const int i = blockIdx.x;
  const int t = threadIdx.x;
  __shared__ ull red[4];
  int cj[16];
  {
    const int4* cp = (const int4*)comp;
    const int4 a0 = cp[t * 4 + 0], a1 = cp[t * 4 + 1];
    const int4 a2 = cp[t * 4 + 2], a3 = cp[t * 4 + 3];
    cj[0] = a0.x;  cj[1] = a0.y;  cj[2] = a0.z;  cj[3] = a0.w;
    cj[4] = a1.x;  cj[5] = a1.y;  cj[6] = a1.z;  cj[7] = a1.w;
    cj[8] = a2.x;  cj[9] = a2.y;  cj[10] = a2.z; cj[11] = a2.w;
    cj[12] = a3.x; cj[13] = a3.y; cj[14] = a3.z; cj[15] = a3.w;
  }
  const int ci = comp[i];
  const uint4* rp = (const uint4*)(d16 + (size_t)i * NPTS);
  const uint4 Aw = rp[t * 2 + 0], Bw = rp[t * 2 + 1];
  const unsigned wds[8] = {Aw.x, Aw.y, Aw.z, Aw.w, Bw.x, Bw.y, Bw.z, Bw.w};
  ull kmin = KEY_MAX_ULL;
#pragma unroll
  for (int u = 0; u < 8; ++u) {
    const int j0c = t * 16 + u * 2;
    const unsigned lo = wds[u] & 0xFFFFu;
    const unsigned hi2 = wds[u] >> 16;
    if (cj[u * 2] != ci) {
      const int j = j0c;
      const ull pair = (i < j) ? (((ull)i << 12) | (unsigned)j)
                               : (((ull)j << 12) | (unsigned)i);
      const ull key = ((ull)lo << 24) | pair;
      kmin = (key < kmin) ? key : kmin;
    }
    if (cj[u * 2 + 1] != ci) {
      const int j = j0c + 1;
      const ull pair = (i < j) ? (((ull)i << 12) | (unsigned)j)
                               : (((ull)j << 12) | (unsigned)i);
      const ull key = ((ull)hi2 << 24) | pair;
      kmin = (key < kmin) ? key : kmin;
    }
  }
  for (int off = 32; off > 0; off >>= 1) {
    const ull o = __shfl_xor(kmin, off, 64);
    kmin = (o < kmin) ? o : kmin;
  }
  if ((t & 63) == 0) red[t >> 6] = kmin;
  __syncthreads();
  if (t == 0) {
    ull k2 = red[0];
    k2 = (red[1] < k2) ? red[1] : k2;
    k2 = (red[2] < k2) ? red[2] : k2;
    k2 = (red[3] < k2) ? red[3] : k2;
    if (k2 != KEY_MAX_ULL) atomicMin(best + ci, k2);
  }
}

// ------------------------- f32 Boruvka scan (tiers b/c) ---------------------
__global__ __launch_bounds__(256)
void k_scan32(const float* __restrict__ d2, const int* __restrict__ comp,
              ull* __restrict__ best, const int* __restrict__ done) {
  if (*done) return;
  const int i = blockIdx.x;
  const int t = threadIdx.x;
  __shared__ ull red[4];
  int cj[16];
  {
    const int4* cp = (const int4*)comp;
    const int4 a0 = cp[t * 4 + 0], a1 = cp[t * 4 + 1];
    const int4 a2 = cp[t * 4 + 2], a3 = cp[t * 4 + 3];
    cj[0] = a0.x;  cj[1] = a0.y;  cj[2] = a0.z;  cj[3] = a0.w;
    cj[4] = a1.x;  cj[5] = a1.y;  cj[6] = a1.z;  cj[7] = a1.w;
    cj[8] = a2.x;  cj[9] = a2.y;  cj[10] = a2.z; cj[11] = a2.w;
    cj[12] = a3.x; cj[13] = a3.y; cj[14] = a3.z; cj[15] = a3.w;
  }
  const int ci = comp[i];
  const float* row = d2 + (size_t)i * NPTS;
  ull kmin = KEY_MAX_ULL;
#pragma unroll
  for (int q = 0; q < 4; ++q) {
    const float4 v = ((const float4*)row)[t * 4 + q];
    const float vv[4] = {v.x, v.y, v.z, v.w};
#pragma unroll
    for (int u = 0; u < 4; ++u) {
      const int j = t * 16 + q * 4 + u;
      if (cj[q * 4 + u] != ci) {
        const ull pair = (i < j) ? (((ull)i << 12) | (unsigned)j)
                                 : (((ull)j << 12) | (unsigned)i);
        const ull key = ((ull)__float_as_uint(vv[u]) << 24) | pair;
        kmin = (key < kmin) ? key : kmin;
      }
    }
  }
  for (int off = 32; off > 0; off >>= 1) {
    const ull o = __shfl_xor(kmin, off, 64);
    kmin = (o < kmin) ? o : kmin;
  }
  if ((t & 63) == 0) red[t >> 6] = kmin;
  __syncthreads();
  if (t == 0) {
    ull k2 = red[0];
    k2 = (red[1] < k2) ? red[1] : k2;
    k2 = (red[2] < k2) ? red[2] : k2;
    k2 = (red[3] < k2) ? red[3] : k2;
    if (k2 != KEY_MAX_ULL) atomicMin(best + ci, k2);
  }
}

// --------------------- Boruvka merge + dense relabel ------------------------
// Deaths recorded via EXACT f32 lookup d2[pair] (key value bits unused here).
__global__ __launch_bounds__(1024)
void k_merge(ull* __restrict__ best, int* __restrict__ comp,
             int* __restrict__ comp2, const float* __restrict__ d2,
             float* __restrict__ deaths, int* __restrict__ cnt,
             int* __restrict__ done, int* __restrict__ Cout) {
  if (*done) return;
  __shared__ int par[NPTS];
  __shared__ int hk[NPTS];
  __shared__ int redi[16];
  __shared__ int chg;
  __shared__ int cdense;
  const int t = threadIdx.x;
  ull bb[4];
#pragma unroll
  for (int s = 0; s < 4; ++s) {
    const int v = t + s * 1024;
    par[v] = comp[v];
    bb[s] = best[v];
    best[v] = KEY_MAX_ULL;
  }
  __syncthreads();
#pragma unroll
  for (int s = 0; s < 4; ++s) {
    const int v = t + s * 1024;
    const ull b2 = bb[s];
    int h;
    if (b2 == KEY_MAX_ULL) {
      h = par[v];
    } else {
      const int pair = (int)(b2 & 0xFFFFFF);
      const int a = pair >> 12, c2 = pair & 4095;
      const int ra = par[a], rb = par[c2];
      h = (ra == v) ? rb : ra;
    }
    hk[v] = h;
  }
  __syncthreads();
  bool win[4];
#pragma unroll
  for (int s = 0; s < 4; ++s) {
    const int v = t + s * 1024;
    const ull b2 = bb[s];
    win[s] = false;
    if (b2 != KEY_MAX_ULL) {
      const int so = hk[v];
      const bool mut = (hk[so] == v);
      win[s] = mut && (v < so);
      if (!mut || v < so) {
        const int pair = (int)(b2 & 0xFFFFFF);
        const int a = pair >> 12, c2 = pair & 4095;
        const float dd = d2[(size_t)a * NPTS + c2];  // exact f32
        deaths[atomicAdd(cnt, 1)] = sqrtf(fmaxf(dd, 1e-12f));
      }
    }
  }
  if (t == 0) chg = 0;
  __syncthreads();
#pragma unroll
  for (int s = 0; s < 4; ++s)
    if (win[s]) hk[t + s * 1024] = t + s * 1024;
  __syncthreads();
  for (int it = 0; it < 12; ++it) {
    int w2[4]; int ch = 0;
#pragma unroll
    for (int s = 0; s < 4; ++s) {
      const int v = t + s * 1024;
      w2[s] = hk[hk[v]];
      ch |= (w2[s] != hk[v]);
    }
    __syncthreads();
#pragma unroll
    for (int s = 0; s < 4; ++s) hk[t + s * 1024] = w2[s];
    if (ch) chg = 1;
    __syncthreads();
    const int any = chg;
    __syncthreads();
    if (t == 0) chg = 0;
    if (!any) break;
  }
  int nroot = 0;
#pragma unroll
  for (int s = 0; s < 4; ++s) {
    const int v = t + s * 1024;
    const int rv = hk[v];
    comp[v] = rv;
    nroot += (rv == v);
  }
  for (int off = 32; off > 0; off >>= 1) nroot += __shfl_xor(nroot, off, 64);
  if ((t & 63) == 0) redi[t >> 6] = nroot;
  if (t == 0) cdense = 0;
  __syncthreads();
#pragma unroll
  for (int s = 0; s < 4; ++s) {
    const int v = t + s * 1024;
    if (hk[v] == v) par[v] = atomicAdd(&cdense, 1);
  }
  __syncthreads();
#pragma unroll
  for (int s = 0; s < 4; ++s) {
    const int v = t + s * 1024;
    comp2[v] = par[hk[v]];
  }
  if (t == 0) {
    int tot = 0;
    for (int q = 0; q < 16; ++q) tot += redi[q];
    *Cout = cdense;
    if (tot == 1) *done = 1;
  }
}

// ------------------------- contraction, f16 input ---------------------------
__global__ __launch_bounds__(256)
void k_contract16(const u16* __restrict__ d16, const int* __restrict__ comp2,
                  ull* __restrict__ cd, const int* __restrict__ done) {
  if (*done) return;
  const int i = blockIdx.x;
  const int t = threadIdx.x;
  __shared__ ull tbl[256];
  tbl[t] = KEY_MAX_ULL;
  int cj[16];
  {
    const int4* cp = (const int4*)comp2;
    const int4 a0 = cp[t * 4 + 0], a1 = cp[t * 4 + 1];
    const int4 a2 = cp[t * 4 + 2], a3 = cp[t * 4 + 3];
    cj[0] = a0.x;  cj[1] = a0.y;  cj[2] = a0.z;  cj[3] = a0.w;
    cj[4] = a1.x;  cj[5] = a1.y;  cj[6] = a1.z;  cj[7] = a1.w;
    cj[8] = a2.x;  cj[9] = a2.y;  cj[10] = a2.z; cj[11] = a2.w;
    cj[12] = a3.x; cj[13] = a3.y; cj[14] = a3.z; cj[15] = a3.w;
  }
  const int ci = comp2[i];
  __syncthreads();
  const uint4* rp = (const uint4*)(d16 + (size_t)i * NPTS);
  const uint4 Aw = rp[t * 2 + 0], Bw = rp[t * 2 + 1];
  const unsigned wds[8] = {Aw.x, Aw.y, Aw.z, Aw.w, Bw.x, Bw.y, Bw.z, Bw.w};
#pragma unroll
  for (int u = 0; u < 8; ++u) {
    const int j0c = t * 16 + u * 2;
    const unsigned lo = wds[u] & 0xFFFFu;
    const unsigned hi2 = wds[u] >> 16;
    const int c0 = cj[u * 2], c1 = cj[u * 2 + 1];
    if (c0 != ci) {
      const int j = j0c;
      const ull pair = (i < j) ? (((ull)i << 12) | (unsigned)j)
                               : (((ull)j << 12) | (unsigned)i);
      atomicMin(&tbl[c0], ((ull)lo << 24) | pair);
    }
    if (c1 != ci) {
      const int j = j0c + 1;
      const ull pair = (i < j) ? (((ull)i << 12) | (unsigned)j)
                               : (((ull)j << 12) | (unsigned)i);
      atomicMin(&tbl[c1], ((ull)hi2 << 24) | pair);
    }
  }
  __syncthreads();
  const ull tv = tbl[t];
  if (tv != KEY_MAX_ULL) atomicMin(&cd[ci * 256 + t], tv);
}

// ------------------------- contraction, f32 input (tier b) ------------------
__global__ __launch_bounds__(256)
void k_contract32(const float* __restrict__ d2, const int* __restrict__ comp2,
                  ull* __restrict__ cd, const int* __restrict__ done) {
  if (*done) return;
  const int i = blockIdx.x;
  const int t = threadIdx.x;
  __shared__ ull tbl[256];
  tbl[t] = KEY_MAX_ULL;
  int cj[16];
  {
    const int4* cp = (const int4*)comp2;
    const int4 a0 = cp[t * 4 + 0], a1 = cp[t * 4 + 1];
    const int4 a2 = cp[t * 4 + 2], a3 = cp[t * 4 + 3];
    cj[0] = a0.x;  cj[1] = a0.y;  cj[2] = a0.z;  cj[3] = a0.w;
    cj[4] = a1.x;  cj[5] = a1.y;  cj[6] = a1.z;  cj[7] = a1.w;
    cj[8] = a2.x;  cj[9] = a2.y;  cj[10] = a2.z; cj[11] = a2.w;
    cj[12] = a3.x; cj[13] = a3.y; cj[14] = a3.z; cj[15] = a3.w;
  }
  const int ci = comp2[i];
  __syncthreads();
  const float* row = d2 + (size_t)i * NPTS;
#pragma unroll
  for (int q = 0; q < 4; ++q) {
    const float4 v = ((const float4*)row)[t * 4 + q];
    const float vv[4] = {v.x, v.y, v.z, v.w};
#pragma unroll
    for (int u = 0; u < 4; ++u) {
      const int j = t * 16 + q * 4 + u;
      const int c = cj[q * 4 + u];
      if (c != ci) {
        const ull pair = (i < j) ? (((ull)i << 12) | (unsigned)j)
                                 : (((ull)j << 12) | (unsigned)i);
        atomicMin(&tbl[c], ((ull)__float_as_uint(vv[u]) << 24) | pair);
      }
    }
  }
  __syncthreads();
  const ull tv = tbl[t];
  if (tv != KEY_MAX_ULL) atomicMin(&cd[ci * 256 + t], tv);
}

// ------------------------------ finish (single WG) --------------------------
__global__ __launch_bounds__(1024)
void k_finish(const ull* __restrict__ cd, const int* __restrict__ comp2,
              const int* __restrict__ Cptr, const float* __restrict__ d2,
              float* __restrict__ deaths, int* __restrict__ cnt,
              const int* __restrict__ done) {
  if (*done) return;
  __shared__ int c2[NPTS];
  __shared__ ull bst[256];
  __shared__ int lbl[256];
  __shared__ int hk2[256];
  __shared__ int mk[256];
  __shared__ int nr_sh;
  const int t = threadIdx.x;
  const int C = *Cptr;
#pragma unroll
  for (int s = 0; s < 4; ++s) c2[t + s * 1024] = comp2[t + s * 1024];
  if (t < 256) lbl[t] = t;
  __syncthreads();
  for (int round = 0; round < 9; ++round) {
    if (t < 256) { bst[t] = KEY_MAX_ULL; mk[t] = 0; }
    if (t == 0) nr_sh = 0;
    __syncthreads();
    for (int idx = t; idx < C * 256; idx += 1024) {
      const int d = idx & 255;
      if (d < C) {
        const ull k = cd[idx];
        if (k != KEY_MAX_ULL) {
          const int lc = lbl[idx >> 8], ld = lbl[d];
          if (lc != ld) atomicMin(&bst[lc], k);
        }
      }
    }
    __syncthreads();
    if (t < 256) {
      int h = t;
      const ull b = bst[t];
      if (t < C && b != KEY_MAX_ULL) {
        const int pair = (int)(b & 0xFFFFFF);
        const int a = pair >> 12, b2 = pair & 4095;
        const int sa = lbl[c2[a]], sb = lbl[c2[b2]];
        const int other = (sa == t) ? sb : sa;
        const ull bo = bst[other];
        const bool mut = (bo != KEY_MAX_ULL) && ((int)(bo & 0xFFFFFF) == pair);
        bool rec;
        if (mut) { h = (t < other) ? t : other; rec = (t < other); }
        else     { h = other;                   rec = true; }
        if (rec) {
          const float dd = d2[(size_t)a * NPTS + b2];  // exact f32
          deaths[atomicAdd(cnt, 1)] = sqrtf(fmaxf(dd, 1e-12f));
        }
      }
      hk2[t] = h;
    }
    __syncthreads();
    for (int it = 0; it < 8; ++it) {
      int w2 = 0;
      if (t < 256) w2 = hk2[hk2[t]];
      __syncthreads();
      if (t < 256) hk2[t] = w2;
      __syncthreads();
    }
    if (t < 256) lbl[t] = hk2[lbl[t]];
    __syncthreads();
    if (t < C) mk[lbl[t]] = 1;
    __syncthreads();
    if (t < 256 && mk[t]) atomicAdd(&nr_sh, 1);
    __syncthreads();
    if (nr_sh <= 1) break;
  }
}

// ------------------------------ sort (bitonic, 4096 in LDS) -----------------
__global__ __launch_bounds__(1024)
void k_sort(float* __restrict__ deaths) {
  __shared__ float s[NPTS];
  float* g = deaths + (size_t)blockIdx.x * NPTS;
  const int t = threadIdx.x;
#pragma unroll
  for (int q = 0; q < 4; ++q) s[t + q * 1024] = g[t + q * 1024];
  for (int k = 2; k <= NPTS; k <<= 1) {
    for (int j = k >> 1; j > 0; j >>= 1) {
      __syncthreads();
#pragma unroll
      for (int q = 0; q < 4; ++q) {
        const int i = t + q * 1024;
        const int ixj = i ^ j;
        if (ixj > i) {
          const float a = s[i], b = s[ixj];
          const bool up = ((i & k) == 0);
          if ((a > b) == up) { s[i] = b; s[ixj] = a; }
        }
      }
    }
  }
  __syncthreads();
#pragma unroll
  for (int q = 0; q < 4; ++q) g[t + q * 1024] = s[t + q * 1024];
}

// ------------------------------ final loss ----------------------------------
__global__ __launch_bounds__(1024)
void k_final(const float* __restrict__ deaths, float* __restrict__ out) {
  const float* a = deaths;
  const float* p = deaths + NPTS;
  const float* n = deaths + 2 * NPTS;
  const int t = threadIdx.x;
  float s1 = 0.f, s2 = 0.f;
  for (int i = t; i < NPTS - 1; i += 1024) {
    s1 += fabsf(a[i] - p[i]);
    s2 += fabsf(a[i] - n[i]);
  }
  for (int off = 32; off > 0; off >>= 1) {
    s1 += __shfl_xor(s1, off, 64);
    s2 += __shfl_xor(s2, off, 64);
  }
  __shared__ float r1[16], r2[16];
  if ((t & 63) == 0) { r1[t >> 6] = s1; r2[t >> 6] = s2; }
  __syncthreads();
  if (t == 0) {
    float t1 = 0.f, t2 = 0.f;
    for (int q = 0; q < 16; ++q) { t1 += r1[q]; t2 += r2[q]; }
    out[0] = fmaxf(t1 - t2 + 1.0f, 0.0f);
  }
}

__global__ void k_fail(float* out) { if (threadIdx.x == 0) out[0] = 0.f; }

// ------------------------------ launch --------------------------------------
extern "C" void kernel_launch(void* const* d_in, const int* in_sizes, int n_in,
                              void* d_out, int out_size, void* d_ws, size_t ws_size,
                              hipStream_t stream) {
  const float* xs[3] = {(const float*)d_in[0], (const float*)d_in[1],
                        (const float*)d_in[2]};
  char* ws = (char*)d_ws;
  const size_t d2_bytes = (size_t)NPTS * NPTS * 4;    // 64MB
  const size_t d16_bytes = (size_t)NPTS * NPTS * 2;   // 32MB
  const size_t hi_bytes = (size_t)NPTS * DIMF * 2;    // 8MB
  const size_t cd_bytes = 256 * 256 * 8;              // 512KB
  const size_t small = NPTS * 4 /*sq*/ + NPTS * 4 /*comp*/ + NPTS * 8 /*best*/ +
                       3 * NPTS * 4 /*deaths*/ + NPTS * 4 /*comp2*/ + 256;
  const size_t need_c = d2_bytes + small;                          // fp32 path
  const size_t need_b = d2_bytes + hi_bytes + cd_bytes + small;    // f16, no shadow
  const size_t need_a = need_b + d16_bytes;                        // f16 + shadow
  if (ws_size < need_c) {
    k_fail<<<1, 64, 0, stream>>>((float*)d_out);
    return;
  }
  const int tier = (ws_size >= need_a) ? 0 : (ws_size >= need_b) ? 1 : 2;
  const size_t off_hi = d2_bytes;
  const size_t off_cd = d2_bytes + hi_bytes;
  const size_t off_d16 = d2_bytes + hi_bytes + cd_bytes;
  const size_t tail0 = (tier == 0) ? (off_d16 + d16_bytes)
                     : (tier == 1) ? off_d16 : d2_bytes;

  float* d2 = (float*)ws;
  f16* hi = (f16*)(ws + off_hi);
  ull* cd = (ull*)(ws + off_cd);
  f16* d16 = (tier == 0) ? (f16*)(ws + off_d16) : nullptr;
  float* sq = (float*)(ws + tail0);
  int* comp = (int*)(ws + tail0 + NPTS * 4);
  ull* best = (ull*)(ws + tail0 + NPTS * 8);
  float* deaths = (float*)(ws + tail0 + NPTS * 16);
  int* comp2 = (int*)(ws + tail0 + NPTS * 16 + 3 * NPTS * 4);
  int* cnt = (int*)(ws + tail0 + NPTS * 16 + 3 * NPTS * 4 + NPTS * 4);
  int* done = cnt + 3;
  int* Cdev = cnt + 5;

  k_init_global<<<48, 256, 0, stream>>>(deaths, cnt);
  for (int c = 0; c < 3; ++c) {
    float* dth = deaths + c * NPTS;
    int* cn = cnt + c;
    if (tier <= 1) {
      k_prep<<<NPTS, 256, 0, stream>>>(xs[c], sq, hi, comp, best, done, cd);
      k_gemm_f16<<<dim3(NPTS / 128, NPTS / 128), 256, 0, stream>>>(hi, sq, d2,
                                                                   d16);
      for (int r = 0; r < 4; ++r) {  // 4 rounds -> C <= 256 guaranteed
        if (tier == 0)
          k_scan16<<<NPTS, 256, 0, stream>>>((const u16*)d16, comp, best, done);
        else
          k_scan32<<<NPTS, 256, 0, stream>>>(d2, comp, best, done);
        k_merge<<<1, 1024, 0, stream>>>(best, comp, comp2, d2, dth, cn, done,
                                        Cdev);
      }
      if (tier == 0)
        k_contract16<<<NPTS, 256, 0, stream>>>((const u16*)d16, comp2, cd, done);
      else
        k_contract32<<<NPTS, 256, 0, stream>>>(d2, comp2, cd, done);
      k_finish<<<1, 1024, 0, stream>>>(cd, comp2, Cdev, d2, dth, cn, done);
    } else {
      k_norms<<<NPTS, 256, 0, stream>>>(xs[c], sq);
      k_init_cloud<<<16, 256, 0, stream>>>(comp, best, done);
      k_gemm_d2<<<dim3(NPTS / BN, NPTS / BM), 256, 0, stream>>>(xs[c], sq, d2);
      for (int r = 0; r < 12; ++r) {
        k_scan32<<<NPTS, 256, 0, stream>>>(d2, comp, best, done);
        k_merge<<<1, 1024, 0, stream>>>(best, comp, comp2, d2, dth, cn, done,
                                        Cdev);
      }
    }
  }
  k_sort<<<3, 1024, 0, stream>>>(deaths);
  k_final<<<1, 1024, 0, stream>>>(deaths, (float*)d_out);
}

// Round 9
// 507.243 us; speedup vs baseline: 8.5645x; 1.2332x over previous
//
#include <hip/hip_runtime.h>
#include <stdint.h>

// ---------------------------------------------------------------------------
// TopologicalContrastiveLoss: H0 persistence (MST edge weights) of 3 point
// clouds -> 1-Wasserstein between sorted death vectors -> hinge loss.
//
// R9: no f32 d2 at all. GEMM writes only f16 d16 (33MB/cloud); MST selection
// on d16 keys (f16 monotone, pair tie-break); merges record PAIR indices;
// k_deaths3 recomputes exact fp32 deaths from the pristine inputs x.
// All 3 clouds' d16 resident simultaneously -> Boruvka rounds batched:
// one scan3 (3x4096 blocks) + one merge3 (3 blocks, parallel merges) per
// round; 4 rounds -> C<=256 -> contract3 -> finish3. 20 dispatches total.
// cd aliases the dead hi buffer (inited by the last merge3). Fence-free.
// ---------------------------------------------------------------------------

#define NPTS 4096
#define DIMF 1024
typedef unsigned short u16;
typedef _Float16 f16;
typedef unsigned long long ull;
static const ull KEY_MAX_ULL = ~0ull;

typedef f16 f16x8 __attribute__((ext_vector_type(8)));
typedef f16 f16x4v __attribute__((ext_vector_type(4)));
typedef float f32x4 __attribute__((ext_vector_type(4)));

#define GLOAD_LDS16(g, l)                                                      \
  __builtin_amdgcn_global_load_lds(                                            \
      (const __attribute__((address_space(1))) void*)(g),                      \
      (__attribute__((address_space(3))) void*)(l), 16, 0, 0)

// ------------------------------ init ---------------------------------------
// comp/best for all 3 clouds + deaths pad + counters.
__global__ void k_init_global(int* __restrict__ comp, ull* __restrict__ best,
                              float* __restrict__ deaths, int* __restrict__ cnt) {
  const int i = blockIdx.x * blockDim.x + threadIdx.x;
  if (i < 3 * NPTS) {
    comp[i] = i & (NPTS - 1);
    best[i] = KEY_MAX_ULL;
    deaths[i] = __int_as_float(0x7f800000);  // +inf
  }
  if (i < 16) cnt[i] = 0;  // cnt[0..2]=edge counters, cnt[3..5]=done, cnt[6..8]=C
}

// ------------------------------ prep: norms + f16 cast ----------------------
__global__ __launch_bounds__(256)
void k_prep(const float* __restrict__ x, float* __restrict__ sq,
            f16* __restrict__ hi) {
  const int row = blockIdx.x;
  const int t = threadIdx.x;
  const float4 v = ((const float4*)(x + (size_t)row * DIMF))[t];
  f16x4v h;
  h.x = (f16)v.x; h.y = (f16)v.y; h.z = (f16)v.z; h.w = (f16)v.w;
  ((f16x4v*)(hi + (size_t)row * DIMF))[t] = h;
  float s = v.x * v.x + v.y * v.y + v.z * v.z + v.w * v.w;
  for (int off = 32; off > 0; off >>= 1) s += __shfl_xor(s, off, 64);
  __shared__ float ws[4];
  if ((t & 63) == 0) ws[t >> 6] = s;
  __syncthreads();
  if (t == 0) sq[row] = ws[0] + ws[1] + ws[2] + ws[3];
}

// ------------------------------ fp16 MFMA GEMM -> d16 only ------------------
__global__ __launch_bounds__(256)
void k_gemm_f16(const f16* __restrict__ hi, const float* __restrict__ sq,
                f16* __restrict__ d16) {
  __shared__ u16 smem[8192];
  u16* As = smem;
  u16* Bs = smem + 4096;
  const int t = threadIdx.x;
  const int w = t >> 6, l = t & 63;
  const int wm = w >> 1, wn = w & 1;
  const int ml = l & 15, kq = l >> 4;
  const int i0 = blockIdx.y * 128, j0 = blockIdx.x * 128;

  const int srow = t >> 2, schk = t & 3;
  char* ldsA0 = (char*)As + t * 16;
  char* ldsB0 = (char*)Bs + t * 16;

  f32x4 acc[4][4];
#pragma unroll
  for (int a = 0; a < 4; ++a)
#pragma unroll
    for (int b = 0; b < 4; ++b) acc[a][b] = (f32x4)0.f;

  for (int k0 = 0; k0 < DIMF; k0 += 32) {
    __syncthreads();
    {
      const f16* ga0 = hi + (size_t)(i0 + srow) * DIMF + k0 + schk * 8;
      const f16* ga1 = hi + (size_t)(i0 + srow + 64) * DIMF + k0 + schk * 8;
      const f16* gb0 = hi + (size_t)(j0 + srow) * DIMF + k0 + schk * 8;
      const f16* gb1 = hi + (size_t)(j0 + srow + 64) * DIMF + k0 + schk * 8;
      GLOAD_LDS16(ga0, ldsA0);
      GLOAD_LDS16(ga1, ldsA0 + 4096);
      GLOAD_LDS16(gb0, ldsB0);
      GLOAD_LDS16(gb1, ldsB0 + 4096);
    }
    asm volatile("s_waitcnt vmcnt(0)" ::: "memory");
    __syncthreads();

    const char* Ab = (const char*)As + (wm * 64 + ml) * 64 + kq * 16;
    const char* Bb = (const char*)Bs + (wn * 64 + ml) * 64 + kq * 16;
    f16x8 af[4], bf[4];
#pragma unroll
    for (int mt = 0; mt < 4; ++mt) af[mt] = *(const f16x8*)(Ab + mt * 1024);
#pragma unroll
    for (int nt = 0; nt < 4; ++nt) bf[nt] = *(const f16x8*)(Bb + nt * 1024);
#pragma unroll
    for (int mt = 0; mt < 4; ++mt)
#pragma unroll
      for (int nt = 0; nt < 4; ++nt)
        acc[mt][nt] = __builtin_amdgcn_mfma_f32_16x16x32_f16(
            af[mt], bf[nt], acc[mt][nt], 0, 0, 0);
  }

  float sr[4][4], sc[4];
#pragma unroll
  for (int mt = 0; mt < 4; ++mt)
#pragma unroll
    for (int r = 0; r < 4; ++r)
      sr[mt][r] = sq[i0 + wm * 64 + mt * 16 + kq * 4 + r];
#pragma unroll
  for (int nt = 0; nt < 4; ++nt) sc[nt] = sq[j0 + wn * 64 + nt * 16 + ml];

#pragma unroll
  for (int mt = 0; mt < 4; ++mt)
#pragma unroll
    for (int nt = 0; nt < 4; ++nt) {
      const int col = j0 + wn * 64 + nt * 16 + ml;
#pragma unroll
      for (int r = 0; r < 4; ++r) {
        const int row = i0 + wm * 64 + mt * 16 + kq * 4 + r;
        const float v = fmaxf(sr[mt][r] + sc[nt] - 2.f * acc[mt][nt][r], 0.f);
        d16[(size_t)row * NPTS + col] = (f16)v;
      }
    }
}

// -------------------- batched f16 Boruvka scan (3 clouds) -------------------
__global__ __launch_bounds__(256)
void k_scan3(const u16* __restrict__ d16, const int* __restrict__ comp,
             ull* __restrict__ best, const int* __restrict__ done) {
  const int b = blockIdx.x;
  const int c = b >> 12;
  const int i = b & (NPTS - 1);
  if (done[c]) return;
  const int t = threadIdx.x;
  __shared__ ull red[4];
  const int* compc = comp + c * NPTS;
  int cj[16];
  {
    const int4* cp = (const int4*)compc;
    const int4 a0 = cp[t * 4 + 0], a1 = cp[t * 4 + 1];
    const int4 a2 = cp[t * 4 + 2], a3 = cp[t * 4 + 3];
    cj[0] = a0.x;  cj[1] = a0.y;  cj[2] = a0.z;  cj[3] = a0.w;
    cj[4] = a1.x;  cj[5] = a1.y;  cj[6] = a1.z;  cj[7] = a1.w;
    cj[8] = a2.x;  cj[9] = a2.y;  cj[10] = a2.z; cj[11] = a2.w;
    cj[12] = a3.x; cj[13] = a3.y; cj[14] = a3.z; cj[15] = a3.w;
  }
  const int ci = compc[i];
  const uint4* rp =
      (const uint4*)(d16 + (size_t)c * NPTS * NPTS + (size_t)i * NPTS);
  const uint4 Aw = rp[t * 2 + 0], Bw = rp[t * 2 + 1];
  const unsigned wds[8] = {Aw.x, Aw.y, Aw.z, Aw.w, Bw.x, Bw.y, Bw.z, Bw.w};
  ull kmin = KEY_MAX_ULL;
#pragma unroll
  for (int u = 0; u < 8; ++u) {
    const int j0c = t * 16 + u * 2;
    const unsigned lo = wds[u] & 0xFFFFu;
    const unsigned hi2 = wds[u] >> 16;
    if (cj[u * 2] != ci) {
      const int j = j0c;
      const ull pair = (i < j) ? (((ull)i << 12) | (unsigned)j)
                               : (((ull)j << 12) | (unsigned)i);
      const ull key = ((ull)lo << 24) | pair;
      kmin = (key < kmin) ? key : kmin;
    }
    if (cj[u * 2 + 1] != ci) {
      const int j = j0c + 1;
      const ull pair = (i < j) ? (((ull)i << 12) | (unsigned)j)
                               : (((ull)j << 12) | (unsigned)i);
      const ull key = ((ull)hi2 << 24) | pair;
      kmin = (key < kmin) ? key : kmin;
    }
  }
  for (int off = 32; off > 0; off >>= 1) {
    const ull o = __shfl_xor(kmin, off, 64);
    kmin = (o < kmin) ? o : kmin;
  }
  if ((t & 63) == 0) red[t >> 6] = kmin;
  __syncthreads();
  if (t == 0) {
    ull k2 = red[0];
    k2 = (red[1] < k2) ? red[1] : k2;
    k2 = (red[2] < k2) ? red[2] : k2;
    k2 = (red[3] < k2) ? red[3] : k2;
    if (k2 != KEY_MAX_ULL) atomicMin(best + c * NPTS + ci, k2);
  }
}

// -------------- batched merge (3 blocks; records PAIR indices) --------------
__global__ __launch_bounds__(1024)
void k_merge3(ull* __restrict__ best, int* __restrict__ comp,
              int* __restrict__ comp2, int* __restrict__ pairs,
              int* __restrict__ cnt, int* __restrict__ done,
              int* __restrict__ Cdev, ull* __restrict__ cd, int initCd) {
  const int c = blockIdx.x;
  if (done[c]) return;
  ull* bestc = best + c * NPTS;
  int* compc = comp + c * NPTS;
  int* comp2c = comp2 + c * NPTS;
  int* pairsc = pairs + c * NPTS;
  __shared__ int par[NPTS];
  __shared__ int hk[NPTS];
  __shared__ int redi[16];
  __shared__ int chg;
  __shared__ int cdense;
  const int t = threadIdx.x;
  ull bb[4];
#pragma unroll
  for (int s = 0; s < 4; ++s) {
    const int v = t + s * 1024;
    par[v] = compc[v];
    bb[s] = bestc[v];
    bestc[v] = KEY_MAX_ULL;
  }
  __syncthreads();
#pragma unroll
  for (int s = 0; s < 4; ++s) {
    const int v = t + s * 1024;
    const ull b2 = bb[s];
    int h;
    if (b2 == KEY_MAX_ULL) {
      h = par[v];
    } else {
      const int pair = (int)(b2 & 0xFFFFFF);
      const int a = pair >> 12, c2 = pair & 4095;
      const int ra = par[a], rb = par[c2];
      h = (ra == v) ? rb : ra;
    }
    hk[v] = h;
  }
  __syncthreads();
  bool win[4];
#pragma unroll
  for (int s = 0; s < 4; ++s) {
    const int v = t + s * 1024;
    const ull b2 = bb[s];
    win[s] = false;
    if (b2 != KEY_MAX_ULL) {
      const int so = hk[v];
      const bool mut = (hk[so] == v);
      win[s] = mut && (v < so);
      if (!mut || v < so)
        pairsc[atomicAdd(cnt + c, 1)] = (int)(b2 & 0xFFFFFF);
    }
  }
  if (t == 0) chg = 0;
  __syncthreads();
#pragma unroll
  for (int s = 0; s < 4; ++s)
    if (win[s]) hk[t + s * 1024] = t + s * 1024;
  __syncthreads();
  for (int it = 0; it < 12; ++it) {
    int w2[4]; int ch = 0;
#pragma unroll
    for (int s = 0; s < 4; ++s) {
      const int v = t + s * 1024;
      w2[s] = hk[hk[v]];
      ch |= (w2[s] != hk[v]);
    }
    __syncthreads();
#pragma unroll
    for (int s = 0; s < 4; ++s) hk[t + s * 1024] = w2[s];
    if (ch) chg = 1;
    __syncthreads();
    const int any = chg;
    __syncthreads();
    if (t == 0) chg = 0;
    if (!any) break;
  }
  int nroot = 0;
#pragma unroll
  for (int s = 0; s < 4; ++s) {
    const int v = t + s * 1024;
    const int rv = hk[v];
    compc[v] = rv;
    nroot += (rv == v);
  }
  for (int off = 32; off > 0; off >>= 1) nroot += __shfl_xor(nroot, off, 64);
  if ((t & 63) == 0) redi[t >> 6] = nroot;
  if (t == 0) cdense = 0;
  __syncthreads();
#pragma unroll
  for (int s = 0; s < 4; ++s) {
    const int v = t + s * 1024;
    if (hk[v] == v) par[v] = atomicAdd(&cdense, 1);
  }
  __syncthreads();
#pragma unroll
  for (int s = 0; s < 4; ++s) {
    const int v = t + s * 1024;
    comp2c[v] = par[hk[v]];
  }
  if (initCd) {  // cd aliases hi (dead after GEMMs); init this cloud's slice
    ull* cdc = cd + (size_t)c * 65536;
    for (int q = t; q < 65536; q += 1024) cdc[q] = KEY_MAX_ULL;
  }
  if (t == 0) {
    int tot = 0;
    for (int q = 0; q < 16; ++q) tot += redi[q];
    Cdev[c] = cdense;
    if (tot == 1) done[c] = 1;
  }
}

// ---------------------- batched contraction (f16 input) ---------------------
__global__ __launch_bounds__(256)
void k_contract3(const u16* __restrict__ d16, const int* __restrict__ comp2,
                 ull* __restrict__ cd, const int* __restrict__ done) {
  const int b = blockIdx.x;
  const int c = b >> 12;
  const int i = b & (NPTS - 1);
  if (done[c]) return;
  const int t = threadIdx.x;
  __shared__ ull tbl[256];
  tbl[t] = KEY_MAX_ULL;
  const int* comp2c = comp2 + c * NPTS;
  int cj[16];
  {
    const int4* cp = (const int4*)comp2c;
    const int4 a0 = cp[t * 4 + 0], a1 = cp[t * 4 + 1];
    const int4 a2 = cp[t * 4 + 2], a3 = cp[t * 4 + 3];
    cj[0] = a0.x;  cj[1] = a0.y;  cj[2] = a0.z;  cj[3] = a0.w;
    cj[4] = a1.x;  cj[5] = a1.y;  cj[6] = a1.z;  cj[7] = a1.w;
    cj[8] = a2.x;  cj[9] = a2.y;  cj[10] = a2.z; cj[11] = a2.w;
    cj[12] = a3.x; cj[13] = a3.y; cj[14] = a3.z; cj[15] = a3.w;
  }
  const int ci = comp2c[i];
  __syncthreads();
  const uint4* rp =
      (const uint4*)(d16 + (size_t)c * NPTS * NPTS + (size_t)i * NPTS);
  const uint4 Aw = rp[t * 2 + 0], Bw = rp[t * 2 + 1];
  const unsigned wds[8] = {Aw.x, Aw.y, Aw.z, Aw.w, Bw.x, Bw.y, Bw.z, Bw.w};
#pragma unroll
  for (int u = 0; u < 8; ++u) {
    const int j0c = t * 16 + u * 2;
    const unsigned lo = wds[u] & 0xFFFFu;
    const unsigned hi2 = wds[u] >> 16;
    const int c0 = cj[u * 2], c1 = cj[u * 2 + 1];
    if (c0 != ci) {
      const int j = j0c;
      const ull pair = (i < j) ? (((ull)i << 12) | (unsigned)j)
                               : (((ull)j << 12) | (unsigned)i);
      atomicMin(&tbl[c0], ((ull)lo << 24) | pair);
    }
    if (c1 != ci) {
      const int j = j0c + 1;
      const ull pair = (i < j) ? (((ull)i << 12) | (unsigned)j)
                               : (((ull)j << 12) | (unsigned)i);
      atomicMin(&tbl[c1], ((ull)hi2 << 24) | pair);
    }
  }
  __syncthreads();
  const ull tv = tbl[t];
  if (tv != KEY_MAX_ULL) atomicMin(&cd[(size_t)c * 65536 + ci * 256 + t], tv);
}

// --------------------- batched finish (3 single-WG blocks) ------------------
__global__ __launch_bounds__(1024)
void k_finish3(const ull* __restrict__ cd, const int* __restrict__ comp2,
               const int* __restrict__ Cdev, int* __restrict__ pairs,
               int* __restrict__ cnt, const int* __restrict__ done) {
  const int c = blockIdx.x;
  if (done[c]) return;
  const ull* cdc = cd + (size_t)c * 65536;
  const int* comp2c = comp2 + c * NPTS;
  int* pairsc = pairs + c * NPTS;
  __shared__ int c2[NPTS];
  __shared__ ull bst[256];
  __shared__ int lbl[256];
  __shared__ int hk2[256];
  __shared__ int mk[256];
  __shared__ int nr_sh;
  const int t = threadIdx.x;
  const int C = Cdev[c];
#pragma unroll
  for (int s = 0; s < 4; ++s) c2[t + s * 1024] = comp2c[t + s * 1024];
  if (t < 256) lbl[t] = t;
  __syncthreads();
  for (int round = 0; round < 9; ++round) {
    if (t < 256) { bst[t] = KEY_MAX_ULL; mk[t] = 0; }
    if (t == 0) nr_sh = 0;
    __syncthreads();
    for (int idx = t; idx < C * 256; idx += 1024) {
      const int d = idx & 255;
      if (d < C) {
        const ull k = cdc[idx];
        if (k != KEY_MAX_ULL) {
          const int lc = lbl[idx >> 8], ld = lbl[d];
          if (lc != ld) atomicMin(&bst[lc], k);
        }
      }
    }
    __syncthreads();
    if (t < 256) {
      int h = t;
      const ull b = bst[t];
      if (t < C && b != KEY_MAX_ULL) {
        const int pair = (int)(b & 0xFFFFFF);
        const int a = pair >> 12, b2 = pair & 4095;
        const int sa = lbl[c2[a]], sb = lbl[c2[b2]];
        const int other = (sa == t) ? sb : sa;
        const ull bo = bst[other];
        const bool mut = (bo != KEY_MAX_ULL) && ((int)(bo & 0xFFFFFF) == pair);
        bool rec;
        if (mut) { h = (t < other) ? t : other; rec = (t < other); }
        else     { h = other;                   rec = true; }
        if (rec) pairsc[atomicAdd(cnt + c, 1)] = pair;
      }
      hk2[t] = h;
    }
    __syncthreads();
    for (int it = 0; it < 8; ++it) {
      int w2 = 0;
      if (t < 256) w2 = hk2[hk2[t]];
      __syncthreads();
      if (t < 256) hk2[t] = w2;
      __syncthreads();
    }
    if (t < 256) lbl[t] = hk2[lbl[t]];
    __syncthreads();
    if (t < C) mk[lbl[t]] = 1;
    __syncthreads();
    if (t < 256 && mk[t]) atomicAdd(&nr_sh, 1);
    __syncthreads();
    if (nr_sh <= 1) break;
  }
}

// ------------------ exact deaths from pristine fp32 inputs ------------------
__global__ __launch_bounds__(256)
void k_deaths3(const float* __restrict__ x0, const float* __restrict__ x1,
               const float* __restrict__ x2, const float* __restrict__ sq,
               const int* __restrict__ pairs, float* __restrict__ deaths) {
  const int b = blockIdx.x;
  const int c = b >> 12;
  const int s = b & (NPTS - 1);
  if (s >= NPTS - 1) return;  // 4095 real edges per cloud
  const int t = threadIdx.x;
  const int pr = pairs[c * NPTS + s];
  const int a = pr >> 12, e = pr & 4095;
  const float* X = (c == 0) ? x0 : (c == 1) ? x1 : x2;
  const float4 va = ((const float4*)(X + (size_t)a * DIMF))[t];
  const float4 vb = ((const float4*)(X + (size_t)e * DIMF))[t];
  float d = va.x * vb.x + va.y * vb.y + va.z * vb.z + va.w * vb.w;
  for (int off = 32; off > 0; off >>= 1) d += __shfl_xor(d, off, 64);
  __shared__ float ws[4];
  if ((t & 63) == 0) ws[t >> 6] = d;
  __syncthreads();
  if (t == 0) {
    const float dot = ws[0] + ws[1] + ws[2] + ws[3];
    const float dd = sq[c * NPTS + a] + sq[c * NPTS + e] - 2.f * dot;
    deaths[c * NPTS + s] = sqrtf(fmaxf(dd, 1e-12f));
  }
}

// ------------------------------ sort (bitonic, 4096 in LDS) -----------------
__global__ __launch_bounds__(1024)
void k_sort(float* __restrict__ deaths) {
  __shared__ float s[NPTS];
  float* g = deaths + (size_t)blockIdx.x * NPTS;
  const int t = threadIdx.x;
#pragma unroll
  for (int q = 0; q < 4; ++q) s[t + q * 1024] = g[t + q * 1024];
  for (int k = 2; k <= NPTS; k <<= 1) {
    for (int j = k >> 1; j > 0; j >>= 1) {
      __syncthreads();
#pragma unroll
      for (int q = 0; q < 4; ++q) {
        const int i = t + q * 1024;
        const int ixj = i ^ j;
        if (ixj > i) {
          const float a = s[i], b = s[ixj];
          const bool up = ((i & k) == 0);
          if ((a > b) == up) { s[i] = b; s[ixj] = a; }
        }
      }
    }
  }
  __syncthreads();
#pragma unroll
  for (int q = 0; q < 4; ++q) g[t + q * 1024] = s[t + q * 1024];
}

// ------------------------------ final loss ----------------------------------
__global__ __launch_bounds__(1024)
void k_final(const float* __restrict__ deaths, float* __restrict__ out) {
  const float* a = deaths;
  const float* p = deaths + NPTS;
  const float* n = deaths + 2 * NPTS;
  const int t = threadIdx.x;
  float s1 = 0.f, s2 = 0.f;
  for (int i = t; i < NPTS - 1; i += 1024) {
    s1 += fabsf(a[i] - p[i]);
    s2 += fabsf(a[i] - n[i]);
  }
  for (int off = 32; off > 0; off >>= 1) {
    s1 += __shfl_xor(s1, off, 64);
    s2 += __shfl_xor(s2, off, 64);
  }
  __shared__ float r1[16], r2[16];
  if ((t & 63) == 0) { r1[t >> 6] = s1; r2[t >> 6] = s2; }
  __syncthreads();
  if (t == 0) {
    float t1 = 0.f, t2 = 0.f;
    for (int q = 0; q < 16; ++q) { t1 += r1[q]; t2 += r2[q]; }
    out[0] = fmaxf(t1 - t2 + 1.0f, 0.0f);
  }
}

// ---------------------- fp32 fallback path (small ws) -----------------------
__global__ __launch_bounds__(256)
void k_norms(const float* __restrict__ x, float* __restrict__ sq) {
  const int row = blockIdx.x;
  const int t = threadIdx.x;
  const float4 v = ((const float4*)(x + (size_t)row * DIMF))[t];
  float s = v.x * v.x + v.y * v.y + v.z * v.z + v.w * v.w;
  for (int off = 32; off > 0; off >>= 1) s += __shfl_xor(s, off, 64);
  __shared__ float ws[4];
  if ((t & 63) == 0) ws[t >> 6] = s;
  __syncthreads();
  if (t == 0) sq[row] = ws[0] + ws[1] + ws[2] + ws[3];
}

__global__ void k_init_cloud(int* __restrict__ comp, ull* __restrict__ best,
                             int* __restrict__ done) {
  int i = blockIdx.x * blockDim.x + threadIdx.x;
  if (i < NPTS) { comp[i] = i; best[i] = KEY_MAX_ULL; }
  if (i == 0) *done = 0;
}

#define BM 128
#define BN 128
#define BK 16
__global__ __launch_bounds__(256)
void k_gemm_d2(const float* __restrict__ X, const float* __restrict__ sq,
               float* __restrict__ d2) {
  __shared__ float As[BK][BM];
  __shared__ float Bs[BK][BN];
  const int tid = threadIdx.x;
  const int tx = tid & 15, ty = tid >> 4;
  const int i0 = blockIdx.y * BM, j0 = blockIdx.x * BN;
  float acc[8][8] = {};
  for (int k0 = 0; k0 < DIMF; k0 += BK) {
#pragma unroll
    for (int id = tid; id < 512; id += 256) {
      const int row = id >> 2;
      const int kk = (id & 3) << 2;
      const float4 a = *(const float4*)(X + (size_t)(i0 + row) * DIMF + k0 + kk);
      const float4 b = *(const float4*)(X + (size_t)(j0 + row) * DIMF + k0 + kk);
      As[kk + 0][row] = a.x; As[kk + 1][row] = a.y;
      As[kk + 2][row] = a.z; As[kk + 3][row] = a.w;
      Bs[kk + 0][row] = b.x; Bs[kk + 1][row] = b.y;
      Bs[kk + 2][row] = b.z; Bs[kk + 3][row] = b.w;
    }
    __syncthreads();
#pragma unroll
    for (int kk = 0; kk < BK; ++kk) {
      float a[8], b[8];
#pragma unroll
      for (int m = 0; m < 8; ++m) a[m] = As[kk][ty * 8 + m];
#pragma unroll
      for (int n = 0; n < 8; ++n) b[n] = Bs[kk][tx * 8 + n];
#pragma unroll
      for (int m = 0; m < 8; ++m)
#pragma unroll
        for (int n = 0; n < 8; ++n)
          acc[m][n] = fmaf(a[m], b[n], acc[m][n]);
    }
    __syncthreads();
  }
#pragma unroll
  for (int m = 0; m < 8; ++m) {
    const int i = i0 + ty * 8 + m;
    const float si = sq[i];
    const int j = j0 + tx * 8;
    float4 o0, o1;
    o0.x = fmaxf(si + sq[j + 0] - 2.f * acc[m][0], 0.f);
    o0.y = fmaxf(si + sq[j + 1] - 2.f * acc[m][1], 0.f);
    o0.z = fmaxf(si + sq[j + 2] - 2.f * acc[m][2], 0.f);
    o0.w = fmaxf(si + sq[j + 3] - 2.f * acc[m][3], 0.f);
    o1.x = fmaxf(si + sq[j + 4] - 2.f * acc[m][4], 0.f);
    o1.y = fmaxf(si + sq[j + 5] - 2.f * acc[m][5], 0.f);
    o1.z = fmaxf(si + sq[j + 6] - 2.f * acc[m][6], 0.f);
    o1.w = fmaxf(si + sq[j + 7] - 2.f * acc[m][7], 0.f);
    *(float4*)(d2 + (size_t)i * NPTS + j) = o0;
    *(float4*)(d2 + (size_t)i * NPTS + j + 4) = o1;
  }
}

__global__ __launch_bounds__(256)
void k_scan32(const float* __restrict__ d2, const int* __restrict__ comp,
              ull* __restrict__ best, const int* __restrict__ done) {
  if (*done) return;
  const int i = blockIdx.x;
  const int t = threadIdx.x;
  __shared__ ull red[4];
  int cj[16];
  {
    const int4* cp = (const int4*)comp;
    const int4 a0 = cp[t * 4 + 0], a1 = cp[t * 4 + 1];
    const int4 a2 = cp[t * 4 + 2], a3 = cp[t * 4 + 3];
    cj[0] = a0.x;  cj[1] = a0.y;  cj[2] = a0.z;  cj[3] = a0.w;
    cj[4] = a1.x;  cj[5] = a1.y;  cj[6] = a1.z;  cj[7] = a1.w;
    cj[8] = a2.x;  cj[9] = a2.y;  cj[10] = a2.z; cj[11] = a2.w;
    cj[12] = a3.x; cj[13] = a3.y; cj[14] = a3.z; cj[15] = a3.w;
  }
  const int ci = comp[i];
  const float* row = d2 + (size_t)i * NPTS;
  ull kmin = KEY_MAX_ULL;
#pragma unroll
  for (int q = 0; q < 4; ++q) {
    const float4 v = ((const float4*)row)[t * 4 + q];
    const float vv[4] = {v.x, v.y, v.z, v.w};
#pragma unroll
    for (int u = 0; u < 4; ++u) {
      const int j = t * 16 + q * 4 + u;
      if (cj[q * 4 + u] != ci) {
        const ull pair = (i < j) ? (((ull)i << 12) | (unsigned)j)
                                 : (((ull)j << 12) | (unsigned)i);
        const ull key = ((ull)__float_as_uint(vv[u]) << 24) | pair;
        kmin = (key < kmin) ? key : kmin;
      }
    }
  }
  for (int off = 32; off > 0; off >>= 1) {
    const ull o = __shfl_xor(kmin, off, 64);
    kmin = (o < kmin) ? o : kmin;
  }
  if ((t & 63) == 0) red[t >> 6] = kmin;
  __syncthreads();
  if (t == 0) {
    ull k2 = red[0];
    k2 = (red[1] < k2) ? red[1] : k2;
    k2 = (red[2] < k2) ? red[2] : k2;
    k2 = (red[3] < k2) ? red[3] : k2;
    if (k2 != KEY_MAX_ULL) atomicMin(best + ci, k2);
  }
}

__global__ __launch_bounds__(1024)
void k_merge1(ull* __restrict__ best, int* __restrict__ comp,
              const float* __restrict__ d2, float* __restrict__ deaths,
              int* __restrict__ cnt, int* __restrict__ done) {
  if (*done) return;
  __shared__ int par[NPTS];
  __shared__ int hk[NPTS];
  __shared__ int redi[16];
  const int t = threadIdx.x;
  ull bb[4];
#pragma unroll
  for (int s = 0; s < 4; ++s) {
    const int v = t + s * 1024;
    par[v] = comp[v];
    bb[s] = best[v];
    best[v] = KEY_MAX_ULL;
  }
  __syncthreads();
#pragma unroll
  for (int s = 0; s < 4; ++s) {
    const int v = t + s * 1024;
    const ull b2 = bb[s];
    int h;
    if (b2 == KEY_MAX_ULL) {
      h = par[v];
    } else {
      const int pair = (int)(b2 & 0xFFFFFF);
      const int a = pair >> 12, c2 = pair & 4095;
      const int ra = par[a], rb = par[c2];
      h = (ra == v) ? rb : ra;
    }
    hk[v] = h;
  }
  __syncthreads();
  bool win[4];
#pragma unroll
  for (int s = 0; s < 4; ++s) {
    const int v = t + s * 1024;
    const ull b2 = bb[s];
    win[s] = false;
    if (b2 != KEY_MAX_ULL) {
      const int so = hk[v];
      const bool mut = (hk[so] == v);
      win[s] = mut && (v < so);
      if (!mut || v < so) {
        const int pair = (int)(b2 & 0xFFFFFF);
        const float dd = d2[(size_t)(pair >> 12) * NPTS + (pair & 4095)];
        deaths[atomicAdd(cnt, 1)] = sqrtf(fmaxf(dd, 1e-12f));
      }
    }
  }
  __syncthreads();
#pragma unroll
  for (int s = 0; s < 4; ++s)
    if (win[s]) hk[t + s * 1024] = t + s * 1024;
  __syncthreads();
  for (int it = 0; it < 12; ++it) {
    int w2[4];
#pragma unroll
    for (int s = 0; s < 4; ++s) w2[s] = hk[hk[t + s * 1024]];
    __syncthreads();
#pragma unroll
    for (int s = 0; s < 4; ++s) hk[t + s * 1024] = w2[s];
    __syncthreads();
  }
  int nroot = 0;
#pragma unroll
  for (int s = 0; s < 4; ++s) {
    const int v = t + s * 1024;
    const int rv = hk[v];
    comp[v] = rv;
    nroot += (rv == v);
  }
  for (int off = 32; off > 0; off >>= 1) nroot += __shfl_xor(nroot, off, 64);
  if ((t & 63) == 0) redi[t >> 6] = nroot;
  __syncthreads();
  if (t == 0) {
    int tot = 0;
    for (int q = 0; q < 16; ++q) tot += redi[q];
    if (tot == 1) *done = 1;
  }
}

__global__ void k_fail(float* out) { if (threadIdx.x == 0) out[0] = 0.f; }

// ------------------------------ launch --------------------------------------
extern "C" void kernel_launch(void* const* d_in, const int* in_sizes, int n_in,
                              void* d_out, int out_size, void* d_ws, size_t ws_size,
                              hipStream_t stream) {
  const float* xs[3] = {(const float*)d_in[0], (const float*)d_in[1],
                        (const float*)d_in[2]};
  char* ws = (char*)d_ws;
  const size_t d16_one = (size_t)NPTS * NPTS * 2;      // 32MB
  const size_t d16_all = 3 * d16_one;                  // 96MB
  const size_t hi_bytes = (size_t)NPTS * DIMF * 2;     // 8MB (cd aliases this)
  const size_t tail_new = 3 * NPTS * 4 /*sq*/ + 3 * NPTS * 4 /*comp*/ +
                          3 * NPTS * 4 /*comp2*/ + 3 * NPTS * 8 /*best*/ +
                          3 * NPTS * 4 /*deaths*/ + 3 * NPTS * 4 /*pairs*/ + 128;
  const size_t need_new = d16_all + hi_bytes + tail_new;        // ~109.4MB
  const size_t d2_bytes = (size_t)NPTS * NPTS * 4;              // 64MB
  const size_t small_old = NPTS * 4 + NPTS * 4 + NPTS * 8 + 3 * NPTS * 4 + 128;
  const size_t need_old = d2_bytes + small_old;

  if (ws_size >= need_new) {
    f16* d16 = (f16*)ws;
    f16* hi = (f16*)(ws + d16_all);
    ull* cd = (ull*)(ws + d16_all);  // alias: hi dead after GEMMs
    char* tp = ws + d16_all + hi_bytes;
    float* sq = (float*)tp;                    tp += 3 * NPTS * 4;
    int* comp = (int*)tp;                      tp += 3 * NPTS * 4;
    int* comp2 = (int*)tp;                     tp += 3 * NPTS * 4;
    ull* best = (ull*)tp;                      tp += 3 * NPTS * 8;
    float* deaths = (float*)tp;                tp += 3 * NPTS * 4;
    int* pairs = (int*)tp;                     tp += 3 * NPTS * 4;
    int* cnt = (int*)tp;  // cnt[0..2], done = cnt+3, C = cnt+6
    int* done = cnt + 3;
    int* Cdev = cnt + 6;

    k_init_global<<<48, 256, 0, stream>>>(comp, best, deaths, cnt);
    for (int c = 0; c < 3; ++c) {
      k_prep<<<NPTS, 256, 0, stream>>>(xs[c], sq + c * NPTS, hi);
      k_gemm_f16<<<dim3(NPTS / 128, NPTS / 128), 256, 0, stream>>>(
          hi, sq + c * NPTS, d16 + (size_t)c * NPTS * NPTS);
    }
    for (int r = 0; r < 4; ++r) {  // 4 rounds -> C <= 256 guaranteed
      k_scan3<<<3 * NPTS, 256, 0, stream>>>((const u16*)d16, comp, best, done);
      k_merge3<<<3, 1024, 0, stream>>>(best, comp, comp2, pairs, cnt, done,
                                       Cdev, cd, (r == 3) ? 1 : 0);
    }
    k_contract3<<<3 * NPTS, 256, 0, stream>>>((const u16*)d16, comp2, cd, done);
    k_finish3<<<3, 1024, 0, stream>>>(cd, comp2, Cdev, pairs, cnt, done);
    k_deaths3<<<3 * NPTS, 256, 0, stream>>>(xs[0], xs[1], xs[2], sq, pairs,
                                            deaths);
    k_sort<<<3, 1024, 0, stream>>>(deaths);
    k_final<<<1, 1024, 0, stream>>>(deaths, (float*)d_out);
  } else if (ws_size >= need_old) {
    float* d2 = (float*)ws;
    char* tp = ws + d2_bytes;
    float* sq = (float*)tp;                    tp += NPTS * 4;
    int* comp = (int*)tp;                      tp += NPTS * 4;
    ull* best = (ull*)tp;                      tp += NPTS * 8;
    float* deaths = (float*)tp;                tp += 3 * NPTS * 4;
    int* cnt = (int*)tp;
    int* done = cnt + 3;
    // init deaths/cnt via k_init_global-compatible call is not layout-safe
    // here; use dedicated inits.
    k_init_cloud<<<16, 256, 0, stream>>>(comp, best, done);  // also zero done
    // deaths +inf fill
    {
      // reuse k_fail? simplest: small init inline via k_init_cloud pattern
    }
    // deaths init: use hipMemsetAsync to 0x7f7f? Not +inf; do a tiny kernel:
    k_norms<<<NPTS, 256, 0, stream>>>(xs[0], sq);  // placeholder order fixed below
    // (fallback path, correctness-first)
    // full sequence:
    // init deaths
    struct {} _;
    (void)_;
    // deaths fill kernel:
    // (defined below via lambda-less approach: reuse k_init_global on scratch)
    k_init_global<<<48, 256, 0, stream>>>(comp, best, deaths, cnt);
    for (int c = 0; c < 3; ++c) {
      k_norms<<<NPTS, 256, 0, stream>>>(xs[c], sq);
      k_init_cloud<<<16, 256, 0, stream>>>(comp, best, done);
      k_gemm_d2<<<dim3(NPTS / BN, NPTS / BM), 256, 0, stream>>>(xs[c], sq, d2);
      for (int r = 0; r < 12; ++r) {
        k_scan32<<<NPTS, 256, 0, stream>>>(d2, comp, best, done);
        k_merge1<<<1, 1024, 0, stream>>>(best, comp, d2, deaths + c * NPTS,
                                         cnt + c, done);
      }
    }
    k_sort<<<3, 1024, 0, stream>>>(deaths);
    k_final<<<1, 1024, 0, stream>>>(deaths, (float*)d_out);
  } else {
    k_fail<<<1, 64, 0, stream>>>((float*)d_out);
  }
}

// Round 10
// 461.285 us; speedup vs baseline: 9.4178x; 1.0996x over previous
//
#include <hip/hip_runtime.h>
#include <stdint.h>

// ---------------------------------------------------------------------------
// TopologicalContrastiveLoss: H0 persistence (MST edge weights) of 3 point
// clouds -> 1-Wasserstein between sorted death vectors -> hinge loss.
//
// R10 = R9 skeleton (f16-only d16, batched 3-cloud Boruvka, pair-recorded
// exact deaths) +
//  (a) adaptive round skip: scan3/merge3 gate on Cdev[c] > 256 (typical case
//      finishes in 3 rounds -> saves one full 96MB sweep); cd init moved to
//      round-0 merge (always runs)
//  (b) scan3 does 2 rows/block: 4 outstanding 16B loads/thread vs 2 (the
//      R9 counter showed scans L3-latency-bound: 74us, VALU 17%, HBM 5.7%)
// ---------------------------------------------------------------------------

#define NPTS 4096
#define DIMF 1024
typedef unsigned short u16;
typedef _Float16 f16;
typedef unsigned long long ull;
static const ull KEY_MAX_ULL = ~0ull;

typedef f16 f16x8 __attribute__((ext_vector_type(8)));
typedef f16 f16x4v __attribute__((ext_vector_type(4)));
typedef float f32x4 __attribute__((ext_vector_type(4)));

#define GLOAD_LDS16(g, l)                                                      \
  __builtin_amdgcn_global_load_lds(                                            \
      (const __attribute__((address_space(1))) void*)(g),                      \
      (__attribute__((address_space(3))) void*)(l), 16, 0, 0)

// ------------------------------ init ---------------------------------------
__global__ void k_init_global(int* __restrict__ comp, ull* __restrict__ best,
                              float* __restrict__ deaths, int* __restrict__ cnt) {
  const int i = blockIdx.x * blockDim.x + threadIdx.x;
  if (i < 3 * NPTS) {
    comp[i] = i & (NPTS - 1);
    best[i] = KEY_MAX_ULL;
    deaths[i] = __int_as_float(0x7f800000);  // +inf
  }
  // cnt[0..2]=edge counters, cnt[3..5]=done, cnt[6..8]=C (start at NPTS)
  if (i < 16) cnt[i] = (i >= 6 && i < 9) ? NPTS : 0;
}

// ------------------------------ prep: norms + f16 cast ----------------------
__global__ __launch_bounds__(256)
void k_prep(const float* __restrict__ x, float* __restrict__ sq,
            f16* __restrict__ hi) {
  const int row = blockIdx.x;
  const int t = threadIdx.x;
  const float4 v = ((const float4*)(x + (size_t)row * DIMF))[t];
  f16x4v h;
  h.x = (f16)v.x; h.y = (f16)v.y; h.z = (f16)v.z; h.w = (f16)v.w;
  ((f16x4v*)(hi + (size_t)row * DIMF))[t] = h;
  float s = v.x * v.x + v.y * v.y + v.z * v.z + v.w * v.w;
  for (int off = 32; off > 0; off >>= 1) s += __shfl_xor(s, off, 64);
  __shared__ float ws[4];
  if ((t & 63) == 0) ws[t >> 6] = s;
  __syncthreads();
  if (t == 0) sq[row] = ws[0] + ws[1] + ws[2] + ws[3];
}

// ------------------------------ fp16 MFMA GEMM -> d16 only ------------------
__global__ __launch_bounds__(256)
void k_gemm_f16(const f16* __restrict__ hi, const float* __restrict__ sq,
                f16* __restrict__ d16) {
  __shared__ u16 smem[8192];
  u16* As = smem;
  u16* Bs = smem + 4096;
  const int t = threadIdx.x;
  const int w = t >> 6, l = t & 63;
  const int wm = w >> 1, wn = w & 1;
  const int ml = l & 15, kq = l >> 4;
  const int i0 = blockIdx.y * 128, j0 = blockIdx.x * 128;

  const int srow = t >> 2, schk = t & 3;
  char* ldsA0 = (char*)As + t * 16;
  char* ldsB0 = (char*)Bs + t * 16;

  f32x4 acc[4][4];
#pragma unroll
  for (int a = 0; a < 4; ++a)
#pragma unroll
    for (int b = 0; b < 4; ++b) acc[a][b] = (f32x4)0.f;

  for (int k0 = 0; k0 < DIMF; k0 += 32) {
    __syncthreads();
    {
      const f16* ga0 = hi + (size_t)(i0 + srow) * DIMF + k0 + schk * 8;
      const f16* ga1 = hi + (size_t)(i0 + srow + 64) * DIMF + k0 + schk * 8;
      const f16* gb0 = hi + (size_t)(j0 + srow) * DIMF + k0 + schk * 8;
      const f16* gb1 = hi + (size_t)(j0 + srow + 64) * DIMF + k0 + schk * 8;
      GLOAD_LDS16(ga0, ldsA0);
      GLOAD_LDS16(ga1, ldsA0 + 4096);
      GLOAD_LDS16(gb0, ldsB0);
      GLOAD_LDS16(gb1, ldsB0 + 4096);
    }
    asm volatile("s_waitcnt vmcnt(0)" ::: "memory");
    __syncthreads();

    const char* Ab = (const char*)As + (wm * 64 + ml) * 64 + kq * 16;
    const char* Bb = (const char*)Bs + (wn * 64 + ml) * 64 + kq * 16;
    f16x8 af[4], bf[4];
#pragma unroll
    for (int mt = 0; mt < 4; ++mt) af[mt] = *(const f16x8*)(Ab + mt * 1024);
#pragma unroll
    for (int nt = 0; nt < 4; ++nt) bf[nt] = *(const f16x8*)(Bb + nt * 1024);
#pragma unroll
    for (int mt = 0; mt < 4; ++mt)
#pragma unroll
      for (int nt = 0; nt < 4; ++nt)
        acc[mt][nt] = __builtin_amdgcn_mfma_f32_16x16x32_f16(
            af[mt], bf[nt], acc[mt][nt], 0, 0, 0);
  }

  float sr[4][4], sc[4];
#pragma unroll
  for (int mt = 0; mt < 4; ++mt)
#pragma unroll
    for (int r = 0; r < 4; ++r)
      sr[mt][r] = sq[i0 + wm * 64 + mt * 16 + kq * 4 + r];
#pragma unroll
  for (int nt = 0; nt < 4; ++nt) sc[nt] = sq[j0 + wn * 64 + nt * 16 + ml];

#pragma unroll
  for (int mt = 0; mt < 4; ++mt)
#pragma unroll
    for (int nt = 0; nt < 4; ++nt) {
      const int col = j0 + wn * 64 + nt * 16 + ml;
#pragma unroll
      for (int r = 0; r < 4; ++r) {
        const int row = i0 + wm * 64 + mt * 16 + kq * 4 + r;
        const float v = fmaxf(sr[mt][r] + sc[nt] - 2.f * acc[mt][nt][r], 0.f);
        d16[(size_t)row * NPTS + col] = (f16)v;
      }
    }
}

// ------------- batched f16 Boruvka scan: 2 rows/block, gated ----------------
__global__ __launch_bounds__(256)
void k_scan3(const u16* __restrict__ d16, const int* __restrict__ comp,
             ull* __restrict__ best, const int* __restrict__ done,
             const int* __restrict__ Cdev) {
  const int b = blockIdx.x;          // 3 * 2048 blocks
  const int c = b >> 11;
  const int r0 = (b & 2047) * 2;
  const int r1 = r0 + 1;
  if (done[c] || Cdev[c] <= 256) return;
  const int t = threadIdx.x;
  __shared__ ull red0[4], red1[4];
  const int* compc = comp + c * NPTS;
  int cj[16];
  {
    const int4* cp = (const int4*)compc;
    const int4 a0 = cp[t * 4 + 0], a1 = cp[t * 4 + 1];
    const int4 a2 = cp[t * 4 + 2], a3 = cp[t * 4 + 3];
    cj[0] = a0.x;  cj[1] = a0.y;  cj[2] = a0.z;  cj[3] = a0.w;
    cj[4] = a1.x;  cj[5] = a1.y;  cj[6] = a1.z;  cj[7] = a1.w;
    cj[8] = a2.x;  cj[9] = a2.y;  cj[10] = a2.z; cj[11] = a2.w;
    cj[12] = a3.x; cj[13] = a3.y; cj[14] = a3.z; cj[15] = a3.w;
  }
  const int ci0 = compc[r0];
  const int ci1 = compc[r1];
  const u16* base = d16 + (size_t)c * NPTS * NPTS;
  const uint4* rp0 = (const uint4*)(base + (size_t)r0 * NPTS);
  const uint4* rp1 = (const uint4*)(base + (size_t)r1 * NPTS);
  // issue all 4 loads up-front (MLP against L3 latency)
  const uint4 A0 = rp0[t * 2 + 0], B0 = rp0[t * 2 + 1];
  const uint4 A1 = rp1[t * 2 + 0], B1 = rp1[t * 2 + 1];
  const unsigned w0[8] = {A0.x, A0.y, A0.z, A0.w, B0.x, B0.y, B0.z, B0.w};
  const unsigned w1[8] = {A1.x, A1.y, A1.z, A1.w, B1.x, B1.y, B1.z, B1.w};
  ull k0 = KEY_MAX_ULL, k1 = KEY_MAX_ULL;
#pragma unroll
  for (int u = 0; u < 8; ++u) {
    const int jc = t * 16 + u * 2;
    const int c0 = cj[u * 2], c1 = cj[u * 2 + 1];
    // row r0
    if (c0 != ci0) {
      const ull pair = (r0 < jc) ? (((ull)r0 << 12) | (unsigned)jc)
                                 : (((ull)jc << 12) | (unsigned)r0);
      const ull key = ((ull)(w0[u] & 0xFFFFu) << 24) | pair;
      k0 = (key < k0) ? key : k0;
    }
    if (c1 != ci0) {
      const int j = jc + 1;
      const ull pair = (r0 < j) ? (((ull)r0 << 12) | (unsigned)j)
                                : (((ull)j << 12) | (unsigned)r0);
      const ull key = ((ull)(w0[u] >> 16) << 24) | pair;
      k0 = (key < k0) ? key : k0;
    }
    // row r1
    if (c0 != ci1) {
      const ull pair = (r1 < jc) ? (((ull)r1 << 12) | (unsigned)jc)
                                 : (((ull)jc << 12) | (unsigned)r1);
      const ull key = ((ull)(w1[u] & 0xFFFFu) << 24) | pair;
      k1 = (key < k1) ? key : k1;
    }
    if (c1 != ci1) {
      const int j = jc + 1;
      const ull pair = (r1 < j) ? (((ull)r1 << 12) | (unsigned)j)
                                : (((ull)j << 12) | (unsigned)r1);
      const ull key = ((ull)(w1[u] >> 16) << 24) | pair;
      k1 = (key < k1) ? key : k1;
    }
  }
  for (int off = 32; off > 0; off >>= 1) {
    const ull o0 = __shfl_xor(k0, off, 64);
    const ull o1 = __shfl_xor(k1, off, 64);
    k0 = (o0 < k0) ? o0 : k0;
    k1 = (o1 < k1) ? o1 : k1;
  }
  if ((t & 63) == 0) { red0[t >> 6] = k0; red1[t >> 6] = k1; }
  __syncthreads();
  if (t == 0) {
    ull m0 = red0[0], m1 = red1[0];
#pragma unroll
    for (int q = 1; q < 4; ++q) {
      m0 = (red0[q] < m0) ? red0[q] : m0;
      m1 = (red1[q] < m1) ? red1[q] : m1;
    }
    ull* bestc = best + c * NPTS;
    if (ci0 == ci1) {
      const ull m = (m1 < m0) ? m1 : m0;
      if (m != KEY_MAX_ULL) atomicMin(bestc + ci0, m);
    } else {
      if (m0 != KEY_MAX_ULL) atomicMin(bestc + ci0, m0);
      if (m1 != KEY_MAX_ULL) atomicMin(bestc + ci1, m1);
    }
  }
}

// -------------- batched merge (3 blocks; records PAIR indices) --------------
__global__ __launch_bounds__(1024)
void k_merge3(ull* __restrict__ best, int* __restrict__ comp,
              int* __restrict__ comp2, int* __restrict__ pairs,
              int* __restrict__ cnt, int* __restrict__ done,
              int* __restrict__ Cdev, ull* __restrict__ cd, int initCd) {
  const int c = blockIdx.x;
  if (done[c] || Cdev[c] <= 256) return;
  ull* bestc = best + c * NPTS;
  int* compc = comp + c * NPTS;
  int* comp2c = comp2 + c * NPTS;
  int* pairsc = pairs + c * NPTS;
  __shared__ int par[NPTS];
  __shared__ int hk[NPTS];
  __shared__ int redi[16];
  __shared__ int chg;
  __shared__ int cdense;
  const int t = threadIdx.x;
  ull bb[4];
#pragma unroll
  for (int s = 0; s < 4; ++s) {
    const int v = t + s * 1024;
    par[v] = compc[v];
    bb[s] = bestc[v];
    bestc[v] = KEY_MAX_ULL;
  }
  __syncthreads();
#pragma unroll
  for (int s = 0; s < 4; ++s) {
    const int v = t + s * 1024;
    const ull b2 = bb[s];
    int h;
    if (b2 == KEY_MAX_ULL) {
      h = par[v];
    } else {
      const int pair = (int)(b2 & 0xFFFFFF);
      const int a = pair >> 12, c2 = pair & 4095;
      const int ra = par[a], rb = par[c2];
      h = (ra == v) ? rb : ra;
    }
    hk[v] = h;
  }
  __syncthreads();
  bool win[4];
#pragma unroll
  for (int s = 0; s < 4; ++s) {
    const int v = t + s * 1024;
    const ull b2 = bb[s];
    win[s] = false;
    if (b2 != KEY_MAX_ULL) {
      const int so = hk[v];
      const bool mut = (hk[so] == v);
      win[s] = mut && (v < so);
      if (!mut || v < so)
        pairsc[atomicAdd(cnt + c, 1)] = (int)(b2 & 0xFFFFFF);
    }
  }
  if (t == 0) chg = 0;
  __syncthreads();
#pragma unroll
  for (int s = 0; s < 4; ++s)
    if (win[s]) hk[t + s * 1024] = t + s * 1024;
  __syncthreads();
  for (int it = 0; it < 12; ++it) {
    int w2[4]; int ch = 0;
#pragma unroll
    for (int s = 0; s < 4; ++s) {
      const int v = t + s * 1024;
      w2[s] = hk[hk[v]];
      ch |= (w2[s] != hk[v]);
    }
    __syncthreads();
#pragma unroll
    for (int s = 0; s < 4; ++s) hk[t + s * 1024] = w2[s];
    if (ch) chg = 1;
    __syncthreads();
    const int any = chg;
    __syncthreads();
    if (t == 0) chg = 0;
    if (!any) break;
  }
  int nroot = 0;
#pragma unroll
  for (int s = 0; s < 4; ++s) {
    const int v = t + s * 1024;
    const int rv = hk[v];
    compc[v] = rv;
    nroot += (rv == v);
  }
  for (int off = 32; off > 0; off >>= 1) nroot += __shfl_xor(nroot, off, 64);
  if ((t & 63) == 0) redi[t >> 6] = nroot;
  if (t == 0) cdense = 0;
  __syncthreads();
#pragma unroll
  for (int s = 0; s < 4; ++s) {
    const int v = t + s * 1024;
    if (hk[v] == v) par[v] = atomicAdd(&cdense, 1);
  }
  __syncthreads();
#pragma unroll
  for (int s = 0; s < 4; ++s) {
    const int v = t + s * 1024;
    comp2c[v] = par[hk[v]];
  }
  if (initCd) {  // round 0 (always runs): init this cloud's cd slice
    ull* cdc = cd + (size_t)c * 65536;
    for (int q = t; q < 65536; q += 1024) cdc[q] = KEY_MAX_ULL;
  }
  if (t == 0) {
    int tot = 0;
    for (int q = 0; q < 16; ++q) tot += redi[q];
    Cdev[c] = cdense;
    if (tot == 1) done[c] = 1;
  }
}

// ---------------------- batched contraction (f16 input) ---------------------
__global__ __launch_bounds__(256)
void k_contract3(const u16* __restrict__ d16, const int* __restrict__ comp2,
                 ull* __restrict__ cd, const int* __restrict__ done) {
  const int b = blockIdx.x;
  const int c = b >> 12;
  const int i = b & (NPTS - 1);
  if (done[c]) return;
  const int t = threadIdx.x;
  __shared__ ull tbl[256];
  tbl[t] = KEY_MAX_ULL;
  const int* comp2c = comp2 + c * NPTS;
  int cj[16];
  {
    const int4* cp = (const int4*)comp2c;
    const int4 a0 = cp[t * 4 + 0], a1 = cp[t * 4 + 1];
    const int4 a2 = cp[t * 4 + 2], a3 = cp[t * 4 + 3];
    cj[0] = a0.x;  cj[1] = a0.y;  cj[2] = a0.z;  cj[3] = a0.w;
    cj[4] = a1.x;  cj[5] = a1.y;  cj[6] = a1.z;  cj[7] = a1.w;
    cj[8] = a2.x;  cj[9] = a2.y;  cj[10] = a2.z; cj[11] = a2.w;
    cj[12] = a3.x; cj[13] = a3.y; cj[14] = a3.z; cj[15] = a3.w;
  }
  const int ci = comp2c[i];
  __syncthreads();
  const uint4* rp =
      (const uint4*)(d16 + (size_t)c * NPTS * NPTS + (size_t)i * NPTS);
  const uint4 Aw = rp[t * 2 + 0], Bw = rp[t * 2 + 1];
  const unsigned wds[8] = {Aw.x, Aw.y, Aw.z, Aw.w, Bw.x, Bw.y, Bw.z, Bw.w};
#pragma unroll
  for (int u = 0; u < 8; ++u) {
    const int j0c = t * 16 + u * 2;
    const unsigned lo = wds[u] & 0xFFFFu;
    const unsigned hi2 = wds[u] >> 16;
    const int c0 = cj[u * 2], c1 = cj[u * 2 + 1];
    if (c0 != ci) {
      const int j = j0c;
      const ull pair = (i < j) ? (((ull)i << 12) | (unsigned)j)
                               : (((ull)j << 12) | (unsigned)i);
      atomicMin(&tbl[c0], ((ull)lo << 24) | pair);
    }
    if (c1 != ci) {
      const int j = j0c + 1;
      const ull pair = (i < j) ? (((ull)i << 12) | (unsigned)j)
                               : (((ull)j << 12) | (unsigned)i);
      atomicMin(&tbl[c1], ((ull)hi2 << 24) | pair);
    }
  }
  __syncthreads();
  const ull tv = tbl[t];
  if (tv != KEY_MAX_ULL) atomicMin(&cd[(size_t)c * 65536 + ci * 256 + t], tv);
}

// --------------------- batched finish (3 single-WG blocks) ------------------
__global__ __launch_bounds__(1024)
void k_finish3(const ull* __restrict__ cd, const int* __restrict__ comp2,
               const int* __restrict__ Cdev, int* __restrict__ pairs,
               int* __restrict__ cnt, const int* __restrict__ done) {
  const int c = blockIdx.x;
  if (done[c]) return;
  const ull* cdc = cd + (size_t)c * 65536;
  const int* comp2c = comp2 + c * NPTS;
  int* pairsc = pairs + c * NPTS;
  __shared__ int c2[NPTS];
  __shared__ ull bst[256];
  __shared__ int lbl[256];
  __shared__ int hk2[256];
  __shared__ int mk[256];
  __shared__ int nr_sh;
  const int t = threadIdx.x;
  const int C = Cdev[c];
#pragma unroll
  for (int s = 0; s < 4; ++s) c2[t + s * 1024] = comp2c[t + s * 1024];
  if (t < 256) lbl[t] = t;
  __syncthreads();
  for (int round = 0; round < 9; ++round) {
    if (t < 256) { bst[t] = KEY_MAX_ULL; mk[t] = 0; }
    if (t == 0) nr_sh = 0;
    __syncthreads();
    for (int idx = t; idx < C * 256; idx += 1024) {
      const int d = idx & 255;
      if (d < C) {
        const ull k = cdc[idx];
        if (k != KEY_MAX_ULL) {
          const int lc = lbl[idx >> 8], ld = lbl[d];
          if (lc != ld) atomicMin(&bst[lc], k);
        }
      }
    }
    __syncthreads();
    if (t < 256) {
      int h = t;
      const ull b = bst[t];
      if (t < C && b != KEY_MAX_ULL) {
        const int pair = (int)(b & 0xFFFFFF);
        const int a = pair >> 12, b2 = pair & 4095;
        const int sa = lbl[c2[a]], sb = lbl[c2[b2]];
        const int other = (sa == t) ? sb : sa;
        const ull bo = bst[other];
        const bool mut = (bo != KEY_MAX_ULL) && ((int)(bo & 0xFFFFFF) == pair);
        bool rec;
        if (mut) { h = (t < other) ? t : other; rec = (t < other); }
        else     { h = other;                   rec = true; }
        if (rec) pairsc[atomicAdd(cnt + c, 1)] = pair;
      }
      hk2[t] = h;
    }
    __syncthreads();
    for (int it = 0; it < 8; ++it) {
      int w2 = 0;
      if (t < 256) w2 = hk2[hk2[t]];
      __syncthreads();
      if (t < 256) hk2[t] = w2;
      __syncthreads();
    }
    if (t < 256) lbl[t] = hk2[lbl[t]];
    __syncthreads();
    if (t < C) mk[lbl[t]] = 1;
    __syncthreads();
    if (t < 256 && mk[t]) atomicAdd(&nr_sh, 1);
    __syncthreads();
    if (nr_sh <= 1) break;
  }
}

// ------------------ exact deaths from pristine fp32 inputs ------------------
__global__ __launch_bounds__(256)
void k_deaths3(const float* __restrict__ x0, const float* __restrict__ x1,
               const float* __restrict__ x2, const float* __restrict__ sq,
               const int* __restrict__ pairs, float* __restrict__ deaths) {
  const int b = blockIdx.x;
  const int c = b >> 12;
  const int s = b & (NPTS - 1);
  if (s >= NPTS - 1) return;  // 4095 real edges per cloud
  const int t = threadIdx.x;
  const int pr = pairs[c * NPTS + s];
  const int a = pr >> 12, e = pr & 4095;
  const float* X = (c == 0) ? x0 : (c == 1) ? x1 : x2;
  const float4 va = ((const float4*)(X + (size_t)a * DIMF))[t];
  const float4 vb = ((const float4*)(X + (size_t)e * DIMF))[t];
  float d = va.x * vb.x + va.y * vb.y + va.z * vb.z + va.w * vb.w;
  for (int off = 32; off > 0; off >>= 1) d += __shfl_xor(d, off, 64);
  __shared__ float ws[4];
  if ((t & 63) == 0) ws[t >> 6] = d;
  __syncthreads();
  if (t == 0) {
    const float dot = ws[0] + ws[1] + ws[2] + ws[3];
    const float dd = sq[c * NPTS + a] + sq[c * NPTS + e] - 2.f * dot;
    deaths[c * NPTS + s] = sqrtf(fmaxf(dd, 1e-12f));
  }
}

// ------------------------------ sort (bitonic, 4096 in LDS) -----------------
__global__ __launch_bounds__(1024)
void k_sort(float* __restrict__ deaths) {
  __shared__ float s[NPTS];
  float* g = deaths + (size_t)blockIdx.x * NPTS;
  const int t = threadIdx.x;
#pragma unroll
  for (int q = 0; q < 4; ++q) s[t + q * 1024] = g[t + q * 1024];
  for (int k = 2; k <= NPTS; k <<= 1) {
    for (int j = k >> 1; j > 0; j >>= 1) {
      __syncthreads();
#pragma unroll
      for (int q = 0; q < 4; ++q) {
        const int i = t + q * 1024;
        const int ixj = i ^ j;
        if (ixj > i) {
          const float a = s[i], b = s[ixj];
          const bool up = ((i & k) == 0);
          if ((a > b) == up) { s[i] = b; s[ixj] = a; }
        }
      }
    }
  }
  __syncthreads();
#pragma unroll
  for (int q = 0; q < 4; ++q) g[t + q * 1024] = s[t + q * 1024];
}

// ------------------------------ final loss ----------------------------------
__global__ __launch_bounds__(1024)
void k_final(const float* __restrict__ deaths, float* __restrict__ out) {
  const float* a = deaths;
  const float* p = deaths + NPTS;
  const float* n = deaths + 2 * NPTS;
  const int t = threadIdx.x;
  float s1 = 0.f, s2 = 0.f;
  for (int i = t; i < NPTS - 1; i += 1024) {
    s1 += fabsf(a[i] - p[i]);
    s2 += fabsf(a[i] - n[i]);
  }
  for (int off = 32; off > 0; off >>= 1) {
    s1 += __shfl_xor(s1, off, 64);
    s2 += __shfl_xor(s2, off, 64);
  }
  __shared__ float r1[16], r2[16];
  if ((t & 63) == 0) { r1[t >> 6] = s1; r2[t >> 6] = s2; }
  __syncthreads();
  if (t == 0) {
    float t1 = 0.f, t2 = 0.f;
    for (int q = 0; q < 16; ++q) { t1 += r1[q]; t2 += r2[q]; }
    out[0] = fmaxf(t1 - t2 + 1.0f, 0.0f);
  }
}

// ---------------------- fp32 fallback path (small ws) -----------------------
__global__ __launch_bounds__(256)
void k_norms(const float* __restrict__ x, float* __restrict__ sq) {
  const int row = blockIdx.x;
  const int t = threadIdx.x;
  const float4 v = ((const float4*)(x + (size_t)row * DIMF))[t];
  float s = v.x * v.x + v.y * v.y + v.z * v.z + v.w * v.w;
  for (int off = 32; off > 0; off >>= 1) s += __shfl_xor(s, off, 64);
  __shared__ float ws[4];
  if ((t & 63) == 0) ws[t >> 6] = s;
  __syncthreads();
  if (t == 0) sq[row] = ws[0] + ws[1] + ws[2] + ws[3];
}

__global__ void k_init_cloud(int* __restrict__ comp, ull* __restrict__ best,
                             int* __restrict__ done) {
  int i = blockIdx.x * blockDim.x + threadIdx.x;
  if (i < NPTS) { comp[i] = i; best[i] = KEY_MAX_ULL; }
  if (i == 0) *done = 0;
}

__global__ void k_init_deaths(float* __restrict__ deaths, int* __restrict__ cnt) {
  int i = blockIdx.x * blockDim.x + threadIdx.x;
  if (i < 3 * NPTS) deaths[i] = __int_as_float(0x7f800000);
  if (i < 8) cnt[i] = 0;
}

#define BM 128
#define BN 128
#define BK 16
__global__ __launch_bounds__(256)
void k_gemm_d2(const float* __restrict__ X, const float* __restrict__ sq,
               float* __restrict__ d2) {
  __shared__ float As[BK][BM];
  __shared__ float Bs[BK][BN];
  const int tid = threadIdx.x;
  const int tx = tid & 15, ty = tid >> 4;
  const int i0 = blockIdx.y * BM, j0 = blockIdx.x * BN;
  float acc[8][8] = {};
  for (int k0 = 0; k0 < DIMF; k0 += BK) {
#pragma unroll
    for (int id = tid; id < 512; id += 256) {
      const int row = id >> 2;
      const int kk = (id & 3) << 2;
      const float4 a = *(const float4*)(X + (size_t)(i0 + row) * DIMF + k0 + kk);
      const float4 b = *(const float4*)(X + (size_t)(j0 + row) * DIMF + k0 + kk);
      As[kk + 0][row] = a.x; As[kk + 1][row] = a.y;
      As[kk + 2][row] = a.z; As[kk + 3][row] = a.w;
      Bs[kk + 0][row] = b.x; Bs[kk + 1][row] = b.y;
      Bs[kk + 2][row] = b.z; Bs[kk + 3][row] = b.w;
    }
    __syncthreads();
#pragma unroll
    for (int kk = 0; kk < BK; ++kk) {
      float a[8], b[8];
#pragma unroll
      for (int m = 0; m < 8; ++m) a[m] = As[kk][ty * 8 + m];
#pragma unroll
      for (int n = 0; n < 8; ++n) b[n] = Bs[kk][tx * 8 + n];
#pragma unroll
      for (int m = 0; m < 8; ++m)
#pragma unroll
        for (int n = 0; n < 8; ++n)
          acc[m][n] = fmaf(a[m], b[n], acc[m][n]);
    }
    __syncthreads();
  }
#pragma unroll
  for (int m = 0; m < 8; ++m) {
    const int i = i0 + ty * 8 + m;
    const float si = sq[i];
    const int j = j0 + tx * 8;
    float4 o0, o1;
    o0.x = fmaxf(si + sq[j + 0] - 2.f * acc[m][0], 0.f);
    o0.y = fmaxf(si + sq[j + 1] - 2.f * acc[m][1], 0.f);
    o0.z = fmaxf(si + sq[j + 2] - 2.f * acc[m][2], 0.f);
    o0.w = fmaxf(si + sq[j + 3] - 2.f * acc[m][3], 0.f);
    o1.x = fmaxf(si + sq[j + 4] - 2.f * acc[m][4], 0.f);
    o1.y = fmaxf(si + sq[j + 5] - 2.f * acc[m][5], 0.f);
    o1.z = fmaxf(si + sq[j + 6] - 2.f * acc[m][6], 0.f);
    o1.w = fmaxf(si + sq[j + 7] - 2.f * acc[m][7], 0.f);
    *(float4*)(d2 + (size_t)i * NPTS + j) = o0;
    *(float4*)(d2 + (size_t)i * NPTS + j + 4) = o1;
  }
}

__global__ __launch_bounds__(256)
void k_scan32(const float* __restrict__ d2, const int* __restrict__ comp,
              ull* __restrict__ best, const int* __restrict__ done) {
  if (*done) return;
  const int i = blockIdx.x;
  const int t = threadIdx.x;
  __shared__ ull red[4];
  int cj[16];
  {
    const int4* cp = (const int4*)comp;
    const int4 a0 = cp[t * 4 + 0], a1 = cp[t * 4 + 1];
    const int4 a2 = cp[t * 4 + 2], a3 = cp[t * 4 + 3];
    cj[0] = a0.x;  cj[1] = a0.y;  cj[2] = a0.z;  cj[3] = a0.w;
    cj[4] = a1.x;  cj[5] = a1.y;  cj[6] = a1.z;  cj[7] = a1.w;
    cj[8] = a2.x;  cj[9] = a2.y;  cj[10] = a2.z; cj[11] = a2.w;
    cj[12] = a3.x; cj[13] = a3.y; cj[14] = a3.z; cj[15] = a3.w;
  }
  const int ci = comp[i];
  const float* row = d2 + (size_t)i * NPTS;
  ull kmin = KEY_MAX_ULL;
#pragma unroll
  for (int q = 0; q < 4; ++q) {
    const float4 v = ((const float4*)row)[t * 4 + q];
    const float vv[4] = {v.x, v.y, v.z, v.w};
#pragma unroll
    for (int u = 0; u < 4; ++u) {
      const int j = t * 16 + q * 4 + u;
      if (cj[q * 4 + u] != ci) {
        const ull pair = (i < j) ? (((ull)i << 12) | (unsigned)j)
                                 : (((ull)j << 12) | (unsigned)i);
        const ull key = ((ull)__float_as_uint(vv[u]) << 24) | pair;
        kmin = (key < kmin) ? key : kmin;
      }
    }
  }
  for (int off = 32; off > 0; off >>= 1) {
    const ull o = __shfl_xor(kmin, off, 64);
    kmin = (o < kmin) ? o : kmin;
  }
  if ((t & 63) == 0) red[t >> 6] = kmin;
  __syncthreads();
  if (t == 0) {
    ull k2 = red[0];
    k2 = (red[1] < k2) ? red[1] : k2;
    k2 = (red[2] < k2) ? red[2] : k2;
    k2 = (red[3] < k2) ? red[3] : k2;
    if (k2 != KEY_MAX_ULL) atomicMin(best + ci, k2);
  }
}

__global__ __launch_bounds__(1024)
void k_merge1(ull* __restrict__ best, int* __restrict__ comp,
              const float* __restrict__ d2, float* __restrict__ deaths,
              int* __restrict__ cnt, int* __restrict__ done) {
  if (*done) return;
  __shared__ int par[NPTS];
  __shared__ int hk[NPTS];
  __shared__ int redi[16];
  const int t = threadIdx.x;
  ull bb[4];
#pragma unroll
  for (int s = 0; s < 4; ++s) {
    const int v = t + s * 1024;
    par[v] = comp[v];
    bb[s] = best[v];
    best[v] = KEY_MAX_ULL;
  }
  __syncthreads();
#pragma unroll
  for (int s = 0; s < 4; ++s) {
    const int v = t + s * 1024;
    const ull b2 = bb[s];
    int h;
    if (b2 == KEY_MAX_ULL) {
      h = par[v];
    } else {
      const int pair = (int)(b2 & 0xFFFFFF);
      const int a = pair >> 12, c2 = pair & 4095;
      const int ra = par[a], rb = par[c2];
      h = (ra == v) ? rb : ra;
    }
    hk[v] = h;
  }
  __syncthreads();
  bool win[4];
#pragma unroll
  for (int s = 0; s < 4; ++s) {
    const int v = t + s * 1024;
    const ull b2 = bb[s];
    win[s] = false;
    if (b2 != KEY_MAX_ULL) {
      const int so = hk[v];
      const bool mut = (hk[so] == v);
      win[s] = mut && (v < so);
      if (!mut || v < so) {
        const int pair = (int)(b2 & 0xFFFFFF);
        const float dd = d2[(size_t)(pair >> 12) * NPTS + (pair & 4095)];
        deaths[atomicAdd(cnt, 1)] = sqrtf(fmaxf(dd, 1e-12f));
      }
    }
  }
  __syncthreads();
#pragma unroll
  for (int s = 0; s < 4; ++s)
    if (win[s]) hk[t + s * 1024] = t + s * 1024;
  __syncthreads();
  for (int it = 0; it < 12; ++it) {
    int w2[4];
#pragma unroll
    for (int s = 0; s < 4; ++s) w2[s] = hk[hk[t + s * 1024]];
    __syncthreads();
#pragma unroll
    for (int s = 0; s < 4; ++s) hk[t + s * 1024] = w2[s];
    __syncthreads();
  }
  int nroot = 0;
#pragma unroll
  for (int s = 0; s < 4; ++s) {
    const int v = t + s * 1024;
    const int rv = hk[v];
    comp[v] = rv;
    nroot += (rv == v);
  }
  for (int off = 32; off > 0; off >>= 1) nroot += __shfl_xor(nroot, off, 64);
  if ((t & 63) == 0) redi[t >> 6] = nroot;
  __syncthreads();
  if (t == 0) {
    int tot = 0;
    for (int q = 0; q < 16; ++q) tot += redi[q];
    if (tot == 1) *done = 1;
  }
}

__global__ void k_fail(float* out) { if (threadIdx.x == 0) out[0] = 0.f; }

// ------------------------------ launch --------------------------------------
extern "C" void kernel_launch(void* const* d_in, const int* in_sizes, int n_in,
                              void* d_out, int out_size, void* d_ws, size_t ws_size,
                              hipStream_t stream) {
  const float* xs[3] = {(const float*)d_in[0], (const float*)d_in[1],
                        (const float*)d_in[2]};
  char* ws = (char*)d_ws;
  const size_t d16_one = (size_t)NPTS * NPTS * 2;      // 32MB
  const size_t d16_all = 3 * d16_one;                  // 96MB
  const size_t hi_bytes = (size_t)NPTS * DIMF * 2;     // 8MB (cd aliases this)
  const size_t tail_new = 3 * NPTS * 4 /*sq*/ + 3 * NPTS * 4 /*comp*/ +
                          3 * NPTS * 4 /*comp2*/ + 3 * NPTS * 8 /*best*/ +
                          3 * NPTS * 4 /*deaths*/ + 3 * NPTS * 4 /*pairs*/ + 128;
  const size_t need_new = d16_all + hi_bytes + tail_new;        // ~109.4MB
  const size_t d2_bytes = (size_t)NPTS * NPTS * 4;              // 64MB
  const size_t small_old = NPTS * 4 + NPTS * 4 + NPTS * 8 + 3 * NPTS * 4 + 128;
  const size_t need_old = d2_bytes + small_old;

  if (ws_size >= need_new) {
    f16* d16 = (f16*)ws;
    f16* hi = (f16*)(ws + d16_all);
    ull* cd = (ull*)(ws + d16_all);  // alias: hi dead after GEMMs
    char* tp = ws + d16_all + hi_bytes;
    float* sq = (float*)tp;                    tp += 3 * NPTS * 4;
    int* comp = (int*)tp;                      tp += 3 * NPTS * 4;
    int* comp2 = (int*)tp;                     tp += 3 * NPTS * 4;
    ull* best = (ull*)tp;                      tp += 3 * NPTS * 8;
    float* deaths = (float*)tp;                tp += 3 * NPTS * 4;
    int* pairs = (int*)tp;                     tp += 3 * NPTS * 4;
    int* cnt = (int*)tp;  // cnt[0..2], done = cnt+3, C = cnt+6
    int* done = cnt + 3;
    int* Cdev = cnt + 6;

    k_init_global<<<48, 256, 0, stream>>>(comp, best, deaths, cnt);
    for (int c = 0; c < 3; ++c) {
      k_prep<<<NPTS, 256, 0, stream>>>(xs[c], sq + c * NPTS, hi);
      k_gemm_f16<<<dim3(NPTS / 128, NPTS / 128), 256, 0, stream>>>(
          hi, sq + c * NPTS, d16 + (size_t)c * NPTS * NPTS);
    }
    for (int r = 0; r < 4; ++r) {  // gated: rounds stop once C <= 256
      k_scan3<<<3 * (NPTS / 2), 256, 0, stream>>>((const u16*)d16, comp, best,
                                                  done, Cdev);
      k_merge3<<<3, 1024, 0, stream>>>(best, comp, comp2, pairs, cnt, done,
                                       Cdev, cd, (r == 0) ? 1 : 0);
    }
    k_contract3<<<3 * NPTS, 256, 0, stream>>>((const u16*)d16, comp2, cd, done);
    k_finish3<<<3, 1024, 0, stream>>>(cd, comp2, Cdev, pairs, cnt, done);
    k_deaths3<<<3 * NPTS, 256, 0, stream>>>(xs[0], xs[1], xs[2], sq, pairs,
                                            deaths);
    k_sort<<<3, 1024, 0, stream>>>(deaths);
    k_final<<<1, 1024, 0, stream>>>(deaths, (float*)d_out);
  } else if (ws_size >= need_old) {
    float* d2 = (float*)ws;
    char* tp = ws + d2_bytes;
    float* sq = (float*)tp;                    tp += NPTS * 4;
    int* comp = (int*)tp;                      tp += NPTS * 4;
    ull* best = (ull*)tp;                      tp += NPTS * 8;
    float* deaths = (float*)tp;                tp += 3 * NPTS * 4;
    int* cnt = (int*)tp;
    int* done = cnt + 3;
    k_init_deaths<<<48, 256, 0, stream>>>(deaths, cnt);
    for (int c = 0; c < 3; ++c) {
      k_norms<<<NPTS, 256, 0, stream>>>(xs[c], sq);
      k_init_cloud<<<16, 256, 0, stream>>>(comp, best, done);
      k_gemm_d2<<<dim3(NPTS / BN, NPTS / BM), 256, 0, stream>>>(xs[c], sq, d2);
      for (int r = 0; r < 12; ++r) {
        k_scan32<<<NPTS, 256, 0, stream>>>(d2, comp, best, done);
        k_merge1<<<1, 1024, 0, stream>>>(best, comp, d2, deaths + c * NPTS,
                                         cnt + c, done);
      }
    }
    k_sort<<<3, 1024, 0, stream>>>(deaths);
    k_final<<<1, 1024, 0, stream>>>(deaths, (float*)d_out);
  } else {
    k_fail<<<1, 64, 0, stream>>>((float*)d_out);
  }
}

// Round 11
// 419.853 us; speedup vs baseline: 10.3471x; 1.0987x over previous
//
#include <hip/hip_runtime.h>
#include <stdint.h>

// ---------------------------------------------------------------------------
// TopologicalContrastiveLoss: H0 persistence (MST edge weights) of 3 point
// clouds -> 1-Wasserstein between sorted death vectors -> hinge loss.
//
// R11 = R10 +
//  (a) k_finish3 rewritten: per-row register min (4 thr/row) + ONE LDS
//      atomicMin per row (R10 counter: 179k LDS bank-conflict cycles ~ 75us
//      of serialized per-cell atomics); c2 LDS copy dropped (L2 lookups)
//  (b) k_scan3 does 4 rows/block: 8 outstanding 16B loads/thread (scans are
//      L3-latency-bound: VALU 17%, HBM 5.7%)
// ---------------------------------------------------------------------------

#define NPTS 4096
#define DIMF 1024
typedef unsigned short u16;
typedef _Float16 f16;
typedef unsigned long long ull;
static const ull KEY_MAX_ULL = ~0ull;

typedef f16 f16x8 __attribute__((ext_vector_type(8)));
typedef f16 f16x4v __attribute__((ext_vector_type(4)));
typedef float f32x4 __attribute__((ext_vector_type(4)));

#define GLOAD_LDS16(g, l)                                                      \
  __builtin_amdgcn_global_load_lds(                                            \
      (const __attribute__((address_space(1))) void*)(g),                      \
      (__attribute__((address_space(3))) void*)(l), 16, 0, 0)

// ------------------------------ init ---------------------------------------
__global__ void k_init_global(int* __restrict__ comp, ull* __restrict__ best,
                              float* __restrict__ deaths, int* __restrict__ cnt) {
  const int i = blockIdx.x * blockDim.x + threadIdx.x;
  if (i < 3 * NPTS) {
    comp[i] = i & (NPTS - 1);
    best[i] = KEY_MAX_ULL;
    deaths[i] = __int_as_float(0x7f800000);  // +inf
  }
  // cnt[0..2]=edge counters, cnt[3..5]=done, cnt[6..8]=C (start at NPTS)
  if (i < 16) cnt[i] = (i >= 6 && i < 9) ? NPTS : 0;
}

// ------------------------------ prep: norms + f16 cast ----------------------
__global__ __launch_bounds__(256)
void k_prep(const float* __restrict__ x, float* __restrict__ sq,
            f16* __restrict__ hi) {
  const int row = blockIdx.x;
  const int t = threadIdx.x;
  const float4 v = ((const float4*)(x + (size_t)row * DIMF))[t];
  f16x4v h;
  h.x = (f16)v.x; h.y = (f16)v.y; h.z = (f16)v.z; h.w = (f16)v.w;
  ((f16x4v*)(hi + (size_t)row * DIMF))[t] = h;
  float s = v.x * v.x + v.y * v.y + v.z * v.z + v.w * v.w;
  for (int off = 32; off > 0; off >>= 1) s += __shfl_xor(s, off, 64);
  __shared__ float ws[4];
  if ((t & 63) == 0) ws[t >> 6] = s;
  __syncthreads();
  if (t == 0) sq[row] = ws[0] + ws[1] + ws[2] + ws[3];
}

// ------------------------------ fp16 MFMA GEMM -> d16 only ------------------
__global__ __launch_bounds__(256)
void k_gemm_f16(const f16* __restrict__ hi, const float* __restrict__ sq,
                f16* __restrict__ d16) {
  __shared__ u16 smem[8192];
  u16* As = smem;
  u16* Bs = smem + 4096;
  const int t = threadIdx.x;
  const int w = t >> 6, l = t & 63;
  const int wm = w >> 1, wn = w & 1;
  const int ml = l & 15, kq = l >> 4;
  const int i0 = blockIdx.y * 128, j0 = blockIdx.x * 128;

  const int srow = t >> 2, schk = t & 3;
  char* ldsA0 = (char*)As + t * 16;
  char* ldsB0 = (char*)Bs + t * 16;

  f32x4 acc[4][4];
#pragma unroll
  for (int a = 0; a < 4; ++a)
#pragma unroll
    for (int b = 0; b < 4; ++b) acc[a][b] = (f32x4)0.f;

  for (int k0 = 0; k0 < DIMF; k0 += 32) {
    __syncthreads();
    {
      const f16* ga0 = hi + (size_t)(i0 + srow) * DIMF + k0 + schk * 8;
      const f16* ga1 = hi + (size_t)(i0 + srow + 64) * DIMF + k0 + schk * 8;
      const f16* gb0 = hi + (size_t)(j0 + srow) * DIMF + k0 + schk * 8;
      const f16* gb1 = hi + (size_t)(j0 + srow + 64) * DIMF + k0 + schk * 8;
      GLOAD_LDS16(ga0, ldsA0);
      GLOAD_LDS16(ga1, ldsA0 + 4096);
      GLOAD_LDS16(gb0, ldsB0);
      GLOAD_LDS16(gb1, ldsB0 + 4096);
    }
    asm volatile("s_waitcnt vmcnt(0)" ::: "memory");
    __syncthreads();

    const char* Ab = (const char*)As + (wm * 64 + ml) * 64 + kq * 16;
    const char* Bb = (const char*)Bs + (wn * 64 + ml) * 64 + kq * 16;
    f16x8 af[4], bf[4];
#pragma unroll
    for (int mt = 0; mt < 4; ++mt) af[mt] = *(const f16x8*)(Ab + mt * 1024);
#pragma unroll
    for (int nt = 0; nt < 4; ++nt) bf[nt] = *(const f16x8*)(Bb + nt * 1024);
#pragma unroll
    for (int mt = 0; mt < 4; ++mt)
#pragma unroll
      for (int nt = 0; nt < 4; ++nt)
        acc[mt][nt] = __builtin_amdgcn_mfma_f32_16x16x32_f16(
            af[mt], bf[nt], acc[mt][nt], 0, 0, 0);
  }

  float sr[4][4], sc[4];
#pragma unroll
  for (int mt = 0; mt < 4; ++mt)
#pragma unroll
    for (int r = 0; r < 4; ++r)
      sr[mt][r] = sq[i0 + wm * 64 + mt * 16 + kq * 4 + r];
#pragma unroll
  for (int nt = 0; nt < 4; ++nt) sc[nt] = sq[j0 + wn * 64 + nt * 16 + ml];

#pragma unroll
  for (int mt = 0; mt < 4; ++mt)
#pragma unroll
    for (int nt = 0; nt < 4; ++nt) {
      const int col = j0 + wn * 64 + nt * 16 + ml;
#pragma unroll
      for (int r = 0; r < 4; ++r) {
        const int row = i0 + wm * 64 + mt * 16 + kq * 4 + r;
        const float v = fmaxf(sr[mt][r] + sc[nt] - 2.f * acc[mt][nt][r], 0.f);
        d16[(size_t)row * NPTS + col] = (f16)v;
      }
    }
}

// ------------- batched f16 Boruvka scan: 4 rows/block, gated ----------------
__global__ __launch_bounds__(256)
void k_scan3(const u16* __restrict__ d16, const int* __restrict__ comp,
             ull* __restrict__ best, const int* __restrict__ done,
             const int* __restrict__ Cdev) {
  const int b = blockIdx.x;          // 3 * 1024 blocks
  const int c = b >> 10;
  const int r0 = (b & 1023) * 4;
  if (done[c] || Cdev[c] <= 256) return;
  const int t = threadIdx.x;
  __shared__ ull red[4][4];
  const int* compc = comp + c * NPTS;
  int cj[16];
  {
    const int4* cp = (const int4*)compc;
    const int4 a0 = cp[t * 4 + 0], a1 = cp[t * 4 + 1];
    const int4 a2 = cp[t * 4 + 2], a3 = cp[t * 4 + 3];
    cj[0] = a0.x;  cj[1] = a0.y;  cj[2] = a0.z;  cj[3] = a0.w;
    cj[4] = a1.x;  cj[5] = a1.y;  cj[6] = a1.z;  cj[7] = a1.w;
    cj[8] = a2.x;  cj[9] = a2.y;  cj[10] = a2.z; cj[11] = a2.w;
    cj[12] = a3.x; cj[13] = a3.y; cj[14] = a3.z; cj[15] = a3.w;
  }
  int ci[4];
#pragma unroll
  for (int r = 0; r < 4; ++r) ci[r] = compc[r0 + r];
  const u16* base = d16 + (size_t)c * NPTS * NPTS;
  // issue all 8 loads up-front (MLP against L3 latency)
  uint4 A[4], B[4];
#pragma unroll
  for (int r = 0; r < 4; ++r) {
    const uint4* rp = (const uint4*)(base + (size_t)(r0 + r) * NPTS);
    A[r] = rp[t * 2 + 0];
    B[r] = rp[t * 2 + 1];
  }
  ull km[4] = {KEY_MAX_ULL, KEY_MAX_ULL, KEY_MAX_ULL, KEY_MAX_ULL};
#pragma unroll
  for (int r = 0; r < 4; ++r) {
    const unsigned wds[8] = {A[r].x, A[r].y, A[r].z, A[r].w,
                             B[r].x, B[r].y, B[r].z, B[r].w};
    const int i = r0 + r;
    const int cir = ci[r];
#pragma unroll
    for (int u = 0; u < 8; ++u) {
      const int jc = t * 16 + u * 2;
      if (cj[u * 2] != cir) {
        const ull pair = (i < jc) ? (((ull)i << 12) | (unsigned)jc)
                                  : (((ull)jc << 12) | (unsigned)i);
        const ull key = ((ull)(wds[u] & 0xFFFFu) << 24) | pair;
        km[r] = (key < km[r]) ? key : km[r];
      }
      if (cj[u * 2 + 1] != cir) {
        const int j = jc + 1;
        const ull pair = (i < j) ? (((ull)i << 12) | (unsigned)j)
                                 : (((ull)j << 12) | (unsigned)i);
        const ull key = ((ull)(wds[u] >> 16) << 24) | pair;
        km[r] = (key < km[r]) ? key : km[r];
      }
    }
  }
  for (int off = 32; off > 0; off >>= 1) {
#pragma unroll
    for (int r = 0; r < 4; ++r) {
      const ull o = __shfl_xor(km[r], off, 64);
      km[r] = (o < km[r]) ? o : km[r];
    }
  }
  if ((t & 63) == 0) {
#pragma unroll
    for (int r = 0; r < 4; ++r) red[r][t >> 6] = km[r];
  }
  __syncthreads();
  if (t == 0) {
    ull m[4];
#pragma unroll
    for (int r = 0; r < 4; ++r) {
      m[r] = red[r][0];
#pragma unroll
      for (int q = 1; q < 4; ++q) m[r] = (red[r][q] < m[r]) ? red[r][q] : m[r];
    }
    ull* bestc = best + c * NPTS;
#pragma unroll
    for (int r = 0; r < 4; ++r) {
      if (m[r] == KEY_MAX_ULL) continue;
#pragma unroll
      for (int r2 = r + 1; r2 < 4; ++r2) {
        if (ci[r2] == ci[r]) {
          m[r] = (m[r2] < m[r]) ? m[r2] : m[r];
          m[r2] = KEY_MAX_ULL;
        }
      }
      atomicMin(bestc + ci[r], m[r]);
    }
  }
}

// -------------- batched merge (3 blocks; records PAIR indices) --------------
__global__ __launch_bounds__(1024)
void k_merge3(ull* __restrict__ best, int* __restrict__ comp,
              int* __restrict__ comp2, int* __restrict__ pairs,
              int* __restrict__ cnt, int* __restrict__ done,
              int* __restrict__ Cdev, ull* __restrict__ cd, int initCd) {
  const int c = blockIdx.x;
  if (done[c] || Cdev[c] <= 256) return;
  ull* bestc = best + c * NPTS;
  int* compc = comp + c * NPTS;
  int* comp2c = comp2 + c * NPTS;
  int* pairsc = pairs + c * NPTS;
  __shared__ int par[NPTS];
  __shared__ int hk[NPTS];
  __shared__ int redi[16];
  __shared__ int chg;
  __shared__ int cdense;
  const int t = threadIdx.x;
  ull bb[4];
#pragma unroll
  for (int s = 0; s < 4; ++s) {
    const int v = t + s * 1024;
    par[v] = compc[v];
    bb[s] = bestc[v];
    bestc[v] = KEY_MAX_ULL;
  }
  __syncthreads();
#pragma unroll
  for (int s = 0; s < 4; ++s) {
    const int v = t + s * 1024;
    const ull b2 = bb[s];
    int h;
    if (b2 == KEY_MAX_ULL) {
      h = par[v];
    } else {
      const int pair = (int)(b2 & 0xFFFFFF);
      const int a = pair >> 12, c2 = pair & 4095;
      const int ra = par[a], rb = par[c2];
      h = (ra == v) ? rb : ra;
    }
    hk[v] = h;
  }
  __syncthreads();
  bool win[4];
#pragma unroll
  for (int s = 0; s < 4; ++s) {
    const int v = t + s * 1024;
    const ull b2 = bb[s];
    win[s] = false;
    if (b2 != KEY_MAX_ULL) {
      const int so = hk[v];
      const bool mut = (hk[so] == v);
      win[s] = mut && (v < so);
      if (!mut || v < so)
        pairsc[atomicAdd(cnt + c, 1)] = (int)(b2 & 0xFFFFFF);
    }
  }
  if (t == 0) chg = 0;
  __syncthreads();
#pragma unroll
  for (int s = 0; s < 4; ++s)
    if (win[s]) hk[t + s * 1024] = t + s * 1024;
  __syncthreads();
  for (int it = 0; it < 12; ++it) {
    int w2[4]; int ch = 0;
#pragma unroll
    for (int s = 0; s < 4; ++s) {
      const int v = t + s * 1024;
      w2[s] = hk[hk[v]];
      ch |= (w2[s] != hk[v]);
    }
    __syncthreads();
#pragma unroll
    for (int s = 0; s < 4; ++s) hk[t + s * 1024] = w2[s];
    if (ch) chg = 1;
    __syncthreads();
    const int any = chg;
    __syncthreads();
    if (t == 0) chg = 0;
    if (!any) break;
  }
  int nroot = 0;
#pragma unroll
  for (int s = 0; s < 4; ++s) {
    const int v = t + s * 1024;
    const int rv = hk[v];
    compc[v] = rv;
    nroot += (rv == v);
  }
  for (int off = 32; off > 0; off >>= 1) nroot += __shfl_xor(nroot, off, 64);
  if ((t & 63) == 0) redi[t >> 6] = nroot;
  if (t == 0) cdense = 0;
  __syncthreads();
#pragma unroll
  for (int s = 0; s < 4; ++s) {
    const int v = t + s * 1024;
    if (hk[v] == v) par[v] = atomicAdd(&cdense, 1);
  }
  __syncthreads();
#pragma unroll
  for (int s = 0; s < 4; ++s) {
    const int v = t + s * 1024;
    comp2c[v] = par[hk[v]];
  }
  if (initCd) {  // round 0 (always runs): init this cloud's cd slice
    ull* cdc = cd + (size_t)c * 65536;
    for (int q = t; q < 65536; q += 1024) cdc[q] = KEY_MAX_ULL;
  }
  if (t == 0) {
    int tot = 0;
    for (int q = 0; q < 16; ++q) tot += redi[q];
    Cdev[c] = cdense;
    if (tot == 1) done[c] = 1;
  }
}

// ---------------------- batched contraction (f16 input) ---------------------
__global__ __launch_bounds__(256)
void k_contract3(const u16* __restrict__ d16, const int* __restrict__ comp2,
                 ull* __restrict__ cd, const int* __restrict__ done) {
  const int b = blockIdx.x;
  const int c = b >> 12;
  const int i = b & (NPTS - 1);
  if (done[c]) return;
  const int t = threadIdx.x;
  __shared__ ull tbl[256];
  tbl[t] = KEY_MAX_ULL;
  const int* comp2c = comp2 + c * NPTS;
  int cj[16];
  {
    const int4* cp = (const int4*)comp2c;
    const int4 a0 = cp[t * 4 + 0], a1 = cp[t * 4 + 1];
    const int4 a2 = cp[t * 4 + 2], a3 = cp[t * 4 + 3];
    cj[0] = a0.x;  cj[1] = a0.y;  cj[2] = a0.z;  cj[3] = a0.w;
    cj[4] = a1.x;  cj[5] = a1.y;  cj[6] = a1.z;  cj[7] = a1.w;
    cj[8] = a2.x;  cj[9] = a2.y;  cj[10] = a2.z; cj[11] = a2.w;
    cj[12] = a3.x; cj[13] = a3.y; cj[14] = a3.z; cj[15] = a3.w;
  }
  const int ci = comp2c[i];
  __syncthreads();
  const uint4* rp =
      (const uint4*)(d16 + (size_t)c * NPTS * NPTS + (size_t)i * NPTS);
  const uint4 Aw = rp[t * 2 + 0], Bw = rp[t * 2 + 1];
  const unsigned wds[8] = {Aw.x, Aw.y, Aw.z, Aw.w, Bw.x, Bw.y, Bw.z, Bw.w};
#pragma unroll
  for (int u = 0; u < 8; ++u) {
    const int j0c = t * 16 + u * 2;
    const unsigned lo = wds[u] & 0xFFFFu;
    const unsigned hi2 = wds[u] >> 16;
    const int c0 = cj[u * 2], c1 = cj[u * 2 + 1];
    if (c0 != ci) {
      const int j = j0c;
      const ull pair = (i < j) ? (((ull)i << 12) | (unsigned)j)
                               : (((ull)j << 12) | (unsigned)i);
      atomicMin(&tbl[c0], ((ull)lo << 24) | pair);
    }
    if (c1 != ci) {
      const int j = j0c + 1;
      const ull pair = (i < j) ? (((ull)i << 12) | (unsigned)j)
                               : (((ull)j << 12) | (unsigned)i);
      atomicMin(&tbl[c1], ((ull)hi2 << 24) | pair);
    }
  }
  __syncthreads();
  const ull tv = tbl[t];
  if (tv != KEY_MAX_ULL) atomicMin(&cd[(size_t)c * 65536 + ci * 256 + t], tv);
}

// ----- batched finish (3 single-WG blocks; per-row min, no cell atomics) ----
__global__ __launch_bounds__(1024)
void k_finish3(const ull* __restrict__ cd, const int* __restrict__ comp2,
               const int* __restrict__ Cdev, int* __restrict__ pairs,
               int* __restrict__ cnt, const int* __restrict__ done) {
  const int c = blockIdx.x;
  if (done[c]) return;
  const ull* cdc = cd + (size_t)c * 65536;
  const int* comp2c = comp2 + c * NPTS;
  int* pairsc = pairs + c * NPTS;
  __shared__ ull bst[256];
  __shared__ int lbl[256];
  __shared__ int hk2[256];
  __shared__ int mk[256];
  __shared__ int nr_sh;
  const int t = threadIdx.x;
  const int C = Cdev[c];
  const int row = t >> 2;  // 4 threads per row
  const int sub = t & 3;
  if (t < 256) lbl[t] = t;
  __syncthreads();
  for (int round = 0; round < 9; ++round) {
    if (t < 256) { bst[t] = KEY_MAX_ULL; mk[t] = 0; }
    if (t == 0) nr_sh = 0;
    __syncthreads();
    // per-row sweep: register min over 64 cells, 2-shuffle combine,
    // ONE LDS atomicMin per row (was: 65536 per-cell atomics -> 179k conflicts)
    if (row < C) {
      const int lr = lbl[row];
      const ull* rp2 = cdc + row * 256;
      ull kmin = KEY_MAX_ULL;
#pragma unroll 8
      for (int k = 0; k < 64; ++k) {
        const int d = sub + 4 * k;
        if (d < C && lbl[d] != lr) {
          const ull key = rp2[d];
          kmin = (key < kmin) ? key : kmin;
        }
      }
      ull o = __shfl_xor(kmin, 1, 64);
      kmin = (o < kmin) ? o : kmin;
      o = __shfl_xor(kmin, 2, 64);
      kmin = (o < kmin) ? o : kmin;
      if (sub == 0 && kmin != KEY_MAX_ULL) atomicMin(&bst[lr], kmin);
    }
    __syncthreads();
    if (t < 256) {
      int h = t;
      const ull b = bst[t];
      if (t < C && b != KEY_MAX_ULL) {
        const int pair = (int)(b & 0xFFFFFF);
        const int a = pair >> 12, b2 = pair & 4095;
        const int sa = lbl[comp2c[a]], sb = lbl[comp2c[b2]];
        const int other = (sa == t) ? sb : sa;
        const ull bo = bst[other];
        const bool mut = (bo != KEY_MAX_ULL) && ((int)(bo & 0xFFFFFF) == pair);
        bool rec;
        if (mut) { h = (t < other) ? t : other; rec = (t < other); }
        else     { h = other;                   rec = true; }
        if (rec) pairsc[atomicAdd(cnt + c, 1)] = pair;
      }
      hk2[t] = h;
    }
    __syncthreads();
    for (int it = 0; it < 8; ++it) {
      int w2 = 0;
      if (t < 256) w2 = hk2[hk2[t]];
      __syncthreads();
      if (t < 256) hk2[t] = w2;
      __syncthreads();
    }
    if (t < 256) lbl[t] = hk2[lbl[t]];
    __syncthreads();
    if (t < C) mk[lbl[t]] = 1;
    __syncthreads();
    if (t < 256 && mk[t]) atomicAdd(&nr_sh, 1);
    __syncthreads();
    if (nr_sh <= 1) break;
    __syncthreads();
  }
}

// ------------------ exact deaths from pristine fp32 inputs ------------------
__global__ __launch_bounds__(256)
void k_deaths3(const float* __restrict__ x0, const float* __restrict__ x1,
               const float* __restrict__ x2, const float* __restrict__ sq,
               const int* __restrict__ pairs, float* __restrict__ deaths) {
  const int b = blockIdx.x;
  const int c = b >> 12;
  const int s = b & (NPTS - 1);
  if (s >= NPTS - 1) return;  // 4095 real edges per cloud
  const int t = threadIdx.x;
  const int pr = pairs[c * NPTS + s];
  const int a = pr >> 12, e = pr & 4095;
  const float* X = (c == 0) ? x0 : (c == 1) ? x1 : x2;
  const float4 va = ((const float4*)(X + (size_t)a * DIMF))[t];
  const float4 vb = ((const float4*)(X + (size_t)e * DIMF))[t];
  float d = va.x * vb.x + va.y * vb.y + va.z * vb.z + va.w * vb.w;
  for (int off = 32; off > 0; off >>= 1) d += __shfl_xor(d, off, 64);
  __shared__ float ws[4];
  if ((t & 63) == 0) ws[t >> 6] = d;
  __syncthreads();
  if (t == 0) {
    const float dot = ws[0] + ws[1] + ws[2] + ws[3];
    const float dd = sq[c * NPTS + a] + sq[c * NPTS + e] - 2.f * dot;
    deaths[c * NPTS + s] = sqrtf(fmaxf(dd, 1e-12f));
  }
}

// ------------------------------ sort (bitonic, 4096 in LDS) -----------------
__global__ __launch_bounds__(1024)
void k_sort(float* __restrict__ deaths) {
  __shared__ float s[NPTS];
  float* g = deaths + (size_t)blockIdx.x * NPTS;
  const int t = threadIdx.x;
#pragma unroll
  for (int q = 0; q < 4; ++q) s[t + q * 1024] = g[t + q * 1024];
  for (int k = 2; k <= NPTS; k <<= 1) {
    for (int j = k >> 1; j > 0; j >>= 1) {
      __syncthreads();
#pragma unroll
      for (int q = 0; q < 4; ++q) {
        const int i = t + q * 1024;
        const int ixj = i ^ j;
        if (ixj > i) {
          const float a = s[i], b = s[ixj];
          const bool up = ((i & k) == 0);
          if ((a > b) == up) { s[i] = b; s[ixj] = a; }
        }
      }
    }
  }
  __syncthreads();
#pragma unroll
  for (int q = 0; q < 4; ++q) g[t + q * 1024] = s[t + q * 1024];
}

// ------------------------------ final loss ----------------------------------
__global__ __launch_bounds__(1024)
void k_final(const float* __restrict__ deaths, float* __restrict__ out) {
  const float* a = deaths;
  const float* p = deaths + NPTS;
  const float* n = deaths + 2 * NPTS;
  const int t = threadIdx.x;
  float s1 = 0.f, s2 = 0.f;
  for (int i = t; i < NPTS - 1; i += 1024) {
    s1 += fabsf(a[i] - p[i]);
    s2 += fabsf(a[i] - n[i]);
  }
  for (int off = 32; off > 0; off >>= 1) {
    s1 += __shfl_xor(s1, off, 64);
    s2 += __shfl_xor(s2, off, 64);
  }
  __shared__ float r1[16], r2[16];
  if ((t & 63) == 0) { r1[t >> 6] = s1; r2[t >> 6] = s2; }
  __syncthreads();
  if (t == 0) {
    float t1 = 0.f, t2 = 0.f;
    for (int q = 0; q < 16; ++q) { t1 += r1[q]; t2 += r2[q]; }
    out[0] = fmaxf(t1 - t2 + 1.0f, 0.0f);
  }
}

// ---------------------- fp32 fallback path (small ws) -----------------------
__global__ __launch_bounds__(256)
void k_norms(const float* __restrict__ x, float* __restrict__ sq) {
  const int row = blockIdx.x;
  const int t = threadIdx.x;
  const float4 v = ((const float4*)(x + (size_t)row * DIMF))[t];
  float s = v.x * v.x + v.y * v.y + v.z * v.z + v.w * v.w;
  for (int off = 32; off > 0; off >>= 1) s += __shfl_xor(s, off, 64);
  __shared__ float ws[4];
  if ((t & 63) == 0) ws[t >> 6] = s;
  __syncthreads();
  if (t == 0) sq[row] = ws[0] + ws[1] + ws[2] + ws[3];
}

__global__ void k_init_cloud(int* __restrict__ comp, ull* __restrict__ best,
                             int* __restrict__ done) {
  int i = blockIdx.x * blockDim.x + threadIdx.x;
  if (i < NPTS) { comp[i] = i; best[i] = KEY_MAX_ULL; }
  if (i == 0) *done = 0;
}

__global__ void k_init_deaths(float* __restrict__ deaths, int* __restrict__ cnt) {
  int i = blockIdx.x * blockDim.x + threadIdx.x;
  if (i < 3 * NPTS) deaths[i] = __int_as_float(0x7f800000);
  if (i < 8) cnt[i] = 0;
}

#define BM 128
#define BN 128
#define BK 16
__global__ __launch_bounds__(256)
void k_gemm_d2(const float* __restrict__ X, const float* __restrict__ sq,
               float* __restrict__ d2) {
  __shared__ float As[BK][BM];
  __shared__ float Bs[BK][BN];
  const int tid = threadIdx.x;
  const int tx = tid & 15, ty = tid >> 4;
  const int i0 = blockIdx.y * BM, j0 = blockIdx.x * BN;
  float acc[8][8] = {};
  for (int k0 = 0; k0 < DIMF; k0 += BK) {
#pragma unroll
    for (int id = tid; id < 512; id += 256) {
      const int row = id >> 2;
      const int kk = (id & 3) << 2;
      const float4 a = *(const float4*)(X + (size_t)(i0 + row) * DIMF + k0 + kk);
      const float4 b = *(const float4*)(X + (size_t)(j0 + row) * DIMF + k0 + kk);
      As[kk + 0][row] = a.x; As[kk + 1][row] = a.y;
      As[kk + 2][row] = a.z; As[kk + 3][row] = a.w;
      Bs[kk + 0][row] = b.x; Bs[kk + 1][row] = b.y;
      Bs[kk + 2][row] = b.z; Bs[kk + 3][row] = b.w;
    }
    __syncthreads();
#pragma unroll
    for (int kk = 0; kk < BK; ++kk) {
      float a[8], b[8];
#pragma unroll
      for (int m = 0; m < 8; ++m) a[m] = As[kk][ty * 8 + m];
#pragma unroll
      for (int n = 0; n < 8; ++n) b[n] = Bs[kk][tx * 8 + n];
#pragma unroll
      for (int m = 0; m < 8; ++m)
#pragma unroll
        for (int n = 0; n < 8; ++n)
          acc[m][n] = fmaf(a[m], b[n], acc[m][n]);
    }
    __syncthreads();
  }
#pragma unroll
  for (int m = 0; m < 8; ++m) {
    const int i = i0 + ty * 8 + m;
    const float si = sq[i];
    const int j = j0 + tx * 8;
    float4 o0, o1;
    o0.x = fmaxf(si + sq[j + 0] - 2.f * acc[m][0], 0.f);
    o0.y = fmaxf(si + sq[j + 1] - 2.f * acc[m][1], 0.f);
    o0.z = fmaxf(si + sq[j + 2] - 2.f * acc[m][2], 0.f);
    o0.w = fmaxf(si + sq[j + 3] - 2.f * acc[m][3], 0.f);
    o1.x = fmaxf(si + sq[j + 4] - 2.f * acc[m][4], 0.f);
    o1.y = fmaxf(si + sq[j + 5] - 2.f * acc[m][5], 0.f);
    o1.z = fmaxf(si + sq[j + 6] - 2.f * acc[m][6], 0.f);
    o1.w = fmaxf(si + sq[j + 7] - 2.f * acc[m][7], 0.f);
    *(float4*)(d2 + (size_t)i * NPTS + j) = o0;
    *(float4*)(d2 + (size_t)i * NPTS + j + 4) = o1;
  }
}

__global__ __launch_bounds__(256)
void k_scan32(const float* __restrict__ d2, const int* __restrict__ comp,
              ull* __restrict__ best, const int* __restrict__ done) {
  if (*done) return;
  const int i = blockIdx.x;
  const int t = threadIdx.x;
  __shared__ ull red[4];
  int cj[16];
  {
    const int4* cp = (const int4*)comp;
    const int4 a0 = cp[t * 4 + 0], a1 = cp[t * 4 + 1];
    const int4 a2 = cp[t * 4 + 2], a3 = cp[t * 4 + 3];
    cj[0] = a0.x;  cj[1] = a0.y;  cj[2] = a0.z;  cj[3] = a0.w;
    cj[4] = a1.x;  cj[5] = a1.y;  cj[6] = a1.z;  cj[7] = a1.w;
    cj[8] = a2.x;  cj[9] = a2.y;  cj[10] = a2.z; cj[11] = a2.w;
    cj[12] = a3.x; cj[13] = a3.y; cj[14] = a3.z; cj[15] = a3.w;
  }
  const int ci = comp[i];
  const float* row = d2 + (size_t)i * NPTS;
  ull kmin = KEY_MAX_ULL;
#pragma unroll
  for (int q = 0; q < 4; ++q) {
    const float4 v = ((const float4*)row)[t * 4 + q];
    const float vv[4] = {v.x, v.y, v.z, v.w};
#pragma unroll
    for (int u = 0; u < 4; ++u) {
      const int j = t * 16 + q * 4 + u;
      if (cj[q * 4 + u] != ci) {
        const ull pair = (i < j) ? (((ull)i << 12) | (unsigned)j)
                                 : (((ull)j << 12) | (unsigned)i);
        const ull key = ((ull)__float_as_uint(vv[u]) << 24) | pair;
        kmin = (key < kmin) ? key : kmin;
      }
    }
  }
  for (int off = 32; off > 0; off >>= 1) {
    const ull o = __shfl_xor(kmin, off, 64);
    kmin = (o < kmin) ? o : kmin;
  }
  if ((t & 63) == 0) red[t >> 6] = kmin;
  __syncthreads();
  if (t == 0) {
    ull k2 = red[0];
    k2 = (red[1] < k2) ? red[1] : k2;
    k2 = (red[2] < k2) ? red[2] : k2;
    k2 = (red[3] < k2) ? red[3] : k2;
    if (k2 != KEY_MAX_ULL) atomicMin(best + ci, k2);
  }
}

__global__ __launch_bounds__(1024)
void k_merge1(ull* __restrict__ best, int* __restrict__ comp,
              const float* __restrict__ d2, float* __restrict__ deaths,
              int* __restrict__ cnt, int* __restrict__ done) {
  if (*done) return;
  __shared__ int par[NPTS];
  __shared__ int hk[NPTS];
  __shared__ int redi[16];
  const int t = threadIdx.x;
  ull bb[4];
#pragma unroll
  for (int s = 0; s < 4; ++s) {
    const int v = t + s * 1024;
    par[v] = comp[v];
    bb[s] = best[v];
    best[v] = KEY_MAX_ULL;
  }
  __syncthreads();
#pragma unroll
  for (int s = 0; s < 4; ++s) {
    const int v = t + s * 1024;
    const ull b2 = bb[s];
    int h;
    if (b2 == KEY_MAX_ULL) {
      h = par[v];
    } else {
      const int pair = (int)(b2 & 0xFFFFFF);
      const int a = pair >> 12, c2 = pair & 4095;
      const int ra = par[a], rb = par[c2];
      h = (ra == v) ? rb : ra;
    }
    hk[v] = h;
  }
  __syncthreads();
  bool win[4];
#pragma unroll
  for (int s = 0; s < 4; ++s) {
    const int v = t + s * 1024;
    const ull b2 = bb[s];
    win[s] = false;
    if (b2 != KEY_MAX_ULL) {
      const int so = hk[v];
      const bool mut = (hk[so] == v);
      win[s] = mut && (v < so);
      if (!mut || v < so) {
        const int pair = (int)(b2 & 0xFFFFFF);
        const float dd = d2[(size_t)(pair >> 12) * NPTS + (pair & 4095)];
        deaths[atomicAdd(cnt, 1)] = sqrtf(fmaxf(dd, 1e-12f));
      }
    }
  }
  __syncthreads();
#pragma unroll
  for (int s = 0; s < 4; ++s)
    if (win[s]) hk[t + s * 1024] = t + s * 1024;
  __syncthreads();
  for (int it = 0; it < 12; ++it) {
    int w2[4];
#pragma unroll
    for (int s = 0; s < 4; ++s) w2[s] = hk[hk[t + s * 1024]];
    __syncthreads();
#pragma unroll
    for (int s = 0; s < 4; ++s) hk[t + s * 1024] = w2[s];
    __syncthreads();
  }
  int nroot = 0;
#pragma unroll
  for (int s = 0; s < 4; ++s) {
    const int v = t + s * 1024;
    const int rv = hk[v];
    comp[v] = rv;
    nroot += (rv == v);
  }
  for (int off = 32; off > 0; off >>= 1) nroot += __shfl_xor(nroot, off, 64);
  if ((t & 63) == 0) redi[t >> 6] = nroot;
  __syncthreads();
  if (t == 0) {
    int tot = 0;
    for (int q = 0; q < 16; ++q) tot += redi[q];
    if (tot == 1) *done = 1;
  }
}

__global__ void k_fail(float* out) { if (threadIdx.x == 0) out[0] = 0.f; }

// ------------------------------ launch --------------------------------------
extern "C" void kernel_launch(void* const* d_in, const int* in_sizes, int n_in,
                              void* d_out, int out_size, void* d_ws, size_t ws_size,
                              hipStream_t stream) {
  const float* xs[3] = {(const float*)d_in[0], (const float*)d_in[1],
                        (const float*)d_in[2]};
  char* ws = (char*)d_ws;
  const size_t d16_one = (size_t)NPTS * NPTS * 2;      // 32MB
  const size_t d16_all = 3 * d16_one;                  // 96MB
  const size_t hi_bytes = (size_t)NPTS * DIMF * 2;     // 8MB (cd aliases this)
  const size_t tail_new = 3 * NPTS * 4 /*sq*/ + 3 * NPTS * 4 /*comp*/ +
                          3 * NPTS * 4 /*comp2*/ + 3 * NPTS * 8 /*best*/ +
                          3 * NPTS * 4 /*deaths*/ + 3 * NPTS * 4 /*pairs*/ + 128;
  const size_t need_new = d16_all + hi_bytes + tail_new;        // ~109.4MB
  const size_t d2_bytes = (size_t)NPTS * NPTS * 4;              // 64MB
  const size_t small_old = NPTS * 4 + NPTS * 4 + NPTS * 8 + 3 * NPTS * 4 + 128;
  const size_t need_old = d2_bytes + small_old;

  if (ws_size >= need_new) {
    f16* d16 = (f16*)ws;
    f16* hi = (f16*)(ws + d16_all);
    ull* cd = (ull*)(ws + d16_all);  // alias: hi dead after GEMMs
    char* tp = ws + d16_all + hi_bytes;
    float* sq = (float*)tp;                    tp += 3 * NPTS * 4;
    int* comp = (int*)tp;                      tp += 3 * NPTS * 4;
    int* comp2 = (int*)tp;                     tp += 3 * NPTS * 4;
    ull* best = (ull*)tp;                      tp += 3 * NPTS * 8;
    float* deaths = (float*)tp;                tp += 3 * NPTS * 4;
    int* pairs = (int*)tp;                     tp += 3 * NPTS * 4;
    int* cnt = (int*)tp;  // cnt[0..2], done = cnt+3, C = cnt+6
    int* done = cnt + 3;
    int* Cdev = cnt + 6;

    k_init_global<<<48, 256, 0, stream>>>(comp, best, deaths, cnt);
    for (int c = 0; c < 3; ++c) {
      k_prep<<<NPTS, 256, 0, stream>>>(xs[c], sq + c * NPTS, hi);
      k_gemm_f16<<<dim3(NPTS / 128, NPTS / 128), 256, 0, stream>>>(
          hi, sq + c * NPTS, d16 + (size_t)c * NPTS * NPTS);
    }
    for (int r = 0; r < 4; ++r) {  // gated: rounds stop once C <= 256
      k_scan3<<<3 * (NPTS / 4), 256, 0, stream>>>((const u16*)d16, comp, best,
                                                  done, Cdev);
      k_merge3<<<3, 1024, 0, stream>>>(best, comp, comp2, pairs, cnt, done,
                                       Cdev, cd, (r == 0) ? 1 : 0);
    }
    k_contract3<<<3 * NPTS, 256, 0, stream>>>((const u16*)d16, comp2, cd, done);
    k_finish3<<<3, 1024, 0, stream>>>(cd, comp2, Cdev, pairs, cnt, done);
    k_deaths3<<<3 * NPTS, 256, 0, stream>>>(xs[0], xs[1], xs[2], sq, pairs,
                                            deaths);
    k_sort<<<3, 1024, 0, stream>>>(deaths);
    k_final<<<1, 1024, 0, stream>>>(deaths, (float*)d_out);
  } else if (ws_size >= need_old) {
    float* d2 = (float*)ws;
    char* tp = ws + d2_bytes;
    float* sq = (float*)tp;                    tp += NPTS * 4;
    int* comp = (int*)tp;                      tp += NPTS * 4;
    ull* best = (ull*)tp;                      tp += NPTS * 8;
    float* deaths = (float*)tp;                tp += 3 * NPTS * 4;
    int* cnt = (int*)tp;
    int* done = cnt + 3;
    k_init_deaths<<<48, 256, 0, stream>>>(deaths, cnt);
    for (int c = 0; c < 3; ++c) {
      k_norms<<<NPTS, 256, 0, stream>>>(xs[c], sq);
      k_init_cloud<<<16, 256, 0, stream>>>(comp, best, done);
      k_gemm_d2<<<dim3(NPTS / BN, NPTS / BM), 256, 0, stream>>>(xs[c], sq, d2);
      for (int r = 0; r < 12; ++r) {
        k_scan32<<<NPTS, 256, 0, stream>>>(d2, comp, best, done);
        k_merge1<<<1, 1024, 0, stream>>>(best, comp, d2, deaths + c * NPTS,
                                         cnt + c, done);
      }
    }
    k_sort<<<3, 1024, 0, stream>>>(deaths);
    k_final<<<1, 1024, 0, stream>>>(deaths, (float*)d_out);
  } else {
    k_fail<<<1, 64, 0, stream>>>((float*)d_out);
  }
}